// Round 8
// baseline (1297.606 us; speedup 1.0000x reference)
//
#include <hip/hip_runtime.h>
#include <stdint.h>

typedef unsigned int u32;
typedef unsigned long long u64;
typedef unsigned short u16;
typedef unsigned char u8;

#define CTR_M 0
#define CTR_E 1
#define CTR_C1 2
#define CTR_C3 3
#define CTR_CI 4
#define CTR_T 5
#define CTR_U 6
#define CTR_OUT1 7
#define CTR_TICK0 8    // slots 8..11: per-pass ticket counters

#define FLAG_P (1u << 30)
#define FLAG_X (2u << 30)
#define CNT_MASK 0x3FFFFFFFu

// TET_TABLE rows packed 4 bits/entry (LSB-first), -1 -> 0xF (never read: row
// count limited by num_tets). Row 15 == [0,1,2,3] doubles as the inner-tet row.
__device__ const u64 TETPACK[16] = {
  0xFFFFFFFFFFFFULL,
  0xFFFFFFFF6540ULL,
  0xFFFFFFFF7841ULL,
  0x610567156817ULL,
  0xFFFFFFFF9752ULL,
  0x290767097604ULL,
  0x921549158914ULL,
  0x286921682106ULL,
  0xFFFFFFFF8963ULL,
  0x398538058405ULL,
  0x376936743741ULL,
  0x971539153510ULL,
  0x875385637325ULL,
  0x273078308740ULL,
  0x653452343214ULL,
  0xFFFFFFFF3210ULL
};

// ---- pos = verts + tanh(deform)/grid_res ; also occ bitmap (sdf>0) ----
__global__ void __launch_bounds__(256) k_pos(
    const float* __restrict__ verts, const float* __restrict__ deform,
    const float* __restrict__ sdf, const int* __restrict__ grptr,
    float* __restrict__ pos, u32* __restrict__ occw, int N, int n3)
{
  int i = blockIdx.x * 256 + threadIdx.x;
  if (i < n3) {
    float inv = 1.0f / (float)grptr[0];
    pos[i] = verts[i] + tanhf(deform[i]) * inv;
  }
  const int NOCC = (N + 1023) / 1024;
  if (blockIdx.x < NOCC) {
    __shared__ u32 s_nib[256];
    const int tid = threadIdx.x;
    int base = blockIdx.x * 1024 + tid * 4;
    u32 nib = 0;
    if (base + 3 < N) {
      float4 s = *reinterpret_cast<const float4*>(sdf + base);
      nib = (s.x > 0.0f ? 1u : 0u) | (s.y > 0.0f ? 2u : 0u) |
            (s.z > 0.0f ? 4u : 0u) | (s.w > 0.0f ? 8u : 0u);
    } else {
      for (int k = 0; k < 4; ++k)
        if (base + k < N) nib |= (sdf[base + k] > 0.0f ? 1u : 0u) << k;
    }
    s_nib[tid] = nib;
    __syncthreads();
    if (tid < 32) {
      u32 w = 0;
      #pragma unroll
      for (int j = 0; j < 8; ++j) w |= s_nib[tid * 8 + j] << (4 * j);
      int wi = blockIdx.x * 32 + tid;
      if (wi < (N + 31) / 32) occw[wi] = w;
    }
  }
}

// ---- classify tets, emit crossing-edge records, flag inside verts ----
__global__ void __launch_bounds__(256) k_classify(
    const int* __restrict__ idx, const u32* __restrict__ occw, int F,
    u64* __restrict__ A, u32* __restrict__ ctr,
    u64* __restrict__ bsF, u8* __restrict__ tetidx, u8* __restrict__ flag)
{
  const int tid = threadIdx.x;
  const int lane = tid & 63;
  const int base = blockIdx.x * 1024 + tid * 4;
  u32 tis4 = 0;
  u32 cms[4];
  int4 vs[4];
  u64 cnt = 0;
  u32 ec = 0;
  #pragma unroll
  for (int it = 0; it < 4; ++it) {
    const int f = base + it;
    u32 ti = 0, cm = 0;
    int4 v = make_int4(0, 0, 0, 0);
    if (f < F) {
      v = reinterpret_cast<const int4*>(idx)[f];
      u32 b0 = (occw[(u32)v.x >> 5] >> (v.x & 31)) & 1u;
      u32 b1 = (occw[(u32)v.y >> 5] >> (v.y & 31)) & 1u;
      u32 b2 = (occw[(u32)v.z >> 5] >> (v.z & 31)) & 1u;
      u32 b3 = (occw[(u32)v.w >> 5] >> (v.w & 31)) & 1u;
      if (b0) flag[v.x] = 1;
      if (b1) flag[v.y] = 1;
      if (b2) flag[v.z] = 1;
      if (b3) flag[v.w] = 1;
      ti = b0 | (b1 << 1) | (b2 << 2) | (b3 << 3);
      cm  = (b0 ^ b1);
      cm |= (b0 ^ b2) << 1;
      cm |= (b0 ^ b3) << 2;
      cm |= (b1 ^ b2) << 3;
      cm |= (b1 ^ b3) << 4;
      cm |= (b2 ^ b3) << 5;
      int pc = __popc(ti);
      if (pc == 1) cnt += 1ULL;
      else if (pc == 2 || pc == 3) cnt += (1ULL << 21);
      else if (pc == 4) cnt += (1ULL << 42);
    }
    vs[it] = v;
    cms[it] = cm;
    tis4 |= ti << (8 * it);
    ec += __popc(cm);
  }
  u32 incl = ec;
  #pragma unroll
  for (int d = 1; d < 64; d <<= 1) {
    u32 t = __shfl_up(incl, d);
    if (lane >= d) incl += t;
  }
  u32 excl = incl - ec;
  u32 total = __shfl(incl, 63);
  u32 wbase = 0;
  if (lane == 0 && total) wbase = atomicAdd(&ctr[CTR_M], total);
  wbase = __shfl(wbase, 0);
  u32 w = wbase + excl;
  #pragma unroll
  for (int it = 0; it < 4; ++it) {
    u32 cm = cms[it];
    if (!cm) continue;
    const int f = base + it;
    const int va[6] = {vs[it].x, vs[it].x, vs[it].x, vs[it].y, vs[it].y, vs[it].z};
    const int vb[6] = {vs[it].y, vs[it].z, vs[it].w, vs[it].z, vs[it].w, vs[it].w};
    #pragma unroll
    for (int s = 0; s < 6; ++s) {
      if ((cm >> s) & 1u) {
        int a = va[s], b = vb[s];
        int mn = min(a, b), mx = max(a, b);
        u64 key = ((u64)(u32)mn << 19) | (u64)(u32)mx;
        A[w++] = (key << 24) | (u64)(u32)(f * 6 + s);
      }
    }
  }
  if (base < F) {
    if (base + 3 < F) {
      *reinterpret_cast<u32*>(tetidx + base) = tis4;
    } else {
      for (int it = 0; it < 4; ++it)
        if (base + it < F) tetidx[base + it] = (u8)((tis4 >> (8 * it)) & 255u);
    }
  }
  __shared__ u64 sh[256];
  sh[tid] = cnt;
  __syncthreads();
  for (int d = 128; d > 0; d >>= 1) {
    if (tid < d) sh[tid] += sh[tid + d];
    __syncthreads();
  }
  if (tid == 0) bsF[blockIdx.x] = sh[0];
}

// ---- all-4-pass digit histograms in one read of A (order-invariant) ----
__global__ void __launch_bounds__(256) k_hist4(
    const u64* __restrict__ A, const u32* __restrict__ ctr, u32* __restrict__ gh)
{
  __shared__ u32 sh[3072];
  const int tid = threadIdx.x;
  for (int b = tid; b < 3072; b += 256) sh[b] = 0;
  __syncthreads();
  const int M = (int)ctr[CTR_M];
  for (int i = blockIdx.x * 256 + tid; i < M; i += gridDim.x * 256) {
    u64 v = A[i];
    atomicAdd(&sh[        (u32)(v >> 24) & 1023u], 1u);
    atomicAdd(&sh[1024 + ((u32)(v >> 34) & 1023u)], 1u);
    atomicAdd(&sh[2048 + ((u32)(v >> 44) &  511u)], 1u);
    atomicAdd(&sh[2560 + ((u32)(v >> 53) &  511u)], 1u);
  }
  __syncthreads();
  for (int b = tid; b < 3072; b += 256) if (sh[b]) atomicAdd(&gh[b], sh[b]);
}

// ---- exclusive scan of each pass segment of gh (single launch) ----
__global__ void __launch_bounds__(1024) k_scan4(u32* __restrict__ gh)
{
  __shared__ u32 sh[1024];
  const int tid = threadIdx.x;
  const int off[4] = {0, 1024, 2048, 2560};
  const int len[4] = {1024, 1024, 512, 512};
  for (int s = 0; s < 4; ++s) {
    u32 v = (tid < len[s]) ? gh[off[s] + tid] : 0u;
    sh[tid] = v;
    __syncthreads();
    for (int d = 1; d < 1024; d <<= 1) {
      u32 t = (tid >= d) ? sh[tid - d] : 0u;
      __syncthreads();
      sh[tid] += t;
      __syncthreads();
    }
    if (tid < len[s]) gh[off[s] + tid] = sh[tid] - v;
    __syncthreads();
  }
}

// ---- exclusive scan of packed per-block category counts (single block) ----
__global__ void __launch_bounds__(1024) k_scanF(
    u64* __restrict__ bsF, int nb, u32* __restrict__ ctr)
{
  __shared__ u64 sh[1024];
  const int tid = threadIdx.x;
  u64 carry = 0;
  for (int start = 0; start < nb; start += 1024) {
    int i = start + tid;
    u64 v = (i < nb) ? bsF[i] : 0ULL;
    sh[tid] = v;
    __syncthreads();
    for (int d = 1; d < 1024; d <<= 1) {
      u64 t = (tid >= d) ? sh[tid - d] : 0ULL;
      __syncthreads();
      sh[tid] += t;
      __syncthreads();
    }
    if (i < nb) bsF[i] = carry + sh[tid] - v;
    carry += sh[1023];
    __syncthreads();
  }
  if (tid == 0) {
    u32 c1 = (u32)(carry & 0x1FFFFFULL);
    u32 c3 = (u32)((carry >> 21) & 0x1FFFFFULL);
    u32 ci = (u32)((carry >> 42) & 0x1FFFFFULL);
    ctr[CTR_C1] = c1; ctr[CTR_C3] = c3; ctr[CTR_CI] = ci;
    ctr[CTR_T] = c1 + 3u * c3 + ci;
  }
}

// ---- per-tet output row base (mt1 region | mt3 region | inner region) ----
__global__ void __launch_bounds__(256) k_rowbase(
    const u8* __restrict__ tetidx, const u64* __restrict__ bsF,
    const u32* __restrict__ ctr, int F, int* __restrict__ rowbase)
{
  const int tid = threadIdx.x;
  const int base = blockIdx.x * 1024 + tid * 4;
  u32 tis[4];
  u64 cnt = 0;
  #pragma unroll
  for (int it = 0; it < 4; ++it) {
    int f = base + it;
    u32 ti = (f < F) ? (u32)tetidx[f] : 0u;
    tis[it] = ti;
    int pc = __popc(ti);
    if (ti) {
      if (pc == 1) cnt += 1ULL;
      else if (pc <= 3) cnt += (1ULL << 21);
      else cnt += (1ULL << 42);
    }
  }
  __shared__ u64 sh[256];
  sh[tid] = cnt;
  __syncthreads();
  for (int d = 1; d < 256; d <<= 1) {
    u64 t = (tid >= d) ? sh[tid - d] : 0ULL;
    __syncthreads();
    sh[tid] += t;
    __syncthreads();
  }
  u64 off = bsF[blockIdx.x] + (sh[tid] - cnt);
  u32 o1 = (u32)(off & 0x1FFFFFULL);
  u32 o3 = (u32)((off >> 21) & 0x1FFFFFULL);
  u32 oi = (u32)((off >> 42) & 0x1FFFFFULL);
  const u32 C1 = ctr[CTR_C1], C3 = ctr[CTR_C3];
  int rb[4];
  #pragma unroll
  for (int it = 0; it < 4; ++it) {
    u32 ti = tis[it];
    int pc = __popc(ti);
    int r = -1;
    if (ti == 15u) { r = (int)(C1 + 3u * C3 + oi); ++oi; }
    else if (ti) {
      if (pc == 1) { r = (int)o1; ++o1; }
      else { r = (int)(C1 + 3u * o3); ++o3; }
    }
    rb[it] = r;
  }
  if (base + 3 < F) {
    reinterpret_cast<int4*>(rowbase)[base >> 2] = make_int4(rb[0], rb[1], rb[2], rb[3]);
  } else {
    for (int it = 0; it < 4; ++it)
      if (base + it < F) rowbase[base + it] = rb[it];
  }
}

// ------- parallel 3-kernel exclusive scan (used for partition pass only) -------
#define SCAN_BLOCKS 256
__global__ void __launch_bounds__(256) k_scan_p1(
    const u32* __restrict__ data, int L, u32* __restrict__ totals)
{
  const int tid = threadIdx.x;
  int chunk = ((L + SCAN_BLOCKS * 256 - 1) / (SCAN_BLOCKS * 256)) * 256;
  int s0 = blockIdx.x * chunk;
  int s1 = min(s0 + chunk, L);
  u32 s = 0;
  for (int i = s0 + tid; i < s1; i += 256) s += data[i];
  __shared__ u32 sh[256];
  sh[tid] = s;
  __syncthreads();
  for (int d = 128; d > 0; d >>= 1) {
    if (tid < d) sh[tid] += sh[tid + d];
    __syncthreads();
  }
  if (tid == 0) totals[blockIdx.x] = sh[0];
}

__global__ void __launch_bounds__(256) k_scan_p2(
    u32* __restrict__ totals, u32* __restrict__ ctr, int slot)
{
  const int tid = threadIdx.x;
  __shared__ u32 sh[256];
  u32 v = totals[tid];
  sh[tid] = v;
  __syncthreads();
  for (int d = 1; d < 256; d <<= 1) {
    u32 t = (tid >= d) ? sh[tid - d] : 0u;
    __syncthreads();
    sh[tid] += t;
    __syncthreads();
  }
  totals[tid] = sh[tid] - v;
  if (slot >= 0 && tid == 255) ctr[slot] = sh[255];
}

__global__ void __launch_bounds__(256) k_scan_p3(
    u32* __restrict__ data, int L, const u32* __restrict__ totals)
{
  const int tid = threadIdx.x;
  int chunk = ((L + SCAN_BLOCKS * 256 - 1) / (SCAN_BLOCKS * 256)) * 256;
  int s0 = blockIdx.x * chunk;
  int s1 = min(s0 + chunk, L);
  if (s0 >= L) return;
  u32 carry = totals[blockIdx.x];
  __shared__ u32 sh[256];
  for (int start = s0; start < s1; start += 256) {
    int i = start + tid;
    u32 v = (i < s1) ? data[i] : 0u;
    sh[tid] = v;
    __syncthreads();
    for (int d = 1; d < 256; d <<= 1) {
      u32 t = (tid >= d) ? sh[tid - d] : 0u;
      __syncthreads();
      sh[tid] += t;
      __syncthreads();
    }
    if (i < s1) data[i] = carry + sh[tid] - v;
    u32 tot = sh[255];
    __syncthreads();
    carry += tot;
  }
}

// ---- single-block scan (kept for small arrays: bsE) ----
__device__ __forceinline__ u32 block_scan_incl_1024(u32 x, u32* shtmp, u32& total)
{
  const int lane = threadIdx.x & 63;
  const int wid = threadIdx.x >> 6;
  u32 incl = x;
  #pragma unroll
  for (int d = 1; d < 64; d <<= 1) {
    u32 t = __shfl_up(incl, d);
    if (lane >= d) incl += t;
  }
  if (lane == 63) shtmp[wid] = incl;
  __syncthreads();
  if (wid == 0) {
    u32 w = (lane < 16) ? shtmp[lane] : 0u;
    #pragma unroll
    for (int d = 1; d < 16; d <<= 1) {
      u32 t = __shfl_up(w, d);
      if (lane >= d) w += t;
    }
    if (lane < 16) shtmp[lane] = w;
  }
  __syncthreads();
  u32 waveoff = (wid > 0) ? shtmp[wid - 1] : 0u;
  total = shtmp[15];
  return waveoff + incl;
}

__global__ void __launch_bounds__(1024) k_scan_u32(
    u32* __restrict__ data, int L, u32* __restrict__ ctr, int slot)
{
  __shared__ u32 shtmp[16];
  const int tid = threadIdx.x;
  u32 carry = 0;
  for (int start = 0; start < L; start += 4096) {
    u32 v[4]; u32 s = 0;
    #pragma unroll
    for (int j = 0; j < 4; ++j) {
      int i = start + tid * 4 + j;
      v[j] = (i < L) ? data[i] : 0u;
      s += v[j];
    }
    u32 total;
    u32 incl = block_scan_incl_1024(s, shtmp, total);
    u32 run = carry + incl - s;
    #pragma unroll
    for (int j = 0; j < 4; ++j) {
      int i = start + tid * 4 + j;
      if (i < L) data[i] = run;
      run += v[j];
    }
    carry += total;
    __syncthreads();
  }
  if (slot >= 0 && tid == 0) ctr[slot] = carry;
}

// sum of first keep (clamped to [0,4]) u16 lanes of p
__device__ __forceinline__ u32 hsum16(u64 p, int keep)
{
  if (keep <= 0) return 0;
  u64 m = (keep >= 4) ? ~0ULL : ((1ULL << (16 * keep)) - 1ULL);
  u64 x = p & m;
  x = (x & 0x0000FFFF0000FFFFULL) + ((x >> 16) & 0x0000FFFF0000FFFFULL);
  return (u32)x + (u32)(x >> 32);
}

// ------- onesweep radix scatter: ticket + decoupled lookback -------
// stability: window = ticket order = memory order; ranking phases unchanged.
__global__ void __launch_bounds__(256) k_scatter_lb(
    const u64* __restrict__ src, u64* __restrict__ dst,
    u32* __restrict__ ctr, int shift, int nbits,
    const u32* __restrict__ digbase, u32* __restrict__ status,
    int NBRC, int tick_slot)
{
  const int NB = 1 << nbits;
  __shared__ u32 s_gbase[1024];
  __shared__ u16 s_wh[1024 * 16];     // [digit][slot]
  __shared__ u32 s_bid;
  const int tid = threadIdx.x;
  const int lane = tid & 63;
  const int wid = tid >> 6;
  if (tid == 0) s_bid = atomicAdd(&ctr[tick_slot], 1u);
  for (int b = tid; b < NB; b += 256) s_gbase[b] = 0;   // local hist first
  for (int b = tid; b < NB * 8; b += 256) reinterpret_cast<u32*>(s_wh)[b] = 0;
  __syncthreads();
  const int bid = (int)s_bid;
  const int M = (int)ctr[CTR_M];
  const int base = bid * 16384;
  const int nact = M - base;
  if (nact <= 0) {
    // empty window: publish PARTIAL(0) so any walker passes through
    for (int d = tid; d < NB; d += 256) atomicExch(&status[d * NBRC + bid], FLAG_P);
    return;
  }
  // local digit histogram (coalesced read; window stays hot in L2)
  const int lim = base + min(nact, 16384);
  for (int i = base + tid; i < lim; i += 256)
    atomicAdd(&s_gbase[(u32)(src[i] >> shift) & (u32)(NB - 1)], 1u);
  __syncthreads();
  // publish PARTIAL|count (all state in the atomic word -> no fence needed)
  for (int d = tid; d < NB; d += 256)
    atomicExch(&status[d * NBRC + bid], FLAG_P | s_gbase[d]);
  // lookback per digit
  for (int d = tid; d < NB; d += 256) {
    u32 sum = 0;
    int b = bid - 1;
    while (b >= 0) {
      u32 s = atomicAdd(&status[d * NBRC + b], 0u);
      u32 f = s >> 30;
      if (f == 0) { __builtin_amdgcn_s_sleep(1); continue; }
      sum += s & CNT_MASK;
      if (f == 2) break;
      --b;
    }
    u32 own = s_gbase[d];
    atomicExch(&status[d * NBRC + bid], FLAG_X | (sum + own));
    s_gbase[d] = digbase[d] + sum;     // exclusive running base for this block
  }
  __syncthreads();
  const u64 lowmask = (1ULL << lane) - 1ULL;
  for (int r = 0; r < 16; ++r) {
    int rbase = base + r * 1024;
    if (rbase >= M) break;                 // uniform across block
    u64 v[4]; u32 d4[4]; u32 lr4[4]; u32 cnt4[4]; bool act[4];
    #pragma unroll
    for (int j = 0; j < 4; ++j) {
      int ib = rbase + (wid * 4 + j) * 64 + lane;
      act[j] = ib < M;
      v[j] = act[j] ? src[ib] : 0ULL;
      d4[j] = (u32)(v[j] >> shift) & (u32)(NB - 1);
    }
    #pragma unroll
    for (int j = 0; j < 4; ++j) {
      u32 d = d4[j];
      u64 mask = __ballot(act[j]);
      for (int b = 0; b < nbits; ++b) {
        u64 bal = __ballot(act[j] && ((d >> b) & 1u));
        mask &= ((d >> b) & 1u) ? bal : ~bal;
      }
      lr4[j] = (u32)__popcll(mask & lowmask);
      cnt4[j] = (u32)__popcll(mask);
      if (act[j] && lr4[j] == 0)
        s_wh[d * 16 + (wid * 4 + j)] = (u16)cnt4[j];
    }
    __syncthreads();
    #pragma unroll
    for (int j = 0; j < 4; ++j) {
      if (!act[j]) continue;
      u32 d = d4[j];
      int slot = wid * 4 + j;
      const u64* pw = reinterpret_cast<const u64*>(&s_wh[d * 16]);
      u32 pref = hsum16(pw[0], slot) + hsum16(pw[1], slot - 4) +
                 hsum16(pw[2], slot - 8) + hsum16(pw[3], slot - 12);
      dst[s_gbase[d] + pref + lr4[j]] = v[j];
    }
    __syncthreads();
    #pragma unroll
    for (int j = 0; j < 4; ++j) {
      if (act[j] && lr4[j] == 0) {
        atomicAdd(&s_gbase[d4[j]], cnt4[j]);
        s_wh[d4[j] * 16 + (wid * 4 + j)] = 0;
      }
    }
    __syncthreads();
  }
}

// ------- plain radix scatter (partition pass; per-block hist precomputed) -------
__global__ void __launch_bounds__(256) k_scatter(
    const u64* __restrict__ src, u64* __restrict__ dst,
    const u32* __restrict__ ctr, int shift, int nbits,
    const u32* __restrict__ hist, int NBR)
{
  const int NB = 1 << nbits;
  __shared__ u32 s_gbase[1024];
  __shared__ u16 s_wh[1024 * 16];     // [digit][slot]
  const int tid = threadIdx.x;
  const int lane = tid & 63;
  const int wid = tid >> 6;
  for (int b = tid; b < NB; b += 256) s_gbase[b] = hist[b * NBR + blockIdx.x];
  for (int b = tid; b < NB * 8; b += 256) reinterpret_cast<u32*>(s_wh)[b] = 0;
  __syncthreads();
  const int M = (int)ctr[CTR_M];
  const u64 lowmask = (1ULL << lane) - 1ULL;
  const int base = blockIdx.x * 16384;
  for (int r = 0; r < 16; ++r) {
    int rbase = base + r * 1024;
    if (rbase >= M) break;                 // uniform across block
    u64 v[4]; u32 d4[4]; u32 lr4[4]; u32 cnt4[4]; bool act[4];
    #pragma unroll
    for (int j = 0; j < 4; ++j) {
      int ib = rbase + (wid * 4 + j) * 64 + lane;
      act[j] = ib < M;
      v[j] = act[j] ? src[ib] : 0ULL;
      d4[j] = (u32)(v[j] >> shift) & (u32)(NB - 1);
    }
    #pragma unroll
    for (int j = 0; j < 4; ++j) {
      u32 d = d4[j];
      u64 mask = __ballot(act[j]);
      for (int b = 0; b < nbits; ++b) {
        u64 bal = __ballot(act[j] && ((d >> b) & 1u));
        mask &= ((d >> b) & 1u) ? bal : ~bal;
      }
      lr4[j] = (u32)__popcll(mask & lowmask);
      cnt4[j] = (u32)__popcll(mask);
      if (act[j] && lr4[j] == 0)
        s_wh[d * 16 + (wid * 4 + j)] = (u16)cnt4[j];
    }
    __syncthreads();
    #pragma unroll
    for (int j = 0; j < 4; ++j) {
      if (!act[j]) continue;
      u32 d = d4[j];
      int slot = wid * 4 + j;
      const u64* pw = reinterpret_cast<const u64*>(&s_wh[d * 16]);
      u32 pref = hsum16(pw[0], slot) + hsum16(pw[1], slot - 4) +
                 hsum16(pw[2], slot - 8) + hsum16(pw[3], slot - 12);
      dst[s_gbase[d] + pref + lr4[j]] = v[j];
    }
    __syncthreads();
    #pragma unroll
    for (int j = 0; j < 4; ++j) {
      if (act[j] && lr4[j] == 0) {
        atomicAdd(&s_gbase[d4[j]], cnt4[j]);
        s_wh[d4[j] * 16 + (wid * 4 + j)] = 0;
      }
    }
    __syncthreads();
  }
}

// ---------------- unique-run head counts per block (1024 items/block) ----------------
__global__ void __launch_bounds__(256) k_headcount(
    const u64* __restrict__ S, const u32* __restrict__ ctr, u32* __restrict__ bsE)
{
  const int tid = threadIdx.x;
  const int M = (int)ctr[CTR_M];
  const int base = blockIdx.x * 1024 + tid * 4;
  u32 c = 0;
  u64 prev = (base > 0 && base < M) ? (S[base - 1] >> 24) : 0ULL;
  #pragma unroll
  for (int j = 0; j < 4; ++j) {
    int i = base + j;
    if (i < M) {
      u64 k = S[i] >> 24;
      c += ((i == 0) || (k != prev)) ? 1u : 0u;
      prev = k;
    }
  }
  __shared__ u32 sh[256];
  sh[tid] = c;
  __syncthreads();
  for (int d = 128; d > 0; d >>= 1) {
    if (tid < d) sh[tid] += sh[tid + d];
    __syncthreads();
  }
  if (tid == 0) bsE[blockIdx.x] = sh[0];
}

// ---- assign ids (4 items/thread): unique keys + coalesced pairs + fused hist ----
__global__ void __launch_bounds__(256) k_assign(
    const u64* __restrict__ S, const u32* __restrict__ ctr,
    const u32* __restrict__ bsE, u64* __restrict__ stage,
    u32* __restrict__ hist, int NBR, u64* __restrict__ edgekeys)
{
  const int tid = threadIdx.x;
  const int M = (int)ctr[CTR_M];
  const int base = blockIdx.x * 1024 + tid * 4;
  __shared__ u32 s_h[256];
  __shared__ u32 sh[256];
  s_h[tid] = 0;
  u64 v[4]; bool hd[4];
  u32 c = 0;
  u64 prev = (base > 0 && base < M) ? (S[base - 1] >> 24) : 0ULL;
  #pragma unroll
  for (int j = 0; j < 4; ++j) {
    int i = base + j;
    v[j] = (i < M) ? S[i] : 0ULL;
    u64 k = v[j] >> 24;
    hd[j] = (i < M) && ((i == 0) || (k != prev));
    if (i < M) prev = k;
    c += hd[j] ? 1u : 0u;
  }
  sh[tid] = c;
  __syncthreads();
  for (int d = 1; d < 256; d <<= 1) {
    u32 t = (tid >= d) ? sh[tid - d] : 0u;
    __syncthreads();
    sh[tid] += t;
    __syncthreads();
  }
  u32 run = bsE[blockIdx.x] + sh[tid] - c;
  #pragma unroll
  for (int j = 0; j < 4; ++j) {
    int i = base + j;
    if (i < M) {
      run += hd[j] ? 1u : 0u;
      u32 id = run - 1u;
      if (hd[j]) edgekeys[id] = v[j] >> 24;
      u32 pay = (u32)(v[j] & 0xFFFFFFULL);
      stage[i] = ((u64)pay << 24) | (u64)id;
      atomicAdd(&s_h[(pay >> 16) & 255u], 1u);
    }
  }
  __syncthreads();
  if (s_h[tid]) atomicAdd(&hist[tid * NBR + (blockIdx.x >> 4)], s_h[tid]);
}

// ---- deliver: edge_ids[payload] = id (payload-bucketed for L2 locality) ----
__global__ void __launch_bounds__(256) k_deliver(
    const u64* __restrict__ D, const u32* __restrict__ ctr,
    int* __restrict__ edge_ids)
{
  int i = blockIdx.x * 256 + threadIdx.x;
  if (i >= (int)ctr[CTR_M]) return;
  u64 c = D[i];
  edge_ids[(u32)(c >> 24)] = (int)(c & 0xFFFFFFULL);
}

// ---- rank scan over flag bytes -> bwr (low32 = bits, high32 = wordrank) ----
__global__ void __launch_bounds__(1024) k_scanbits(
    const u32* __restrict__ flag32, u64* __restrict__ bwr,
    int W, u32* __restrict__ ctr)
{
  __shared__ u32 shtmp[16];
  const int tid = threadIdx.x;
  u32 carry = 0;
  for (int start = 0; start < W; start += 1024) {
    int w = start + tid;
    u32 bits = 0;
    if (w < W) {
      #pragma unroll
      for (int k = 0; k < 8; ++k) {
        u32 fo = flag32[w * 8 + k];
        u32 nib = (fo & 1u) | ((fo >> 7) & 2u) | ((fo >> 14) & 4u) | ((fo >> 21) & 8u);
        bits |= nib << (4 * k);
      }
    }
    u32 c = (u32)__popc(bits);
    u32 total;
    u32 incl = block_scan_incl_1024(c, shtmp, total);
    if (w < W) bwr[w] = (u64)bits | ((u64)(carry + incl - c) << 32);
    carry += total;
    __syncthreads();
  }
  if (tid == 0) {
    ctr[CTR_U] = carry;
    ctr[CTR_OUT1] = 3u * (carry + ctr[CTR_E]);
  }
}

// ---------------- output 0a: original vertices ----------------
__global__ void __launch_bounds__(256) k_out0_orig(
    const u64* __restrict__ bwr, const float* __restrict__ pos,
    int N, float* __restrict__ out)
{
  int id = blockIdx.x * 256 + threadIdx.x;
  if (id >= N) return;
  u64 bw = bwr[(u32)id >> 5];
  u32 bits = (u32)bw;
  if (!((bits >> (id & 31)) & 1u)) return;
  u32 j = (u32)(bw >> 32) + (u32)__popc(bits & ((1u << (id & 31)) - 1u));
  size_t o = (size_t)3 * j;
  out[o] = pos[3 * id]; out[o + 1] = pos[3 * id + 1]; out[o + 2] = pos[3 * id + 2];
}

// ---------------- output 0b: interpolated edge vertices ----------------
__global__ void __launch_bounds__(256) k_out0_edge(
    const u64* __restrict__ edgekeys, const float* __restrict__ pos,
    const float* __restrict__ sdf, const u32* __restrict__ ctr,
    float* __restrict__ out)
{
  int e = blockIdx.x * 256 + threadIdx.x;
  if (e >= (int)ctr[CTR_E]) return;
  u64 k = edgekeys[e];
  int a = (int)(k >> 19);
  int b = (int)(k & 0x7FFFFULL);
  float sa = sdf[a], sb = sdf[b];
  float inv = 1.0f / (sa - sb);
  float wa = -sb * inv, wb = sa * inv;
  u32 j = ctr[CTR_U] + (u32)e;
  size_t o = (size_t)3 * j;
  out[o]     = pos[3 * a] * wa + pos[3 * b] * wb;
  out[o + 1] = pos[3 * a + 1] * wa + pos[3 * b + 1] * wb;
  out[o + 2] = pos[3 * a + 2] * wa + pos[3 * b + 2] * wb;
}

// ---------------- output 1: tets = rank(ids), one 16B store per row ----------------
__global__ void __launch_bounds__(256) k_out1(
    const int* __restrict__ idx, const u8* __restrict__ tetidx,
    const int* __restrict__ edge_ids, const int* __restrict__ rowbase,
    const u64* __restrict__ bwr, const u32* __restrict__ ctr,
    int F, int N, float* __restrict__ out)
{
  int f = blockIdx.x * 256 + threadIdx.x;
  if (f >= F) return;
  u32 ti = tetidx[f];
  if (ti == 0) return;
  int4 v = reinterpret_cast<const int4*>(idx)[f];
  int pc = __popc(ti);
  int nt = (pc == 1 || pc == 4) ? 1 : 3;
  u64 row = TETPACK[ti];
  u32 obase = ctr[CTR_OUT1];
  u32 U0 = ctr[CTR_U];
  int rb = rowbase[f];
  float cr[4] = {0.f, 0.f, 0.f, 0.f};
  const int ids[4] = {v.x, v.y, v.z, v.w};
  #pragma unroll
  for (int c = 0; c < 4; ++c) {
    if ((ti >> c) & 1u) {
      int id = ids[c];
      u64 bw = bwr[(u32)id >> 5];
      cr[c] = (float)((u32)(bw >> 32) + (u32)__popc((u32)bw & ((1u << (id & 31)) - 1u)));
    }
  }
  const bool al16 = (obase & 3u) == 0u;
  float* outp = out + (size_t)obase + (size_t)rb * 4;
  for (int t = 0; t < nt; ++t) {
    u32 quad = (u32)(row >> (16 * t)) & 0xFFFFu;
    float o[4];
    #pragma unroll
    for (int k = 0; k < 4; ++k) {
      u32 e = (quad >> (4 * k)) & 15u;
      o[k] = (e < 4u) ? cr[e] : (float)(U0 + (u32)edge_ids[f * 6 + (int)(e - 4u)]);
    }
    if (al16) {
      *reinterpret_cast<float4*>(outp + (size_t)t * 4) =
          make_float4(o[0], o[1], o[2], o[3]);
    } else {
      __builtin_memcpy(outp + (size_t)t * 4, o, 16);
    }
  }
}

extern "C" void kernel_launch(void* const* d_in, const int* in_sizes, int n_in,
                              void* d_out, int out_size, void* d_ws, size_t ws_size,
                              hipStream_t stream)
{
  const float* verts  = (const float*)d_in[0];
  const float* deform = (const float*)d_in[1];
  const float* sdf    = (const float*)d_in[2];
  const int* indices  = (const int*)d_in[3];
  const int* grptr    = (const int*)d_in[4];
  const int N = in_sizes[2];
  const int F = in_sizes[3] / 4;
  const int MMAX = 4 * F;                      // <=4 crossing edges per tet
  const int NBF = (F + 1023) / 1024;
  const int NBR = (MMAX + 16383) / 16384;      // radix block capacity
  const int NBA = (MMAX + 1023) / 1024;        // headcount/assign blocks
  const int W = (N + 31) / 32;                 // flag bitmap words

  char* p = (char*)d_ws;
  auto take = [&](size_t bytes) {
    char* r = p;
    p += (bytes + 255) & ~(size_t)255;
    return r;
  };
  u32* ctr       = (u32*)take(256);
  u32* gh        = (u32*)take(3072 * 4);
  u32* scanaux   = (u32*)take(SCAN_BLOCKS * 4);
  u64* A         = (u64*)take((size_t)MMAX * 8);
  u64* B         = (u64*)take((size_t)MMAX * 8);
  u64* EK        = (u64*)take((size_t)MMAX * 8);
  int* edge_ids  = (int*)take((size_t)F * 6 * 4);
  float* pos     = (float*)take((size_t)N * 3 * 4);
  int* rowbase   = (int*)take((size_t)F * 4);
  u8* tetidx     = (u8*)take((size_t)F);
  u32* hist      = (u32*)take((size_t)NBR * 1024 * 4);  // status / partition hist
  u32* bsE       = (u32*)take((size_t)NBA * 4);
  u64* bsF       = (u64*)take((size_t)NBF * 8);
  u8* flag       = (u8*)take((size_t)W * 32);
  u32* occw      = (u32*)take((size_t)W * 4);
  u64* bwr       = (u64*)take((size_t)W * 8);
  if ((size_t)(p - (char*)d_ws) > ws_size) return;  // insufficient scratch

  hipMemsetAsync(ctr, 0, 256, stream);
  hipMemsetAsync(gh, 0, 3072 * 4, stream);
  hipMemsetAsync(flag, 0, (size_t)W * 32, stream);

  float* out = (float*)d_out;

  k_pos<<<(N * 3 + 255) / 256, 256, 0, stream>>>(verts, deform, sdf, grptr,
                                                 pos, occw, N, N * 3);
  k_classify<<<NBF, 256, 0, stream>>>(indices, occw, F, A, ctr, bsF, tetidx, flag);
  k_scanF<<<1, 1024, 0, stream>>>(bsF, NBF, ctr);
  k_rowbase<<<NBF, 256, 0, stream>>>(tetidx, bsF, ctr, F, rowbase);

  // all-pass digit totals (order-invariant) + per-segment exclusive scan
  k_hist4<<<2048, 256, 0, stream>>>(A, ctr, gh);
  k_scan4<<<1, 1024, 0, stream>>>(gh);

  // 4-pass LSD radix via onesweep lookback: digits {10,10,9,9} over bits 24..61
  const int shifts[4] = {24, 34, 44, 53};
  const int nbitsv[4] = {10, 10, 9, 9};
  const int ghoff[4]  = {0, 1024, 2048, 2560};
  u64* src = A; u64* dst = B;
  for (int pass = 0; pass < 4; ++pass) {
    hipMemsetAsync(hist, 0, (size_t)NBR * (1 << nbitsv[pass]) * 4, stream);
    k_scatter_lb<<<NBR, 256, 0, stream>>>(src, dst, ctr, shifts[pass],
                                          nbitsv[pass], gh + ghoff[pass],
                                          hist, NBR, CTR_TICK0 + pass);
    u64* t = src; src = dst; dst = t;
  }
  // sorted result in src (==A after 4 passes); dst (==B) free -> pair staging
  const u64* S = src;
  u64* stage = dst;

  k_headcount<<<NBA, 256, 0, stream>>>(S, ctr, bsE);
  k_scan_u32<<<1, 1024, 0, stream>>>(bsE, NBA, ctr, CTR_E);
  hipMemsetAsync(hist, 0, (size_t)NBR * 256 * 4, stream);
  k_assign<<<NBA, 256, 0, stream>>>(S, ctr, bsE, stage, hist, NBR, EK);
  // partition pairs by payload>>16 (256KB edge_ids windows) then deliver
  {
    int L = 256 * NBR;
    k_scan_p1<<<SCAN_BLOCKS, 256, 0, stream>>>(hist, L, scanaux);
    k_scan_p2<<<1, 256, 0, stream>>>(scanaux, ctr, -1);
    k_scan_p3<<<SCAN_BLOCKS, 256, 0, stream>>>(hist, L, scanaux);
    k_scatter<<<NBR, 256, 0, stream>>>(stage, (u64*)S, ctr, 40, 8, hist, NBR);
  }
  k_deliver<<<(MMAX + 255) / 256, 256, 0, stream>>>(S, ctr, edge_ids);

  k_scanbits<<<1, 1024, 0, stream>>>((const u32*)flag, bwr, W, ctr);
  k_out0_orig<<<(N + 255) / 256, 256, 0, stream>>>(bwr, pos, N, out);
  k_out0_edge<<<(MMAX + 255) / 256, 256, 0, stream>>>(EK, pos, sdf, ctr, out);
  k_out1<<<(F + 255) / 256, 256, 0, stream>>>(indices, tetidx, edge_ids, rowbase,
                                              bwr, ctr, F, N, out);
}

// Round 9
// 828.527 us; speedup vs baseline: 1.5662x; 1.5662x over previous
//
#include <hip/hip_runtime.h>
#include <stdint.h>

typedef unsigned int u32;
typedef unsigned long long u64;
typedef unsigned short u16;
typedef unsigned char u8;

#define CTR_M 0
#define CTR_E 1
#define CTR_C1 2
#define CTR_C3 3
#define CTR_CI 4
#define CTR_T 5
#define CTR_U 6
#define CTR_OUT1 7

// TET_TABLE rows packed 4 bits/entry (LSB-first), -1 -> 0xF (never read: row
// count limited by num_tets). Row 15 == [0,1,2,3] doubles as the inner-tet row.
__device__ const u64 TETPACK[16] = {
  0xFFFFFFFFFFFFULL,
  0xFFFFFFFF6540ULL,
  0xFFFFFFFF7841ULL,
  0x610567156817ULL,
  0xFFFFFFFF9752ULL,
  0x290767097604ULL,
  0x921549158914ULL,
  0x286921682106ULL,
  0xFFFFFFFF8963ULL,
  0x398538058405ULL,
  0x376936743741ULL,
  0x971539153510ULL,
  0x875385637325ULL,
  0x273078308740ULL,
  0x653452343214ULL,
  0xFFFFFFFF3210ULL
};

// ---- pos = verts + tanh(deform)/grid_res ; also occ bitmap (sdf>0) ----
__global__ void __launch_bounds__(256) k_pos(
    const float* __restrict__ verts, const float* __restrict__ deform,
    const float* __restrict__ sdf, const int* __restrict__ grptr,
    float* __restrict__ pos, u32* __restrict__ occw, int N, int n3)
{
  int i = blockIdx.x * 256 + threadIdx.x;
  if (i < n3) {
    float inv = 1.0f / (float)grptr[0];
    pos[i] = verts[i] + tanhf(deform[i]) * inv;
  }
  const int NOCC = (N + 1023) / 1024;
  if (blockIdx.x < NOCC) {
    __shared__ u32 s_nib[256];
    const int tid = threadIdx.x;
    int base = blockIdx.x * 1024 + tid * 4;
    u32 nib = 0;
    if (base + 3 < N) {
      float4 s = *reinterpret_cast<const float4*>(sdf + base);
      nib = (s.x > 0.0f ? 1u : 0u) | (s.y > 0.0f ? 2u : 0u) |
            (s.z > 0.0f ? 4u : 0u) | (s.w > 0.0f ? 8u : 0u);
    } else {
      for (int k = 0; k < 4; ++k)
        if (base + k < N) nib |= (sdf[base + k] > 0.0f ? 1u : 0u) << k;
    }
    s_nib[tid] = nib;
    __syncthreads();
    if (tid < 32) {
      u32 w = 0;
      #pragma unroll
      for (int j = 0; j < 8; ++j) w |= s_nib[tid * 8 + j] << (4 * j);
      int wi = blockIdx.x * 32 + tid;
      if (wi < (N + 31) / 32) occw[wi] = w;
    }
  }
}

// ---- classify tets, emit crossing-edge records, flag inside verts ----
// one global atomic per BLOCK (wave totals exchanged through LDS)
__global__ void __launch_bounds__(256) k_classify(
    const int* __restrict__ idx, const u32* __restrict__ occw, int F,
    u64* __restrict__ A, u32* __restrict__ ctr,
    u64* __restrict__ bsF, u8* __restrict__ tetidx, u8* __restrict__ flag)
{
  const int tid = threadIdx.x;
  const int lane = tid & 63;
  const int wid = tid >> 6;
  const int base = blockIdx.x * 1024 + tid * 4;
  u32 tis4 = 0;
  u32 cms[4];
  int4 vs[4];
  u64 cnt = 0;
  u32 ec = 0;
  #pragma unroll
  for (int it = 0; it < 4; ++it) {
    const int f = base + it;
    u32 ti = 0, cm = 0;
    int4 v = make_int4(0, 0, 0, 0);
    if (f < F) {
      v = reinterpret_cast<const int4*>(idx)[f];
      u32 b0 = (occw[(u32)v.x >> 5] >> (v.x & 31)) & 1u;
      u32 b1 = (occw[(u32)v.y >> 5] >> (v.y & 31)) & 1u;
      u32 b2 = (occw[(u32)v.z >> 5] >> (v.z & 31)) & 1u;
      u32 b3 = (occw[(u32)v.w >> 5] >> (v.w & 31)) & 1u;
      if (b0) flag[v.x] = 1;
      if (b1) flag[v.y] = 1;
      if (b2) flag[v.z] = 1;
      if (b3) flag[v.w] = 1;
      ti = b0 | (b1 << 1) | (b2 << 2) | (b3 << 3);
      cm  = (b0 ^ b1);
      cm |= (b0 ^ b2) << 1;
      cm |= (b0 ^ b3) << 2;
      cm |= (b1 ^ b2) << 3;
      cm |= (b1 ^ b3) << 4;
      cm |= (b2 ^ b3) << 5;
      int pc = __popc(ti);
      if (pc == 1) cnt += 1ULL;
      else if (pc == 2 || pc == 3) cnt += (1ULL << 21);
      else if (pc == 4) cnt += (1ULL << 42);
    }
    vs[it] = v;
    cms[it] = cm;
    tis4 |= ti << (8 * it);
    ec += __popc(cm);
  }
  u32 incl = ec;
  #pragma unroll
  for (int d = 1; d < 64; d <<= 1) {
    u32 t = __shfl_up(incl, d);
    if (lane >= d) incl += t;
  }
  u32 excl = incl - ec;
  __shared__ u32 s_wtot[4];
  __shared__ u32 s_base;
  if (lane == 63) s_wtot[wid] = incl;
  __syncthreads();
  if (tid == 0) {
    u32 t0 = s_wtot[0], t1 = s_wtot[1], t2 = s_wtot[2], t3 = s_wtot[3];
    u32 tot = t0 + t1 + t2 + t3;
    s_base = tot ? atomicAdd(&ctr[CTR_M], tot) : 0u;
    s_wtot[0] = 0; s_wtot[1] = t0; s_wtot[2] = t0 + t1; s_wtot[3] = t0 + t1 + t2;
  }
  __syncthreads();
  u32 w = s_base + s_wtot[wid] + excl;
  #pragma unroll
  for (int it = 0; it < 4; ++it) {
    u32 cm = cms[it];
    if (!cm) continue;
    const int f = base + it;
    const int va[6] = {vs[it].x, vs[it].x, vs[it].x, vs[it].y, vs[it].y, vs[it].z};
    const int vb[6] = {vs[it].y, vs[it].z, vs[it].w, vs[it].z, vs[it].w, vs[it].w};
    #pragma unroll
    for (int s = 0; s < 6; ++s) {
      if ((cm >> s) & 1u) {
        int a = va[s], b = vb[s];
        int mn = min(a, b), mx = max(a, b);
        u64 key = ((u64)(u32)mn << 19) | (u64)(u32)mx;
        A[w++] = (key << 24) | (u64)(u32)(f * 6 + s);
      }
    }
  }
  if (base < F) {
    if (base + 3 < F) {
      *reinterpret_cast<u32*>(tetidx + base) = tis4;
    } else {
      for (int it = 0; it < 4; ++it)
        if (base + it < F) tetidx[base + it] = (u8)((tis4 >> (8 * it)) & 255u);
    }
  }
  __shared__ u64 sh[256];
  sh[tid] = cnt;
  __syncthreads();
  for (int d = 128; d > 0; d >>= 1) {
    if (tid < d) sh[tid] += sh[tid + d];
    __syncthreads();
  }
  if (tid == 0) bsF[blockIdx.x] = sh[0];
}

// ---- all-pass digit histograms in ONE read of A (order-invariant) ----
// segments: [0,1024) pass0 | [1024,2048) pass1 | [2048,2560) pass2 |
//           [2560,3072) pass3 | [3072,3328) partition (payload>>16 & 255)
__global__ void __launch_bounds__(256) k_hist4(
    const u64* __restrict__ A, const u32* __restrict__ ctr, u32* __restrict__ gh)
{
  __shared__ u32 sh[3328];
  const int tid = threadIdx.x;
  for (int b = tid; b < 3328; b += 256) sh[b] = 0;
  __syncthreads();
  const int M = (int)ctr[CTR_M];
  for (int i = blockIdx.x * 256 + tid; i < M; i += gridDim.x * 256) {
    u64 v = A[i];
    atomicAdd(&sh[        (u32)(v >> 24) & 1023u], 1u);
    atomicAdd(&sh[1024 + ((u32)(v >> 34) & 1023u)], 1u);
    atomicAdd(&sh[2048 + ((u32)(v >> 44) &  511u)], 1u);
    atomicAdd(&sh[2560 + ((u32)(v >> 53) &  511u)], 1u);
    atomicAdd(&sh[3072 + ((u32)(v >> 16) &  255u)], 1u);
  }
  __syncthreads();
  for (int b = tid; b < 3328; b += 256) if (sh[b]) atomicAdd(&gh[b], sh[b]);
}

// ---- exclusive scan of each segment of gh (single launch) ----
__global__ void __launch_bounds__(1024) k_scan4(u32* __restrict__ gh)
{
  __shared__ u32 sh[1024];
  const int tid = threadIdx.x;
  const int off[5] = {0, 1024, 2048, 2560, 3072};
  const int len[5] = {1024, 1024, 512, 512, 256};
  for (int s = 0; s < 5; ++s) {
    u32 v = (tid < len[s]) ? gh[off[s] + tid] : 0u;
    sh[tid] = v;
    __syncthreads();
    for (int d = 1; d < 1024; d <<= 1) {
      u32 t = (tid >= d) ? sh[tid - d] : 0u;
      __syncthreads();
      sh[tid] += t;
      __syncthreads();
    }
    if (tid < len[s]) gh[off[s] + tid] = sh[tid] - v;
    __syncthreads();
  }
}

// ---- per-digit row scan: hist[d][0..NBR) -> global exclusive bases ----
__global__ void __launch_bounds__(256) k_rowscan(
    u32* __restrict__ hist, int NBR, const u32* __restrict__ gh)
{
  const int d = blockIdx.x;
  u32* row = hist + (size_t)d * NBR;
  const int tid = threadIdx.x;
  __shared__ u32 sh[256];
  u32 carry = gh[d];
  for (int start = 0; start < NBR; start += 256) {
    int i = start + tid;
    u32 v = (i < NBR) ? row[i] : 0u;
    sh[tid] = v;
    __syncthreads();
    for (int dd = 1; dd < 256; dd <<= 1) {
      u32 t = (tid >= dd) ? sh[tid - dd] : 0u;
      __syncthreads();
      sh[tid] += t;
      __syncthreads();
    }
    if (i < NBR) row[i] = carry + sh[tid] - v;
    u32 tot = sh[255];
    __syncthreads();
    carry += tot;
  }
}

// ---- exclusive scan of packed per-block category counts (single block) ----
__global__ void __launch_bounds__(1024) k_scanF(
    u64* __restrict__ bsF, int nb, u32* __restrict__ ctr)
{
  __shared__ u64 sh[1024];
  const int tid = threadIdx.x;
  u64 carry = 0;
  for (int start = 0; start < nb; start += 1024) {
    int i = start + tid;
    u64 v = (i < nb) ? bsF[i] : 0ULL;
    sh[tid] = v;
    __syncthreads();
    for (int d = 1; d < 1024; d <<= 1) {
      u64 t = (tid >= d) ? sh[tid - d] : 0ULL;
      __syncthreads();
      sh[tid] += t;
      __syncthreads();
    }
    if (i < nb) bsF[i] = carry + sh[tid] - v;
    carry += sh[1023];
    __syncthreads();
  }
  if (tid == 0) {
    u32 c1 = (u32)(carry & 0x1FFFFFULL);
    u32 c3 = (u32)((carry >> 21) & 0x1FFFFFULL);
    u32 ci = (u32)((carry >> 42) & 0x1FFFFFULL);
    ctr[CTR_C1] = c1; ctr[CTR_C3] = c3; ctr[CTR_CI] = ci;
    ctr[CTR_T] = c1 + 3u * c3 + ci;
  }
}

// ---- per-tet output row base (mt1 region | mt3 region | inner region) ----
__global__ void __launch_bounds__(256) k_rowbase(
    const u8* __restrict__ tetidx, const u64* __restrict__ bsF,
    const u32* __restrict__ ctr, int F, int* __restrict__ rowbase)
{
  const int tid = threadIdx.x;
  const int base = blockIdx.x * 1024 + tid * 4;
  u32 tis[4];
  u64 cnt = 0;
  #pragma unroll
  for (int it = 0; it < 4; ++it) {
    int f = base + it;
    u32 ti = (f < F) ? (u32)tetidx[f] : 0u;
    tis[it] = ti;
    int pc = __popc(ti);
    if (ti) {
      if (pc == 1) cnt += 1ULL;
      else if (pc <= 3) cnt += (1ULL << 21);
      else cnt += (1ULL << 42);
    }
  }
  __shared__ u64 sh[256];
  sh[tid] = cnt;
  __syncthreads();
  for (int d = 1; d < 256; d <<= 1) {
    u64 t = (tid >= d) ? sh[tid - d] : 0ULL;
    __syncthreads();
    sh[tid] += t;
    __syncthreads();
  }
  u64 off = bsF[blockIdx.x] + (sh[tid] - cnt);
  u32 o1 = (u32)(off & 0x1FFFFFULL);
  u32 o3 = (u32)((off >> 21) & 0x1FFFFFULL);
  u32 oi = (u32)((off >> 42) & 0x1FFFFFULL);
  const u32 C1 = ctr[CTR_C1], C3 = ctr[CTR_C3];
  int rb[4];
  #pragma unroll
  for (int it = 0; it < 4; ++it) {
    u32 ti = tis[it];
    int pc = __popc(ti);
    int r = -1;
    if (ti == 15u) { r = (int)(C1 + 3u * C3 + oi); ++oi; }
    else if (ti) {
      if (pc == 1) { r = (int)o1; ++o1; }
      else { r = (int)(C1 + 3u * o3); ++o3; }
    }
    rb[it] = r;
  }
  if (base + 3 < F) {
    reinterpret_cast<int4*>(rowbase)[base >> 2] = make_int4(rb[0], rb[1], rb[2], rb[3]);
  } else {
    for (int it = 0; it < 4; ++it)
      if (base + it < F) rowbase[base + it] = rb[it];
  }
}

// ---------------- radix sort: per-block histogram (16K items/block) ----------------
__global__ void __launch_bounds__(256) k_hist(
    const u64* __restrict__ src, const u32* __restrict__ ctr,
    int shift, int nbits, u32* __restrict__ hist, int NBR)
{
  const int NB = 1 << nbits;
  __shared__ u32 sh[1024];
  const int tid = threadIdx.x;
  for (int b = tid; b < NB; b += 256) sh[b] = 0;
  __syncthreads();
  const int M = (int)ctr[CTR_M];
  const int base = blockIdx.x * 16384;
  for (int r = 0; r < 16; ++r) {
    int rbase = base + r * 1024;
    if (rbase >= M) break;
    int ib = rbase + tid * 4;
    #pragma unroll
    for (int j = 0; j < 4; ++j) {
      if (ib + j < M) {
        u32 d = (u32)(src[ib + j] >> shift) & (u32)(NB - 1);
        atomicAdd(&sh[d], 1u);
      }
    }
  }
  __syncthreads();
  for (int b = tid; b < NB; b += 256) hist[b * NBR + blockIdx.x] = sh[b];
}

// ---- single-block scan (kept for small arrays: bsE) ----
__device__ __forceinline__ u32 block_scan_incl_1024(u32 x, u32* shtmp, u32& total)
{
  const int lane = threadIdx.x & 63;
  const int wid = threadIdx.x >> 6;
  u32 incl = x;
  #pragma unroll
  for (int d = 1; d < 64; d <<= 1) {
    u32 t = __shfl_up(incl, d);
    if (lane >= d) incl += t;
  }
  if (lane == 63) shtmp[wid] = incl;
  __syncthreads();
  if (wid == 0) {
    u32 w = (lane < 16) ? shtmp[lane] : 0u;
    #pragma unroll
    for (int d = 1; d < 16; d <<= 1) {
      u32 t = __shfl_up(w, d);
      if (lane >= d) w += t;
    }
    if (lane < 16) shtmp[lane] = w;
  }
  __syncthreads();
  u32 waveoff = (wid > 0) ? shtmp[wid - 1] : 0u;
  total = shtmp[15];
  return waveoff + incl;
}

__global__ void __launch_bounds__(1024) k_scan_u32(
    u32* __restrict__ data, int L, u32* __restrict__ ctr, int slot)
{
  __shared__ u32 shtmp[16];
  const int tid = threadIdx.x;
  u32 carry = 0;
  for (int start = 0; start < L; start += 4096) {
    u32 v[4]; u32 s = 0;
    #pragma unroll
    for (int j = 0; j < 4; ++j) {
      int i = start + tid * 4 + j;
      v[j] = (i < L) ? data[i] : 0u;
      s += v[j];
    }
    u32 total;
    u32 incl = block_scan_incl_1024(s, shtmp, total);
    u32 run = carry + incl - s;
    #pragma unroll
    for (int j = 0; j < 4; ++j) {
      int i = start + tid * 4 + j;
      if (i < L) data[i] = run;
      run += v[j];
    }
    carry += total;
    __syncthreads();
  }
  if (slot >= 0 && tid == 0) ctr[slot] = carry;
}

// sum of first keep (clamped to [0,4]) u16 lanes of p
__device__ __forceinline__ u32 hsum16(u64 p, int keep)
{
  if (keep <= 0) return 0;
  u64 m = (keep >= 4) ? ~0ULL : ((1ULL << (16 * keep)) - 1ULL);
  u64 x = p & m;
  x = (x & 0x0000FFFF0000FFFFULL) + ((x >> 16) & 0x0000FFFF0000FFFFULL);
  return (u32)x + (u32)(x >> 32);
}

// ------- radix scatter: stable, race-free (write-once per (slot,digit)) -------
__global__ void __launch_bounds__(256) k_scatter(
    const u64* __restrict__ src, u64* __restrict__ dst,
    const u32* __restrict__ ctr, int shift, int nbits,
    const u32* __restrict__ hist, int NBR)
{
  const int NB = 1 << nbits;
  __shared__ u32 s_gbase[1024];
  __shared__ u16 s_wh[1024 * 16];     // [digit][slot]
  const int tid = threadIdx.x;
  const int lane = tid & 63;
  const int wid = tid >> 6;
  for (int b = tid; b < NB; b += 256) s_gbase[b] = hist[b * NBR + blockIdx.x];
  for (int b = tid; b < NB * 8; b += 256) reinterpret_cast<u32*>(s_wh)[b] = 0;
  __syncthreads();
  const int M = (int)ctr[CTR_M];
  const u64 lowmask = (1ULL << lane) - 1ULL;
  const int base = blockIdx.x * 16384;
  for (int r = 0; r < 16; ++r) {
    int rbase = base + r * 1024;
    if (rbase >= M) break;                 // uniform across block
    u64 v[4]; u32 d4[4]; u32 lr4[4]; u32 cnt4[4]; bool act[4];
    #pragma unroll
    for (int j = 0; j < 4; ++j) {
      int ib = rbase + (wid * 4 + j) * 64 + lane;
      act[j] = ib < M;
      v[j] = act[j] ? src[ib] : 0ULL;
      d4[j] = (u32)(v[j] >> shift) & (u32)(NB - 1);
    }
    #pragma unroll
    for (int j = 0; j < 4; ++j) {
      u32 d = d4[j];
      u64 mask = __ballot(act[j]);
      for (int b = 0; b < nbits; ++b) {
        u64 bal = __ballot(act[j] && ((d >> b) & 1u));
        mask &= ((d >> b) & 1u) ? bal : ~bal;
      }
      lr4[j] = (u32)__popcll(mask & lowmask);
      cnt4[j] = (u32)__popcll(mask);
      if (act[j] && lr4[j] == 0)
        s_wh[d * 16 + (wid * 4 + j)] = (u16)cnt4[j];
    }
    __syncthreads();
    #pragma unroll
    for (int j = 0; j < 4; ++j) {
      if (!act[j]) continue;
      u32 d = d4[j];
      int slot = wid * 4 + j;
      const u64* pw = reinterpret_cast<const u64*>(&s_wh[d * 16]);
      u32 pref = hsum16(pw[0], slot) + hsum16(pw[1], slot - 4) +
                 hsum16(pw[2], slot - 8) + hsum16(pw[3], slot - 12);
      dst[s_gbase[d] + pref + lr4[j]] = v[j];
    }
    __syncthreads();
    #pragma unroll
    for (int j = 0; j < 4; ++j) {
      if (act[j] && lr4[j] == 0) {
        atomicAdd(&s_gbase[d4[j]], cnt4[j]);
        s_wh[d4[j] * 16 + (wid * 4 + j)] = 0;
      }
    }
    __syncthreads();
  }
}

// ---------------- unique-run head counts per block (1024 items/block) ----------------
__global__ void __launch_bounds__(256) k_headcount(
    const u64* __restrict__ S, const u32* __restrict__ ctr, u32* __restrict__ bsE)
{
  const int tid = threadIdx.x;
  const int M = (int)ctr[CTR_M];
  const int base = blockIdx.x * 1024 + tid * 4;
  u32 c = 0;
  u64 prev = (base > 0 && base < M) ? (S[base - 1] >> 24) : 0ULL;
  #pragma unroll
  for (int j = 0; j < 4; ++j) {
    int i = base + j;
    if (i < M) {
      u64 k = S[i] >> 24;
      c += ((i == 0) || (k != prev)) ? 1u : 0u;
      prev = k;
    }
  }
  __shared__ u32 sh[256];
  sh[tid] = c;
  __syncthreads();
  for (int d = 128; d > 0; d >>= 1) {
    if (tid < d) sh[tid] += sh[tid + d];
    __syncthreads();
  }
  if (tid == 0) bsE[blockIdx.x] = sh[0];
}

// ---- assign ids (4 items/thread): unique keys + coalesced pairs + fused hist ----
__global__ void __launch_bounds__(256) k_assign(
    const u64* __restrict__ S, const u32* __restrict__ ctr,
    const u32* __restrict__ bsE, u64* __restrict__ stage,
    u32* __restrict__ hist, int NBR, u64* __restrict__ edgekeys)
{
  const int tid = threadIdx.x;
  const int M = (int)ctr[CTR_M];
  const int base = blockIdx.x * 1024 + tid * 4;
  __shared__ u32 s_h[256];
  __shared__ u32 sh[256];
  s_h[tid] = 0;
  u64 v[4]; bool hd[4];
  u32 c = 0;
  u64 prev = (base > 0 && base < M) ? (S[base - 1] >> 24) : 0ULL;
  #pragma unroll
  for (int j = 0; j < 4; ++j) {
    int i = base + j;
    v[j] = (i < M) ? S[i] : 0ULL;
    u64 k = v[j] >> 24;
    hd[j] = (i < M) && ((i == 0) || (k != prev));
    if (i < M) prev = k;
    c += hd[j] ? 1u : 0u;
  }
  sh[tid] = c;
  __syncthreads();
  for (int d = 1; d < 256; d <<= 1) {
    u32 t = (tid >= d) ? sh[tid - d] : 0u;
    __syncthreads();
    sh[tid] += t;
    __syncthreads();
  }
  u32 run = bsE[blockIdx.x] + sh[tid] - c;
  #pragma unroll
  for (int j = 0; j < 4; ++j) {
    int i = base + j;
    if (i < M) {
      run += hd[j] ? 1u : 0u;
      u32 id = run - 1u;
      if (hd[j]) edgekeys[id] = v[j] >> 24;
      u32 pay = (u32)(v[j] & 0xFFFFFFULL);
      stage[i] = ((u64)pay << 24) | (u64)id;
      atomicAdd(&s_h[(pay >> 16) & 255u], 1u);
    }
  }
  __syncthreads();
  if (s_h[tid]) atomicAdd(&hist[tid * NBR + (blockIdx.x >> 4)], s_h[tid]);
}

// ---- deliver: edge_ids[payload] = id (payload-bucketed for L2 locality) ----
__global__ void __launch_bounds__(256) k_deliver(
    const u64* __restrict__ D, const u32* __restrict__ ctr,
    int* __restrict__ edge_ids)
{
  int i = blockIdx.x * 256 + threadIdx.x;
  if (i >= (int)ctr[CTR_M]) return;
  u64 c = D[i];
  edge_ids[(u32)(c >> 24)] = (int)(c & 0xFFFFFFULL);
}

// ---- rank scan over flag bytes -> bwr (low32 = bits, high32 = wordrank) ----
__global__ void __launch_bounds__(1024) k_scanbits(
    const u32* __restrict__ flag32, u64* __restrict__ bwr,
    int W, u32* __restrict__ ctr)
{
  __shared__ u32 shtmp[16];
  const int tid = threadIdx.x;
  u32 carry = 0;
  for (int start = 0; start < W; start += 1024) {
    int w = start + tid;
    u32 bits = 0;
    if (w < W) {
      #pragma unroll
      for (int k = 0; k < 8; ++k) {
        u32 fo = flag32[w * 8 + k];
        u32 nib = (fo & 1u) | ((fo >> 7) & 2u) | ((fo >> 14) & 4u) | ((fo >> 21) & 8u);
        bits |= nib << (4 * k);
      }
    }
    u32 c = (u32)__popc(bits);
    u32 total;
    u32 incl = block_scan_incl_1024(c, shtmp, total);
    if (w < W) bwr[w] = (u64)bits | ((u64)(carry + incl - c) << 32);
    carry += total;
    __syncthreads();
  }
  if (tid == 0) {
    ctr[CTR_U] = carry;
    ctr[CTR_OUT1] = 3u * (carry + ctr[CTR_E]);
  }
}

// ---------------- output 0a: original vertices ----------------
__global__ void __launch_bounds__(256) k_out0_orig(
    const u64* __restrict__ bwr, const float* __restrict__ pos,
    int N, float* __restrict__ out)
{
  int id = blockIdx.x * 256 + threadIdx.x;
  if (id >= N) return;
  u64 bw = bwr[(u32)id >> 5];
  u32 bits = (u32)bw;
  if (!((bits >> (id & 31)) & 1u)) return;
  u32 j = (u32)(bw >> 32) + (u32)__popc(bits & ((1u << (id & 31)) - 1u));
  size_t o = (size_t)3 * j;
  out[o] = pos[3 * id]; out[o + 1] = pos[3 * id + 1]; out[o + 2] = pos[3 * id + 2];
}

// ---------------- output 0b: interpolated edge vertices ----------------
__global__ void __launch_bounds__(256) k_out0_edge(
    const u64* __restrict__ edgekeys, const float* __restrict__ pos,
    const float* __restrict__ sdf, const u32* __restrict__ ctr,
    float* __restrict__ out)
{
  int e = blockIdx.x * 256 + threadIdx.x;
  if (e >= (int)ctr[CTR_E]) return;
  u64 k = edgekeys[e];
  int a = (int)(k >> 19);
  int b = (int)(k & 0x7FFFFULL);
  float sa = sdf[a], sb = sdf[b];
  float inv = 1.0f / (sa - sb);
  float wa = -sb * inv, wb = sa * inv;
  u32 j = ctr[CTR_U] + (u32)e;
  size_t o = (size_t)3 * j;
  out[o]     = pos[3 * a] * wa + pos[3 * b] * wb;
  out[o + 1] = pos[3 * a + 1] * wa + pos[3 * b + 1] * wb;
  out[o + 2] = pos[3 * a + 2] * wa + pos[3 * b + 2] * wb;
}

// ---------------- output 1: tets = rank(ids), one 16B store per row ----------------
__global__ void __launch_bounds__(256) k_out1(
    const int* __restrict__ idx, const u8* __restrict__ tetidx,
    const int* __restrict__ edge_ids, const int* __restrict__ rowbase,
    const u64* __restrict__ bwr, const u32* __restrict__ ctr,
    int F, int N, float* __restrict__ out)
{
  int f = blockIdx.x * 256 + threadIdx.x;
  if (f >= F) return;
  u32 ti = tetidx[f];
  if (ti == 0) return;
  int4 v = reinterpret_cast<const int4*>(idx)[f];
  int pc = __popc(ti);
  int nt = (pc == 1 || pc == 4) ? 1 : 3;
  u64 row = TETPACK[ti];
  u32 obase = ctr[CTR_OUT1];
  u32 U0 = ctr[CTR_U];
  int rb = rowbase[f];
  float cr[4] = {0.f, 0.f, 0.f, 0.f};
  const int ids[4] = {v.x, v.y, v.z, v.w};
  #pragma unroll
  for (int c = 0; c < 4; ++c) {
    if ((ti >> c) & 1u) {
      int id = ids[c];
      u64 bw = bwr[(u32)id >> 5];
      cr[c] = (float)((u32)(bw >> 32) + (u32)__popc((u32)bw & ((1u << (id & 31)) - 1u)));
    }
  }
  const bool al16 = (obase & 3u) == 0u;
  float* outp = out + (size_t)obase + (size_t)rb * 4;
  for (int t = 0; t < nt; ++t) {
    u32 quad = (u32)(row >> (16 * t)) & 0xFFFFu;
    float o[4];
    #pragma unroll
    for (int k = 0; k < 4; ++k) {
      u32 e = (quad >> (4 * k)) & 15u;
      o[k] = (e < 4u) ? cr[e] : (float)(U0 + (u32)edge_ids[f * 6 + (int)(e - 4u)]);
    }
    if (al16) {
      *reinterpret_cast<float4*>(outp + (size_t)t * 4) =
          make_float4(o[0], o[1], o[2], o[3]);
    } else {
      __builtin_memcpy(outp + (size_t)t * 4, o, 16);
    }
  }
}

extern "C" void kernel_launch(void* const* d_in, const int* in_sizes, int n_in,
                              void* d_out, int out_size, void* d_ws, size_t ws_size,
                              hipStream_t stream)
{
  const float* verts  = (const float*)d_in[0];
  const float* deform = (const float*)d_in[1];
  const float* sdf    = (const float*)d_in[2];
  const int* indices  = (const int*)d_in[3];
  const int* grptr    = (const int*)d_in[4];
  const int N = in_sizes[2];
  const int F = in_sizes[3] / 4;
  const int MMAX = 4 * F;                      // <=4 crossing edges per tet
  const int NBF = (F + 1023) / 1024;
  const int NBR = (MMAX + 16383) / 16384;      // radix blocks (16K items each)
  const int NBA = (MMAX + 1023) / 1024;        // headcount/assign blocks
  const int W = (N + 31) / 32;                 // flag bitmap words

  char* p = (char*)d_ws;
  auto take = [&](size_t bytes) {
    char* r = p;
    p += (bytes + 255) & ~(size_t)255;
    return r;
  };
  u32* ctr       = (u32*)take(256);
  u32* gh        = (u32*)take(3328 * 4);
  u64* A         = (u64*)take((size_t)MMAX * 8);
  u64* B         = (u64*)take((size_t)MMAX * 8);
  u64* EK        = (u64*)take((size_t)MMAX * 8);
  int* edge_ids  = (int*)take((size_t)F * 6 * 4);
  float* pos     = (float*)take((size_t)N * 3 * 4);
  int* rowbase   = (int*)take((size_t)F * 4);
  u8* tetidx     = (u8*)take((size_t)F);
  u32* hist      = (u32*)take((size_t)NBR * 1024 * 4);
  u32* bsE       = (u32*)take((size_t)NBA * 4);
  u64* bsF       = (u64*)take((size_t)NBF * 8);
  u8* flag       = (u8*)take((size_t)W * 32);
  u32* occw      = (u32*)take((size_t)W * 4);
  u64* bwr       = (u64*)take((size_t)W * 8);
  if ((size_t)(p - (char*)d_ws) > ws_size) return;  // insufficient scratch

  hipMemsetAsync(ctr, 0, 256, stream);
  hipMemsetAsync(gh, 0, 3328 * 4, stream);
  hipMemsetAsync(flag, 0, (size_t)W * 32, stream);

  float* out = (float*)d_out;

  k_pos<<<(N * 3 + 255) / 256, 256, 0, stream>>>(verts, deform, sdf, grptr,
                                                 pos, occw, N, N * 3);
  k_classify<<<NBF, 256, 0, stream>>>(indices, occw, F, A, ctr, bsF, tetidx, flag);
  k_scanF<<<1, 1024, 0, stream>>>(bsF, NBF, ctr);
  k_rowbase<<<NBF, 256, 0, stream>>>(tetidx, bsF, ctr, F, rowbase);

  // one read of A -> all 5 digit-total segments, then scan each
  k_hist4<<<2048, 256, 0, stream>>>(A, ctr, gh);
  k_scan4<<<1, 1024, 0, stream>>>(gh);

  // 4-pass LSD radix over key bits 24..61: digits {10,10,9,9}
  const int shifts[4] = {24, 34, 44, 53};
  const int nbitsv[4] = {10, 10, 9, 9};
  const int ghoff[4]  = {0, 1024, 2048, 2560};
  u64* src = A; u64* dst = B;
  for (int pass = 0; pass < 4; ++pass) {
    k_hist<<<NBR, 256, 0, stream>>>(src, ctr, shifts[pass], nbitsv[pass], hist, NBR);
    k_rowscan<<<(1 << nbitsv[pass]), 256, 0, stream>>>(hist, NBR, gh + ghoff[pass]);
    k_scatter<<<NBR, 256, 0, stream>>>(src, dst, ctr, shifts[pass], nbitsv[pass], hist, NBR);
    u64* t = src; src = dst; dst = t;
  }
  // sorted result in src (==A after 4 passes); dst (==B) free -> pair staging
  const u64* S = src;
  u64* stage = dst;

  k_headcount<<<NBA, 256, 0, stream>>>(S, ctr, bsE);
  k_scan_u32<<<1, 1024, 0, stream>>>(bsE, NBA, ctr, CTR_E);
  hipMemsetAsync(hist, 0, (size_t)NBR * 256 * 4, stream);
  k_assign<<<NBA, 256, 0, stream>>>(S, ctr, bsE, stage, hist, NBR, EK);
  // partition pairs by payload>>16 (256KB edge_ids windows) then deliver
  k_rowscan<<<256, 256, 0, stream>>>(hist, NBR, gh + 3072);
  k_scatter<<<NBR, 256, 0, stream>>>(stage, (u64*)S, ctr, 40, 8, hist, NBR);
  k_deliver<<<(MMAX + 255) / 256, 256, 0, stream>>>(S, ctr, edge_ids);

  k_scanbits<<<1, 1024, 0, stream>>>((const u32*)flag, bwr, W, ctr);
  k_out0_orig<<<(N + 255) / 256, 256, 0, stream>>>(bwr, pos, N, out);
  k_out0_edge<<<(MMAX + 255) / 256, 256, 0, stream>>>(EK, pos, sdf, ctr, out);
  k_out1<<<(F + 255) / 256, 256, 0, stream>>>(indices, tetidx, edge_ids, rowbase,
                                              bwr, ctr, F, N, out);
}

// Round 10
// 759.326 us; speedup vs baseline: 1.7089x; 1.0911x over previous
//
#include <hip/hip_runtime.h>
#include <stdint.h>

typedef unsigned int u32;
typedef unsigned long long u64;
typedef unsigned short u16;
typedef unsigned char u8;

#define CTR_M 0
#define CTR_E 1
#define CTR_C1 2
#define CTR_C3 3
#define CTR_CI 4
#define CTR_T 5
#define CTR_U 6
#define CTR_OUT1 7

// TET_TABLE rows packed 4 bits/entry (LSB-first), -1 -> 0xF (never read: row
// count limited by num_tets). Row 15 == [0,1,2,3] doubles as the inner-tet row.
__device__ const u64 TETPACK[16] = {
  0xFFFFFFFFFFFFULL,
  0xFFFFFFFF6540ULL,
  0xFFFFFFFF7841ULL,
  0x610567156817ULL,
  0xFFFFFFFF9752ULL,
  0x290767097604ULL,
  0x921549158914ULL,
  0x286921682106ULL,
  0xFFFFFFFF8963ULL,
  0x398538058405ULL,
  0x376936743741ULL,
  0x971539153510ULL,
  0x875385637325ULL,
  0x273078308740ULL,
  0x653452343214ULL,
  0xFFFFFFFF3210ULL
};

// ---- pos = verts + tanh(deform)/grid_res ; also occ bitmap (sdf>0) ----
__global__ void __launch_bounds__(256) k_pos(
    const float* __restrict__ verts, const float* __restrict__ deform,
    const float* __restrict__ sdf, const int* __restrict__ grptr,
    float* __restrict__ pos, u32* __restrict__ occw, int N, int n3)
{
  int i = blockIdx.x * 256 + threadIdx.x;
  if (i < n3) {
    float inv = 1.0f / (float)grptr[0];
    pos[i] = verts[i] + tanhf(deform[i]) * inv;
  }
  const int NOCC = (N + 1023) / 1024;
  if (blockIdx.x < NOCC) {
    __shared__ u32 s_nib[256];
    const int tid = threadIdx.x;
    int base = blockIdx.x * 1024 + tid * 4;
    u32 nib = 0;
    if (base + 3 < N) {
      float4 s = *reinterpret_cast<const float4*>(sdf + base);
      nib = (s.x > 0.0f ? 1u : 0u) | (s.y > 0.0f ? 2u : 0u) |
            (s.z > 0.0f ? 4u : 0u) | (s.w > 0.0f ? 8u : 0u);
    } else {
      for (int k = 0; k < 4; ++k)
        if (base + k < N) nib |= (sdf[base + k] > 0.0f ? 1u : 0u) << k;
    }
    s_nib[tid] = nib;
    __syncthreads();
    if (tid < 32) {
      u32 w = 0;
      #pragma unroll
      for (int j = 0; j < 8; ++j) w |= s_nib[tid * 8 + j] << (4 * j);
      int wi = blockIdx.x * 32 + tid;
      if (wi < (N + 31) / 32) occw[wi] = w;
    }
  }
}

// ---- classify tets, emit crossing-edge records, flag inside verts ----
__global__ void __launch_bounds__(256) k_classify(
    const int* __restrict__ idx, const u32* __restrict__ occw, int F,
    u64* __restrict__ A, u32* __restrict__ ctr,
    u64* __restrict__ bsF, u8* __restrict__ tetidx, u8* __restrict__ flag)
{
  const int tid = threadIdx.x;
  const int lane = tid & 63;
  const int wid = tid >> 6;
  const int base = blockIdx.x * 1024 + tid * 4;
  u32 tis4 = 0;
  u32 cms[4];
  int4 vs[4];
  u64 cnt = 0;
  u32 ec = 0;
  #pragma unroll
  for (int it = 0; it < 4; ++it) {
    const int f = base + it;
    u32 ti = 0, cm = 0;
    int4 v = make_int4(0, 0, 0, 0);
    if (f < F) {
      v = reinterpret_cast<const int4*>(idx)[f];
      u32 b0 = (occw[(u32)v.x >> 5] >> (v.x & 31)) & 1u;
      u32 b1 = (occw[(u32)v.y >> 5] >> (v.y & 31)) & 1u;
      u32 b2 = (occw[(u32)v.z >> 5] >> (v.z & 31)) & 1u;
      u32 b3 = (occw[(u32)v.w >> 5] >> (v.w & 31)) & 1u;
      if (b0) flag[v.x] = 1;
      if (b1) flag[v.y] = 1;
      if (b2) flag[v.z] = 1;
      if (b3) flag[v.w] = 1;
      ti = b0 | (b1 << 1) | (b2 << 2) | (b3 << 3);
      cm  = (b0 ^ b1);
      cm |= (b0 ^ b2) << 1;
      cm |= (b0 ^ b3) << 2;
      cm |= (b1 ^ b2) << 3;
      cm |= (b1 ^ b3) << 4;
      cm |= (b2 ^ b3) << 5;
      int pc = __popc(ti);
      if (pc == 1) cnt += 1ULL;
      else if (pc == 2 || pc == 3) cnt += (1ULL << 21);
      else if (pc == 4) cnt += (1ULL << 42);
    }
    vs[it] = v;
    cms[it] = cm;
    tis4 |= ti << (8 * it);
    ec += __popc(cm);
  }
  u32 incl = ec;
  #pragma unroll
  for (int d = 1; d < 64; d <<= 1) {
    u32 t = __shfl_up(incl, d);
    if (lane >= d) incl += t;
  }
  u32 excl = incl - ec;
  __shared__ u32 s_wtot[4];
  __shared__ u32 s_base;
  if (lane == 63) s_wtot[wid] = incl;
  __syncthreads();
  if (tid == 0) {
    u32 t0 = s_wtot[0], t1 = s_wtot[1], t2 = s_wtot[2], t3 = s_wtot[3];
    u32 tot = t0 + t1 + t2 + t3;
    s_base = tot ? atomicAdd(&ctr[CTR_M], tot) : 0u;
    s_wtot[0] = 0; s_wtot[1] = t0; s_wtot[2] = t0 + t1; s_wtot[3] = t0 + t1 + t2;
  }
  __syncthreads();
  u32 w = s_base + s_wtot[wid] + excl;
  #pragma unroll
  for (int it = 0; it < 4; ++it) {
    u32 cm = cms[it];
    if (!cm) continue;
    const int f = base + it;
    const int va[6] = {vs[it].x, vs[it].x, vs[it].x, vs[it].y, vs[it].y, vs[it].z};
    const int vb[6] = {vs[it].y, vs[it].z, vs[it].w, vs[it].z, vs[it].w, vs[it].w};
    #pragma unroll
    for (int s = 0; s < 6; ++s) {
      if ((cm >> s) & 1u) {
        int a = va[s], b = vb[s];
        int mn = min(a, b), mx = max(a, b);
        u64 key = ((u64)(u32)mn << 19) | (u64)(u32)mx;
        A[w++] = (key << 24) | (u64)(u32)(f * 6 + s);
      }
    }
  }
  if (base < F) {
    if (base + 3 < F) {
      *reinterpret_cast<u32*>(tetidx + base) = tis4;
    } else {
      for (int it = 0; it < 4; ++it)
        if (base + it < F) tetidx[base + it] = (u8)((tis4 >> (8 * it)) & 255u);
    }
  }
  __shared__ u64 sh[256];
  sh[tid] = cnt;
  __syncthreads();
  for (int d = 128; d > 0; d >>= 1) {
    if (tid < d) sh[tid] += sh[tid + d];
    __syncthreads();
  }
  if (tid == 0) bsF[blockIdx.x] = sh[0];
}

// ---- all-pass digit histograms in ONE read of A (order-invariant) ----
// segments: 0:[256] s24 | 256:[256] s32 | 512:[256] s40 | 768:[256] s48 |
//           1024:[64] s56 | 1088:[256] partition ((v>>16)&255)
__global__ void __launch_bounds__(256) k_hist4(
    const u64* __restrict__ A, const u32* __restrict__ ctr, u32* __restrict__ gh)
{
  __shared__ u32 sh[1344];
  const int tid = threadIdx.x;
  for (int b = tid; b < 1344; b += 256) sh[b] = 0;
  __syncthreads();
  const int M = (int)ctr[CTR_M];
  for (int i = blockIdx.x * 256 + tid; i < M; i += gridDim.x * 256) {
    u64 v = A[i];
    atomicAdd(&sh[        (u32)(v >> 24) & 255u], 1u);
    atomicAdd(&sh[ 256 + ((u32)(v >> 32) & 255u)], 1u);
    atomicAdd(&sh[ 512 + ((u32)(v >> 40) & 255u)], 1u);
    atomicAdd(&sh[ 768 + ((u32)(v >> 48) & 255u)], 1u);
    atomicAdd(&sh[1024 + ((u32)(v >> 56) &  63u)], 1u);
    atomicAdd(&sh[1088 + ((u32)(v >> 16) & 255u)], 1u);
  }
  __syncthreads();
  for (int b = tid; b < 1344; b += 256) if (sh[b]) atomicAdd(&gh[b], sh[b]);
}

// ---- exclusive scan of each segment of gh (single launch, 256 threads) ----
__global__ void __launch_bounds__(256) k_scan4(u32* __restrict__ gh)
{
  __shared__ u32 sh[256];
  const int tid = threadIdx.x;
  const int off[6] = {0, 256, 512, 768, 1024, 1088};
  const int len[6] = {256, 256, 256, 256, 64, 256};
  for (int s = 0; s < 6; ++s) {
    u32 v = (tid < len[s]) ? gh[off[s] + tid] : 0u;
    sh[tid] = v;
    __syncthreads();
    for (int d = 1; d < 256; d <<= 1) {
      u32 t = (tid >= d) ? sh[tid - d] : 0u;
      __syncthreads();
      sh[tid] += t;
      __syncthreads();
    }
    if (tid < len[s]) gh[off[s] + tid] = sh[tid] - v;
    __syncthreads();
  }
}

// ---- per-digit row scan: hist[d][0..NBR) -> global exclusive bases ----
__global__ void __launch_bounds__(256) k_rowscan(
    u32* __restrict__ hist, int NBR, const u32* __restrict__ gh)
{
  const int d = blockIdx.x;
  u32* row = hist + (size_t)d * NBR;
  const int tid = threadIdx.x;
  __shared__ u32 sh[256];
  u32 carry = gh[d];
  for (int start = 0; start < NBR; start += 256) {
    int i = start + tid;
    u32 v = (i < NBR) ? row[i] : 0u;
    sh[tid] = v;
    __syncthreads();
    for (int dd = 1; dd < 256; dd <<= 1) {
      u32 t = (tid >= dd) ? sh[tid - dd] : 0u;
      __syncthreads();
      sh[tid] += t;
      __syncthreads();
    }
    if (i < NBR) row[i] = carry + sh[tid] - v;
    u32 tot = sh[255];
    __syncthreads();
    carry += tot;
  }
}

// ---- exclusive scan of packed per-block category counts (single block) ----
__global__ void __launch_bounds__(1024) k_scanF(
    u64* __restrict__ bsF, int nb, u32* __restrict__ ctr)
{
  __shared__ u64 sh[1024];
  const int tid = threadIdx.x;
  u64 carry = 0;
  for (int start = 0; start < nb; start += 1024) {
    int i = start + tid;
    u64 v = (i < nb) ? bsF[i] : 0ULL;
    sh[tid] = v;
    __syncthreads();
    for (int d = 1; d < 1024; d <<= 1) {
      u64 t = (tid >= d) ? sh[tid - d] : 0ULL;
      __syncthreads();
      sh[tid] += t;
      __syncthreads();
    }
    if (i < nb) bsF[i] = carry + sh[tid] - v;
    carry += sh[1023];
    __syncthreads();
  }
  if (tid == 0) {
    u32 c1 = (u32)(carry & 0x1FFFFFULL);
    u32 c3 = (u32)((carry >> 21) & 0x1FFFFFULL);
    u32 ci = (u32)((carry >> 42) & 0x1FFFFFULL);
    ctr[CTR_C1] = c1; ctr[CTR_C3] = c3; ctr[CTR_CI] = ci;
    ctr[CTR_T] = c1 + 3u * c3 + ci;
  }
}

// ---- per-tet output row base (mt1 region | mt3 region | inner region) ----
__global__ void __launch_bounds__(256) k_rowbase(
    const u8* __restrict__ tetidx, const u64* __restrict__ bsF,
    const u32* __restrict__ ctr, int F, int* __restrict__ rowbase)
{
  const int tid = threadIdx.x;
  const int base = blockIdx.x * 1024 + tid * 4;
  u32 tis[4];
  u64 cnt = 0;
  #pragma unroll
  for (int it = 0; it < 4; ++it) {
    int f = base + it;
    u32 ti = (f < F) ? (u32)tetidx[f] : 0u;
    tis[it] = ti;
    int pc = __popc(ti);
    if (ti) {
      if (pc == 1) cnt += 1ULL;
      else if (pc <= 3) cnt += (1ULL << 21);
      else cnt += (1ULL << 42);
    }
  }
  __shared__ u64 sh[256];
  sh[tid] = cnt;
  __syncthreads();
  for (int d = 1; d < 256; d <<= 1) {
    u64 t = (tid >= d) ? sh[tid - d] : 0ULL;
    __syncthreads();
    sh[tid] += t;
    __syncthreads();
  }
  u64 off = bsF[blockIdx.x] + (sh[tid] - cnt);
  u32 o1 = (u32)(off & 0x1FFFFFULL);
  u32 o3 = (u32)((off >> 21) & 0x1FFFFFULL);
  u32 oi = (u32)((off >> 42) & 0x1FFFFFULL);
  const u32 C1 = ctr[CTR_C1], C3 = ctr[CTR_C3];
  int rb[4];
  #pragma unroll
  for (int it = 0; it < 4; ++it) {
    u32 ti = tis[it];
    int pc = __popc(ti);
    int r = -1;
    if (ti == 15u) { r = (int)(C1 + 3u * C3 + oi); ++oi; }
    else if (ti) {
      if (pc == 1) { r = (int)o1; ++o1; }
      else { r = (int)(C1 + 3u * o3); ++o3; }
    }
    rb[it] = r;
  }
  if (base + 3 < F) {
    reinterpret_cast<int4*>(rowbase)[base >> 2] = make_int4(rb[0], rb[1], rb[2], rb[3]);
  } else {
    for (int it = 0; it < 4; ++it)
      if (base + it < F) rowbase[base + it] = rb[it];
  }
}

// ---------------- radix sort: per-block histogram (16K items/block) ----------------
__global__ void __launch_bounds__(256) k_hist(
    const u64* __restrict__ src, const u32* __restrict__ ctr,
    int shift, int nbits, u32* __restrict__ hist, int NBR)
{
  const int NB = 1 << nbits;
  __shared__ u32 sh[256];
  const int tid = threadIdx.x;
  if (tid < NB) sh[tid] = 0;
  __syncthreads();
  const int M = (int)ctr[CTR_M];
  const int base = blockIdx.x * 16384;
  for (int r = 0; r < 16; ++r) {
    int rbase = base + r * 1024;
    if (rbase >= M) break;
    int ib = rbase + tid * 4;
    #pragma unroll
    for (int j = 0; j < 4; ++j) {
      if (ib + j < M) {
        u32 d = (u32)(src[ib + j] >> shift) & (u32)(NB - 1);
        atomicAdd(&sh[d], 1u);
      }
    }
  }
  __syncthreads();
  if (tid < NB) hist[tid * NBR + blockIdx.x] = sh[tid];
}

// ---- single-block scan (kept for small arrays: bsE) ----
__device__ __forceinline__ u32 block_scan_incl_1024(u32 x, u32* shtmp, u32& total)
{
  const int lane = threadIdx.x & 63;
  const int wid = threadIdx.x >> 6;
  u32 incl = x;
  #pragma unroll
  for (int d = 1; d < 64; d <<= 1) {
    u32 t = __shfl_up(incl, d);
    if (lane >= d) incl += t;
  }
  if (lane == 63) shtmp[wid] = incl;
  __syncthreads();
  if (wid == 0) {
    u32 w = (lane < 16) ? shtmp[lane] : 0u;
    #pragma unroll
    for (int d = 1; d < 16; d <<= 1) {
      u32 t = __shfl_up(w, d);
      if (lane >= d) w += t;
    }
    if (lane < 16) shtmp[lane] = w;
  }
  __syncthreads();
  u32 waveoff = (wid > 0) ? shtmp[wid - 1] : 0u;
  total = shtmp[15];
  return waveoff + incl;
}

__global__ void __launch_bounds__(1024) k_scan_u32(
    u32* __restrict__ data, int L, u32* __restrict__ ctr, int slot)
{
  __shared__ u32 shtmp[16];
  const int tid = threadIdx.x;
  u32 carry = 0;
  for (int start = 0; start < L; start += 4096) {
    u32 v[4]; u32 s = 0;
    #pragma unroll
    for (int j = 0; j < 4; ++j) {
      int i = start + tid * 4 + j;
      v[j] = (i < L) ? data[i] : 0u;
      s += v[j];
    }
    u32 total;
    u32 incl = block_scan_incl_1024(s, shtmp, total);
    u32 run = carry + incl - s;
    #pragma unroll
    for (int j = 0; j < 4; ++j) {
      int i = start + tid * 4 + j;
      if (i < L) data[i] = run;
      run += v[j];
    }
    carry += total;
    __syncthreads();
  }
  if (slot >= 0 && tid == 0) ctr[slot] = carry;
}

// ------- radix scatter: stable, race-free, [slot][digit] + per-digit prefix -------
// Phases per 1024-item round:
//   A: ballot-rank; lowest active lane of each (slot,digit) writes count
//   B: thread d (d<NB) converts its 16 slot-counts to exclusive prefixes
//   C: scatter: off = s_gbase[d] + s_wh[slot][d] + lane_rank  (read-only)
//   D: thread d: s_gbase[d] += round total; re-zero its column
__device__ __forceinline__ void scatter_body(
    const u64* __restrict__ src, u64* __restrict__ dst,
    const u32* __restrict__ ctr, int shift, int NBITS,
    const u32* __restrict__ hist, int NBR,
    u32* s_gbase, u16* s_wh)
{
  const int NB = 1 << NBITS;
  const int tid = threadIdx.x;
  const int lane = tid & 63;
  const int wid = tid >> 6;
  if (tid < NB) s_gbase[tid] = hist[tid * NBR + blockIdx.x];
  for (int b = tid; b < NB * 8; b += 256) reinterpret_cast<u32*>(s_wh)[b] = 0;
  __syncthreads();
  const int M = (int)ctr[CTR_M];
  const u64 lowmask = (1ULL << lane) - 1ULL;
  const int base = blockIdx.x * 16384;
  for (int r = 0; r < 16; ++r) {
    int rbase = base + r * 1024;
    if (rbase >= M) break;                 // uniform across block
    u64 v[4]; u32 d4[4]; u32 lr4[4]; bool act[4];
    #pragma unroll
    for (int j = 0; j < 4; ++j) {
      int ib = rbase + (wid * 4 + j) * 64 + lane;
      act[j] = ib < M;
      v[j] = act[j] ? src[ib] : 0ULL;
      d4[j] = (u32)(v[j] >> shift) & (u32)(NB - 1);
    }
    // Phase A
    #pragma unroll
    for (int j = 0; j < 4; ++j) {
      u32 d = d4[j];
      u64 mask = __ballot(act[j]);
      for (int b = 0; b < NBITS; ++b) {
        u64 bal = __ballot(act[j] && ((d >> b) & 1u));
        mask &= ((d >> b) & 1u) ? bal : ~bal;
      }
      lr4[j] = (u32)__popcll(mask & lowmask);
      if (act[j] && lr4[j] == 0)
        s_wh[(wid * 4 + j) * NB + d] = (u16)__popcll(mask);
    }
    __syncthreads();
    // Phase B: per-digit exclusive prefix over 16 slots (thread-exclusive)
    u32 mytot = 0;
    if (tid < NB) {
      u32 run = 0;
      #pragma unroll
      for (int s = 0; s < 16; ++s) {
        u32 c = (u32)s_wh[s * NB + tid];
        s_wh[s * NB + tid] = (u16)run;
        run += c;
      }
      mytot = run;
    }
    __syncthreads();
    // Phase C: scatter (read-only on s_gbase / s_wh)
    #pragma unroll
    for (int j = 0; j < 4; ++j) {
      if (!act[j]) continue;
      u32 d = d4[j];
      dst[s_gbase[d] + (u32)s_wh[(wid * 4 + j) * NB + d] + lr4[j]] = v[j];
    }
    __syncthreads();
    // Phase D: advance bases + re-zero (thread-exclusive per digit)
    if (tid < NB) {
      s_gbase[tid] += mytot;
      #pragma unroll
      for (int s = 0; s < 16; ++s) s_wh[s * NB + tid] = 0;
    }
    __syncthreads();
  }
}

__global__ void __launch_bounds__(256) k_scatter8(
    const u64* __restrict__ src, u64* __restrict__ dst,
    const u32* __restrict__ ctr, int shift,
    const u32* __restrict__ hist, int NBR)
{
  __shared__ u32 s_gbase[256];
  __shared__ u16 s_wh[16 * 256];
  scatter_body(src, dst, ctr, shift, 8, hist, NBR, s_gbase, s_wh);
}

__global__ void __launch_bounds__(256) k_scatter6(
    const u64* __restrict__ src, u64* __restrict__ dst,
    const u32* __restrict__ ctr, int shift,
    const u32* __restrict__ hist, int NBR)
{
  __shared__ u32 s_gbase[64];
  __shared__ u16 s_wh[16 * 64];
  scatter_body(src, dst, ctr, shift, 6, hist, NBR, s_gbase, s_wh);
}

// ---------------- unique-run head counts per block (1024 items/block) ----------------
__global__ void __launch_bounds__(256) k_headcount(
    const u64* __restrict__ S, const u32* __restrict__ ctr, u32* __restrict__ bsE)
{
  const int tid = threadIdx.x;
  const int M = (int)ctr[CTR_M];
  const int base = blockIdx.x * 1024 + tid * 4;
  u32 c = 0;
  u64 prev = (base > 0 && base < M) ? (S[base - 1] >> 24) : 0ULL;
  #pragma unroll
  for (int j = 0; j < 4; ++j) {
    int i = base + j;
    if (i < M) {
      u64 k = S[i] >> 24;
      c += ((i == 0) || (k != prev)) ? 1u : 0u;
      prev = k;
    }
  }
  __shared__ u32 sh[256];
  sh[tid] = c;
  __syncthreads();
  for (int d = 128; d > 0; d >>= 1) {
    if (tid < d) sh[tid] += sh[tid + d];
    __syncthreads();
  }
  if (tid == 0) bsE[blockIdx.x] = sh[0];
}

// ---- assign ids (4 items/thread): unique keys + coalesced pairs + fused hist ----
__global__ void __launch_bounds__(256) k_assign(
    const u64* __restrict__ S, const u32* __restrict__ ctr,
    const u32* __restrict__ bsE, u64* __restrict__ stage,
    u32* __restrict__ hist, int NBR, u64* __restrict__ edgekeys)
{
  const int tid = threadIdx.x;
  const int M = (int)ctr[CTR_M];
  const int base = blockIdx.x * 1024 + tid * 4;
  __shared__ u32 s_h[256];
  __shared__ u32 sh[256];
  s_h[tid] = 0;
  u64 v[4]; bool hd[4];
  u32 c = 0;
  u64 prev = (base > 0 && base < M) ? (S[base - 1] >> 24) : 0ULL;
  #pragma unroll
  for (int j = 0; j < 4; ++j) {
    int i = base + j;
    v[j] = (i < M) ? S[i] : 0ULL;
    u64 k = v[j] >> 24;
    hd[j] = (i < M) && ((i == 0) || (k != prev));
    if (i < M) prev = k;
    c += hd[j] ? 1u : 0u;
  }
  sh[tid] = c;
  __syncthreads();
  for (int d = 1; d < 256; d <<= 1) {
    u32 t = (tid >= d) ? sh[tid - d] : 0u;
    __syncthreads();
    sh[tid] += t;
    __syncthreads();
  }
  u32 run = bsE[blockIdx.x] + sh[tid] - c;
  #pragma unroll
  for (int j = 0; j < 4; ++j) {
    int i = base + j;
    if (i < M) {
      run += hd[j] ? 1u : 0u;
      u32 id = run - 1u;
      if (hd[j]) edgekeys[id] = v[j] >> 24;
      u32 pay = (u32)(v[j] & 0xFFFFFFULL);
      stage[i] = ((u64)pay << 24) | (u64)id;
      atomicAdd(&s_h[(pay >> 16) & 255u], 1u);
    }
  }
  __syncthreads();
  if (s_h[tid]) atomicAdd(&hist[tid * NBR + (blockIdx.x >> 4)], s_h[tid]);
}

// ---- deliver: edge_ids[payload] = id (payload-bucketed for L2 locality) ----
__global__ void __launch_bounds__(256) k_deliver(
    const u64* __restrict__ D, const u32* __restrict__ ctr,
    int* __restrict__ edge_ids)
{
  int i = blockIdx.x * 256 + threadIdx.x;
  if (i >= (int)ctr[CTR_M]) return;
  u64 c = D[i];
  edge_ids[(u32)(c >> 24)] = (int)(c & 0xFFFFFFULL);
}

// ---- rank scan over flag bytes -> bwr (low32 = bits, high32 = wordrank) ----
__global__ void __launch_bounds__(1024) k_scanbits(
    const u32* __restrict__ flag32, u64* __restrict__ bwr,
    int W, u32* __restrict__ ctr)
{
  __shared__ u32 shtmp[16];
  const int tid = threadIdx.x;
  u32 carry = 0;
  for (int start = 0; start < W; start += 1024) {
    int w = start + tid;
    u32 bits = 0;
    if (w < W) {
      #pragma unroll
      for (int k = 0; k < 8; ++k) {
        u32 fo = flag32[w * 8 + k];
        u32 nib = (fo & 1u) | ((fo >> 7) & 2u) | ((fo >> 14) & 4u) | ((fo >> 21) & 8u);
        bits |= nib << (4 * k);
      }
    }
    u32 c = (u32)__popc(bits);
    u32 total;
    u32 incl = block_scan_incl_1024(c, shtmp, total);
    if (w < W) bwr[w] = (u64)bits | ((u64)(carry + incl - c) << 32);
    carry += total;
    __syncthreads();
  }
  if (tid == 0) {
    ctr[CTR_U] = carry;
    ctr[CTR_OUT1] = 3u * (carry + ctr[CTR_E]);
  }
}

// ---------------- output 0a: original vertices ----------------
__global__ void __launch_bounds__(256) k_out0_orig(
    const u64* __restrict__ bwr, const float* __restrict__ pos,
    int N, float* __restrict__ out)
{
  int id = blockIdx.x * 256 + threadIdx.x;
  if (id >= N) return;
  u64 bw = bwr[(u32)id >> 5];
  u32 bits = (u32)bw;
  if (!((bits >> (id & 31)) & 1u)) return;
  u32 j = (u32)(bw >> 32) + (u32)__popc(bits & ((1u << (id & 31)) - 1u));
  size_t o = (size_t)3 * j;
  out[o] = pos[3 * id]; out[o + 1] = pos[3 * id + 1]; out[o + 2] = pos[3 * id + 2];
}

// ---------------- output 0b: interpolated edge vertices ----------------
__global__ void __launch_bounds__(256) k_out0_edge(
    const u64* __restrict__ edgekeys, const float* __restrict__ pos,
    const float* __restrict__ sdf, const u32* __restrict__ ctr,
    float* __restrict__ out)
{
  int e = blockIdx.x * 256 + threadIdx.x;
  if (e >= (int)ctr[CTR_E]) return;
  u64 k = edgekeys[e];
  int a = (int)(k >> 19);
  int b = (int)(k & 0x7FFFFULL);
  float sa = sdf[a], sb = sdf[b];
  float inv = 1.0f / (sa - sb);
  float wa = -sb * inv, wb = sa * inv;
  u32 j = ctr[CTR_U] + (u32)e;
  size_t o = (size_t)3 * j;
  out[o]     = pos[3 * a] * wa + pos[3 * b] * wb;
  out[o + 1] = pos[3 * a + 1] * wa + pos[3 * b + 1] * wb;
  out[o + 2] = pos[3 * a + 2] * wa + pos[3 * b + 2] * wb;
}

// ---------------- output 1: tets = rank(ids), one 16B store per row ----------------
__global__ void __launch_bounds__(256) k_out1(
    const int* __restrict__ idx, const u8* __restrict__ tetidx,
    const int* __restrict__ edge_ids, const int* __restrict__ rowbase,
    const u64* __restrict__ bwr, const u32* __restrict__ ctr,
    int F, int N, float* __restrict__ out)
{
  int f = blockIdx.x * 256 + threadIdx.x;
  if (f >= F) return;
  u32 ti = tetidx[f];
  if (ti == 0) return;
  int4 v = reinterpret_cast<const int4*>(idx)[f];
  int pc = __popc(ti);
  int nt = (pc == 1 || pc == 4) ? 1 : 3;
  u64 row = TETPACK[ti];
  u32 obase = ctr[CTR_OUT1];
  u32 U0 = ctr[CTR_U];
  int rb = rowbase[f];
  float cr[4] = {0.f, 0.f, 0.f, 0.f};
  const int ids[4] = {v.x, v.y, v.z, v.w};
  #pragma unroll
  for (int c = 0; c < 4; ++c) {
    if ((ti >> c) & 1u) {
      int id = ids[c];
      u64 bw = bwr[(u32)id >> 5];
      cr[c] = (float)((u32)(bw >> 32) + (u32)__popc((u32)bw & ((1u << (id & 31)) - 1u)));
    }
  }
  const bool al16 = (obase & 3u) == 0u;
  float* outp = out + (size_t)obase + (size_t)rb * 4;
  for (int t = 0; t < nt; ++t) {
    u32 quad = (u32)(row >> (16 * t)) & 0xFFFFu;
    float o[4];
    #pragma unroll
    for (int k = 0; k < 4; ++k) {
      u32 e = (quad >> (4 * k)) & 15u;
      o[k] = (e < 4u) ? cr[e] : (float)(U0 + (u32)edge_ids[f * 6 + (int)(e - 4u)]);
    }
    if (al16) {
      *reinterpret_cast<float4*>(outp + (size_t)t * 4) =
          make_float4(o[0], o[1], o[2], o[3]);
    } else {
      __builtin_memcpy(outp + (size_t)t * 4, o, 16);
    }
  }
}

extern "C" void kernel_launch(void* const* d_in, const int* in_sizes, int n_in,
                              void* d_out, int out_size, void* d_ws, size_t ws_size,
                              hipStream_t stream)
{
  const float* verts  = (const float*)d_in[0];
  const float* deform = (const float*)d_in[1];
  const float* sdf    = (const float*)d_in[2];
  const int* indices  = (const int*)d_in[3];
  const int* grptr    = (const int*)d_in[4];
  const int N = in_sizes[2];
  const int F = in_sizes[3] / 4;
  const int MMAX = 4 * F;                      // <=4 crossing edges per tet
  const int NBF = (F + 1023) / 1024;
  const int NBR = (MMAX + 16383) / 16384;      // radix blocks (16K items each)
  const int NBA = (MMAX + 1023) / 1024;        // headcount/assign blocks
  const int W = (N + 31) / 32;                 // flag bitmap words

  char* p = (char*)d_ws;
  auto take = [&](size_t bytes) {
    char* r = p;
    p += (bytes + 255) & ~(size_t)255;
    return r;
  };
  u32* ctr       = (u32*)take(256);
  u32* gh        = (u32*)take(1344 * 4);
  u64* A         = (u64*)take((size_t)MMAX * 8);
  u64* B         = (u64*)take((size_t)MMAX * 8);
  u64* EK        = (u64*)take((size_t)MMAX * 8);
  int* edge_ids  = (int*)take((size_t)F * 6 * 4);
  float* pos     = (float*)take((size_t)N * 3 * 4);
  int* rowbase   = (int*)take((size_t)F * 4);
  u8* tetidx     = (u8*)take((size_t)F);
  u32* hist      = (u32*)take((size_t)NBR * 256 * 4);
  u32* bsE       = (u32*)take((size_t)NBA * 4);
  u64* bsF       = (u64*)take((size_t)NBF * 8);
  u8* flag       = (u8*)take((size_t)W * 32);
  u32* occw      = (u32*)take((size_t)W * 4);
  u64* bwr       = (u64*)take((size_t)W * 8);
  if ((size_t)(p - (char*)d_ws) > ws_size) return;  // insufficient scratch

  hipMemsetAsync(ctr, 0, 256, stream);
  hipMemsetAsync(gh, 0, 1344 * 4, stream);
  hipMemsetAsync(flag, 0, (size_t)W * 32, stream);

  float* out = (float*)d_out;

  k_pos<<<(N * 3 + 255) / 256, 256, 0, stream>>>(verts, deform, sdf, grptr,
                                                 pos, occw, N, N * 3);
  k_classify<<<NBF, 256, 0, stream>>>(indices, occw, F, A, ctr, bsF, tetidx, flag);
  k_scanF<<<1, 1024, 0, stream>>>(bsF, NBF, ctr);
  k_rowbase<<<NBF, 256, 0, stream>>>(tetidx, bsF, ctr, F, rowbase);

  // one read of A -> all 6 digit-total segments, then scan each
  k_hist4<<<2048, 256, 0, stream>>>(A, ctr, gh);
  k_scan4<<<1, 256, 0, stream>>>(gh);

  // 5-pass LSD radix over key bits 24..61: digits {8,8,8,8,6}
  const int shifts[5] = {24, 32, 40, 48, 56};
  const int nbitsv[5] = {8, 8, 8, 8, 6};
  const int ghoff[5]  = {0, 256, 512, 768, 1024};
  u64* src = A; u64* dst = B;
  for (int pass = 0; pass < 5; ++pass) {
    k_hist<<<NBR, 256, 0, stream>>>(src, ctr, shifts[pass], nbitsv[pass], hist, NBR);
    k_rowscan<<<(1 << nbitsv[pass]), 256, 0, stream>>>(hist, NBR, gh + ghoff[pass]);
    if (nbitsv[pass] == 8)
      k_scatter8<<<NBR, 256, 0, stream>>>(src, dst, ctr, shifts[pass], hist, NBR);
    else
      k_scatter6<<<NBR, 256, 0, stream>>>(src, dst, ctr, shifts[pass], hist, NBR);
    u64* t = src; src = dst; dst = t;
  }
  // sorted result in src (==B after 5 passes); dst (==A) free -> pair staging
  const u64* S = src;
  u64* stage = dst;

  k_headcount<<<NBA, 256, 0, stream>>>(S, ctr, bsE);
  k_scan_u32<<<1, 1024, 0, stream>>>(bsE, NBA, ctr, CTR_E);
  hipMemsetAsync(hist, 0, (size_t)NBR * 256 * 4, stream);
  k_assign<<<NBA, 256, 0, stream>>>(S, ctr, bsE, stage, hist, NBR, EK);
  // partition pairs by payload>>16 (256KB edge_ids windows) then deliver
  k_rowscan<<<256, 256, 0, stream>>>(hist, NBR, gh + 1088);
  k_scatter8<<<NBR, 256, 0, stream>>>(stage, (u64*)S, ctr, 40, hist, NBR);
  k_deliver<<<(MMAX + 255) / 256, 256, 0, stream>>>(S, ctr, edge_ids);

  k_scanbits<<<1, 1024, 0, stream>>>((const u32*)flag, bwr, W, ctr);
  k_out0_orig<<<(N + 255) / 256, 256, 0, stream>>>(bwr, pos, N, out);
  k_out0_edge<<<(MMAX + 255) / 256, 256, 0, stream>>>(EK, pos, sdf, ctr, out);
  k_out1<<<(F + 255) / 256, 256, 0, stream>>>(indices, tetidx, edge_ids, rowbase,
                                              bwr, ctr, F, N, out);
}

// Round 11
// 744.623 us; speedup vs baseline: 1.7426x; 1.0197x over previous
//
#include <hip/hip_runtime.h>
#include <stdint.h>

typedef unsigned int u32;
typedef unsigned long long u64;
typedef unsigned short u16;
typedef unsigned char u8;

#define CTR_M 0
#define CTR_E 1
#define CTR_C1 2
#define CTR_C3 3
#define CTR_CI 4
#define CTR_T 5
#define CTR_U 6
#define CTR_OUT1 7

// TET_TABLE rows packed 4 bits/entry (LSB-first), -1 -> 0xF (never read: row
// count limited by num_tets). Row 15 == [0,1,2,3] doubles as the inner-tet row.
__device__ const u64 TETPACK[16] = {
  0xFFFFFFFFFFFFULL,
  0xFFFFFFFF6540ULL,
  0xFFFFFFFF7841ULL,
  0x610567156817ULL,
  0xFFFFFFFF9752ULL,
  0x290767097604ULL,
  0x921549158914ULL,
  0x286921682106ULL,
  0xFFFFFFFF8963ULL,
  0x398538058405ULL,
  0x376936743741ULL,
  0x971539153510ULL,
  0x875385637325ULL,
  0x273078308740ULL,
  0x653452343214ULL,
  0xFFFFFFFF3210ULL
};

// ---- 2-barrier block-scan primitives (wave shuffle + 4-entry exchange) ----
__device__ __forceinline__ u32 bscan256(u32 x, u32* s4, u32& total)
{
  const int lane = threadIdx.x & 63;
  const int wid = threadIdx.x >> 6;
  u32 incl = x;
  #pragma unroll
  for (int d = 1; d < 64; d <<= 1) {
    u32 t = __shfl_up(incl, d);
    if (lane >= d) incl += t;
  }
  if (lane == 63) s4[wid] = incl;
  __syncthreads();
  u32 w0 = s4[0], w1 = s4[1], w2 = s4[2], w3 = s4[3];
  total = w0 + w1 + w2 + w3;
  u32 off = (wid > 0 ? w0 : 0u) + (wid > 1 ? w1 : 0u) + (wid > 2 ? w2 : 0u);
  return off + incl;
}

__device__ __forceinline__ u64 bscan256_64(u64 x, u64* s4, u64& total)
{
  const int lane = threadIdx.x & 63;
  const int wid = threadIdx.x >> 6;
  u64 incl = x;
  #pragma unroll
  for (int d = 1; d < 64; d <<= 1) {
    u64 t = __shfl_up(incl, d);
    if (lane >= d) incl += t;
  }
  if (lane == 63) s4[wid] = incl;
  __syncthreads();
  u64 w0 = s4[0], w1 = s4[1], w2 = s4[2], w3 = s4[3];
  total = w0 + w1 + w2 + w3;
  u64 off = (wid > 0 ? w0 : 0ull) + (wid > 1 ? w1 : 0ull) + (wid > 2 ? w2 : 0ull);
  return off + incl;
}

// ---- pos = verts + tanh(deform)/grid_res ; also occ bitmap (sdf>0) ----
__global__ void __launch_bounds__(256) k_pos(
    const float* __restrict__ verts, const float* __restrict__ deform,
    const float* __restrict__ sdf, const int* __restrict__ grptr,
    float* __restrict__ pos, u32* __restrict__ occw, int N, int n3)
{
  int i = blockIdx.x * 256 + threadIdx.x;
  if (i < n3) {
    float inv = 1.0f / (float)grptr[0];
    pos[i] = verts[i] + tanhf(deform[i]) * inv;
  }
  const int NOCC = (N + 1023) / 1024;
  if (blockIdx.x < NOCC) {
    __shared__ u32 s_nib[256];
    const int tid = threadIdx.x;
    int base = blockIdx.x * 1024 + tid * 4;
    u32 nib = 0;
    if (base + 3 < N) {
      float4 s = *reinterpret_cast<const float4*>(sdf + base);
      nib = (s.x > 0.0f ? 1u : 0u) | (s.y > 0.0f ? 2u : 0u) |
            (s.z > 0.0f ? 4u : 0u) | (s.w > 0.0f ? 8u : 0u);
    } else {
      for (int k = 0; k < 4; ++k)
        if (base + k < N) nib |= (sdf[base + k] > 0.0f ? 1u : 0u) << k;
    }
    s_nib[tid] = nib;
    __syncthreads();
    if (tid < 32) {
      u32 w = 0;
      #pragma unroll
      for (int j = 0; j < 8; ++j) w |= s_nib[tid * 8 + j] << (4 * j);
      int wi = blockIdx.x * 32 + tid;
      if (wi < (N + 31) / 32) occw[wi] = w;
    }
  }
}

// ---- classify tets, emit crossing-edge records, flag inside verts ----
__global__ void __launch_bounds__(256) k_classify(
    const int* __restrict__ idx, const u32* __restrict__ occw, int F,
    u64* __restrict__ A, u32* __restrict__ ctr,
    u64* __restrict__ bsF, u8* __restrict__ tetidx, u8* __restrict__ flag)
{
  const int tid = threadIdx.x;
  const int lane = tid & 63;
  const int wid = tid >> 6;
  const int base = blockIdx.x * 1024 + tid * 4;
  u32 tis4 = 0;
  u32 cms[4];
  int4 vs[4];
  u64 cnt = 0;
  u32 ec = 0;
  #pragma unroll
  for (int it = 0; it < 4; ++it) {
    const int f = base + it;
    u32 ti = 0, cm = 0;
    int4 v = make_int4(0, 0, 0, 0);
    if (f < F) {
      v = reinterpret_cast<const int4*>(idx)[f];
      u32 b0 = (occw[(u32)v.x >> 5] >> (v.x & 31)) & 1u;
      u32 b1 = (occw[(u32)v.y >> 5] >> (v.y & 31)) & 1u;
      u32 b2 = (occw[(u32)v.z >> 5] >> (v.z & 31)) & 1u;
      u32 b3 = (occw[(u32)v.w >> 5] >> (v.w & 31)) & 1u;
      if (b0) flag[v.x] = 1;
      if (b1) flag[v.y] = 1;
      if (b2) flag[v.z] = 1;
      if (b3) flag[v.w] = 1;
      ti = b0 | (b1 << 1) | (b2 << 2) | (b3 << 3);
      cm  = (b0 ^ b1);
      cm |= (b0 ^ b2) << 1;
      cm |= (b0 ^ b3) << 2;
      cm |= (b1 ^ b2) << 3;
      cm |= (b1 ^ b3) << 4;
      cm |= (b2 ^ b3) << 5;
      int pc = __popc(ti);
      if (pc == 1) cnt += 1ULL;
      else if (pc == 2 || pc == 3) cnt += (1ULL << 21);
      else if (pc == 4) cnt += (1ULL << 42);
    }
    vs[it] = v;
    cms[it] = cm;
    tis4 |= ti << (8 * it);
    ec += __popc(cm);
  }
  u32 incl = ec;
  #pragma unroll
  for (int d = 1; d < 64; d <<= 1) {
    u32 t = __shfl_up(incl, d);
    if (lane >= d) incl += t;
  }
  u32 excl = incl - ec;
  __shared__ u32 s_wtot[4];
  __shared__ u32 s_base;
  if (lane == 63) s_wtot[wid] = incl;
  __syncthreads();
  if (tid == 0) {
    u32 t0 = s_wtot[0], t1 = s_wtot[1], t2 = s_wtot[2], t3 = s_wtot[3];
    u32 tot = t0 + t1 + t2 + t3;
    s_base = tot ? atomicAdd(&ctr[CTR_M], tot) : 0u;
    s_wtot[0] = 0; s_wtot[1] = t0; s_wtot[2] = t0 + t1; s_wtot[3] = t0 + t1 + t2;
  }
  __syncthreads();
  u32 w = s_base + s_wtot[wid] + excl;
  #pragma unroll
  for (int it = 0; it < 4; ++it) {
    u32 cm = cms[it];
    if (!cm) continue;
    const int f = base + it;
    const int va[6] = {vs[it].x, vs[it].x, vs[it].x, vs[it].y, vs[it].y, vs[it].z};
    const int vb[6] = {vs[it].y, vs[it].z, vs[it].w, vs[it].z, vs[it].w, vs[it].w};
    #pragma unroll
    for (int s = 0; s < 6; ++s) {
      if ((cm >> s) & 1u) {
        int a = va[s], b = vb[s];
        int mn = min(a, b), mx = max(a, b);
        u64 key = ((u64)(u32)mn << 19) | (u64)(u32)mx;
        A[w++] = (key << 24) | (u64)(u32)(f * 6 + s);
      }
    }
  }
  if (base < F) {
    if (base + 3 < F) {
      *reinterpret_cast<u32*>(tetidx + base) = tis4;
    } else {
      for (int it = 0; it < 4; ++it)
        if (base + it < F) tetidx[base + it] = (u8)((tis4 >> (8 * it)) & 255u);
    }
  }
  // block reduce of packed category counts: wave shfl_xor + 1 barrier
  u64 r = cnt;
  #pragma unroll
  for (int d = 32; d > 0; d >>= 1) r += __shfl_xor(r, d);
  __shared__ u64 s_w64[4];
  if (lane == 0) s_w64[wid] = r;
  __syncthreads();
  if (tid == 0) bsF[blockIdx.x] = s_w64[0] + s_w64[1] + s_w64[2] + s_w64[3];
}

// ---- all-pass digit histograms in ONE read of A (order-invariant) ----
// segments: 0:[256] s24 | 256:[256] s32 | 512:[256] s40 | 768:[256] s48 |
//           1024:[64] s56 | 1088:[256] partition ((v>>16)&255)
__global__ void __launch_bounds__(256) k_hist4(
    const u64* __restrict__ A, const u32* __restrict__ ctr, u32* __restrict__ gh)
{
  __shared__ u32 sh[1344];
  const int tid = threadIdx.x;
  for (int b = tid; b < 1344; b += 256) sh[b] = 0;
  __syncthreads();
  const int M = (int)ctr[CTR_M];
  for (int i = blockIdx.x * 256 + tid; i < M; i += gridDim.x * 256) {
    u64 v = A[i];
    atomicAdd(&sh[        (u32)(v >> 24) & 255u], 1u);
    atomicAdd(&sh[ 256 + ((u32)(v >> 32) & 255u)], 1u);
    atomicAdd(&sh[ 512 + ((u32)(v >> 40) & 255u)], 1u);
    atomicAdd(&sh[ 768 + ((u32)(v >> 48) & 255u)], 1u);
    atomicAdd(&sh[1024 + ((u32)(v >> 56) &  63u)], 1u);
    atomicAdd(&sh[1088 + ((u32)(v >> 16) & 255u)], 1u);
  }
  __syncthreads();
  for (int b = tid; b < 1344; b += 256) if (sh[b]) atomicAdd(&gh[b], sh[b]);
}

// ---- exclusive scan of each segment of gh (single launch, 2 barriers/seg) ----
__global__ void __launch_bounds__(256) k_scan4(u32* __restrict__ gh)
{
  __shared__ u32 s4[4];
  const int tid = threadIdx.x;
  const int off[6] = {0, 256, 512, 768, 1024, 1088};
  const int len[6] = {256, 256, 256, 256, 64, 256};
  for (int s = 0; s < 6; ++s) {
    u32 v = (tid < len[s]) ? gh[off[s] + tid] : 0u;
    u32 total;
    u32 incl = bscan256(v, s4, total);
    if (tid < len[s]) gh[off[s] + tid] = incl - v;
    __syncthreads();
  }
}

// ---- per-digit row scan: hist[d][0..NBR) -> global exclusive bases ----
__global__ void __launch_bounds__(256) k_rowscan(
    u32* __restrict__ hist, int NBR, const u32* __restrict__ gh)
{
  const int d = blockIdx.x;
  u32* row = hist + (size_t)d * NBR;
  const int tid = threadIdx.x;
  __shared__ u32 s4[4];
  u32 carry = gh[d];
  for (int start = 0; start < NBR; start += 256) {
    int i = start + tid;
    u32 v = (i < NBR) ? row[i] : 0u;
    u32 total;
    u32 incl = bscan256(v, s4, total);
    if (i < NBR) row[i] = carry + incl - v;
    carry += total;
    __syncthreads();
  }
}

// ---- exclusive scan of packed per-block category counts (single block) ----
__global__ void __launch_bounds__(1024) k_scanF(
    u64* __restrict__ bsF, int nb, u32* __restrict__ ctr)
{
  __shared__ u64 sh16[16];
  const int tid = threadIdx.x;
  const int lane = tid & 63;
  const int wid = tid >> 6;
  u64 carry = 0;
  for (int start = 0; start < nb; start += 1024) {
    int i = start + tid;
    u64 v = (i < nb) ? bsF[i] : 0ULL;
    u64 incl = v;
    #pragma unroll
    for (int d = 1; d < 64; d <<= 1) {
      u64 t = __shfl_up(incl, d);
      if (lane >= d) incl += t;
    }
    if (lane == 63) sh16[wid] = incl;
    __syncthreads();
    if (wid == 0) {
      u64 w = (lane < 16) ? sh16[lane] : 0ull;
      #pragma unroll
      for (int d = 1; d < 16; d <<= 1) {
        u64 t = __shfl_up(w, d);
        if (lane >= d) w += t;
      }
      if (lane < 16) sh16[lane] = w;
    }
    __syncthreads();
    u64 waveoff = (wid > 0) ? sh16[wid - 1] : 0ull;
    u64 total = sh16[15];
    if (i < nb) bsF[i] = carry + waveoff + incl - v;
    carry += total;
    __syncthreads();
  }
  if (tid == 0) {
    u32 c1 = (u32)(carry & 0x1FFFFFULL);
    u32 c3 = (u32)((carry >> 21) & 0x1FFFFFULL);
    u32 ci = (u32)((carry >> 42) & 0x1FFFFFULL);
    ctr[CTR_C1] = c1; ctr[CTR_C3] = c3; ctr[CTR_CI] = ci;
    ctr[CTR_T] = c1 + 3u * c3 + ci;
  }
}

// ---- per-tet output row base (mt1 region | mt3 region | inner region) ----
__global__ void __launch_bounds__(256) k_rowbase(
    const u8* __restrict__ tetidx, const u64* __restrict__ bsF,
    const u32* __restrict__ ctr, int F, int* __restrict__ rowbase)
{
  const int tid = threadIdx.x;
  const int base = blockIdx.x * 1024 + tid * 4;
  u32 tis[4];
  u64 cnt = 0;
  #pragma unroll
  for (int it = 0; it < 4; ++it) {
    int f = base + it;
    u32 ti = (f < F) ? (u32)tetidx[f] : 0u;
    tis[it] = ti;
    int pc = __popc(ti);
    if (ti) {
      if (pc == 1) cnt += 1ULL;
      else if (pc <= 3) cnt += (1ULL << 21);
      else cnt += (1ULL << 42);
    }
  }
  __shared__ u64 s4[4];
  u64 total;
  u64 incl = bscan256_64(cnt, s4, total);
  u64 off = bsF[blockIdx.x] + (incl - cnt);
  u32 o1 = (u32)(off & 0x1FFFFFULL);
  u32 o3 = (u32)((off >> 21) & 0x1FFFFFULL);
  u32 oi = (u32)((off >> 42) & 0x1FFFFFULL);
  const u32 C1 = ctr[CTR_C1], C3 = ctr[CTR_C3];
  int rb[4];
  #pragma unroll
  for (int it = 0; it < 4; ++it) {
    u32 ti = tis[it];
    int pc = __popc(ti);
    int r = -1;
    if (ti == 15u) { r = (int)(C1 + 3u * C3 + oi); ++oi; }
    else if (ti) {
      if (pc == 1) { r = (int)o1; ++o1; }
      else { r = (int)(C1 + 3u * o3); ++o3; }
    }
    rb[it] = r;
  }
  if (base + 3 < F) {
    reinterpret_cast<int4*>(rowbase)[base >> 2] = make_int4(rb[0], rb[1], rb[2], rb[3]);
  } else {
    for (int it = 0; it < 4; ++it)
      if (base + it < F) rowbase[base + it] = rb[it];
  }
}

// ---------------- radix sort: per-block histogram (16K items/block) ----------------
__global__ void __launch_bounds__(256) k_hist(
    const u64* __restrict__ src, const u32* __restrict__ ctr,
    int shift, int nbits, u32* __restrict__ hist, int NBR)
{
  const int NB = 1 << nbits;
  __shared__ u32 sh[256];
  const int tid = threadIdx.x;
  if (tid < NB) sh[tid] = 0;
  __syncthreads();
  const int M = (int)ctr[CTR_M];
  const int base = blockIdx.x * 16384;
  for (int r = 0; r < 16; ++r) {
    int rbase = base + r * 1024;
    if (rbase >= M) break;
    int ib = rbase + tid * 4;
    #pragma unroll
    for (int j = 0; j < 4; ++j) {
      if (ib + j < M) {
        u32 d = (u32)(src[ib + j] >> shift) & (u32)(NB - 1);
        atomicAdd(&sh[d], 1u);
      }
    }
  }
  __syncthreads();
  if (tid < NB) hist[tid * NBR + blockIdx.x] = sh[tid];
}

// ---- single-block scan (kept for small arrays: bsE) ----
__device__ __forceinline__ u32 block_scan_incl_1024(u32 x, u32* shtmp, u32& total)
{
  const int lane = threadIdx.x & 63;
  const int wid = threadIdx.x >> 6;
  u32 incl = x;
  #pragma unroll
  for (int d = 1; d < 64; d <<= 1) {
    u32 t = __shfl_up(incl, d);
    if (lane >= d) incl += t;
  }
  if (lane == 63) shtmp[wid] = incl;
  __syncthreads();
  if (wid == 0) {
    u32 w = (lane < 16) ? shtmp[lane] : 0u;
    #pragma unroll
    for (int d = 1; d < 16; d <<= 1) {
      u32 t = __shfl_up(w, d);
      if (lane >= d) w += t;
    }
    if (lane < 16) shtmp[lane] = w;
  }
  __syncthreads();
  u32 waveoff = (wid > 0) ? shtmp[wid - 1] : 0u;
  total = shtmp[15];
  return waveoff + incl;
}

__global__ void __launch_bounds__(1024) k_scan_u32(
    u32* __restrict__ data, int L, u32* __restrict__ ctr, int slot)
{
  __shared__ u32 shtmp[16];
  const int tid = threadIdx.x;
  u32 carry = 0;
  for (int start = 0; start < L; start += 4096) {
    u32 v[4]; u32 s = 0;
    #pragma unroll
    for (int j = 0; j < 4; ++j) {
      int i = start + tid * 4 + j;
      v[j] = (i < L) ? data[i] : 0u;
      s += v[j];
    }
    u32 total;
    u32 incl = block_scan_incl_1024(s, shtmp, total);
    u32 run = carry + incl - s;
    #pragma unroll
    for (int j = 0; j < 4; ++j) {
      int i = start + tid * 4 + j;
      if (i < L) data[i] = run;
      run += v[j];
    }
    carry += total;
    __syncthreads();
  }
  if (slot >= 0 && tid == 0) ctr[slot] = carry;
}

// ------- radix scatter: stable, race-free, [slot][digit] + per-digit prefix -------
__device__ __forceinline__ void scatter_body(
    const u64* __restrict__ src, u64* __restrict__ dst,
    const u32* __restrict__ ctr, int shift, int NBITS,
    const u32* __restrict__ hist, int NBR,
    u32* s_gbase, u16* s_wh)
{
  const int NB = 1 << NBITS;
  const int tid = threadIdx.x;
  const int lane = tid & 63;
  const int wid = tid >> 6;
  if (tid < NB) s_gbase[tid] = hist[tid * NBR + blockIdx.x];
  for (int b = tid; b < NB * 8; b += 256) reinterpret_cast<u32*>(s_wh)[b] = 0;
  __syncthreads();
  const int M = (int)ctr[CTR_M];
  const u64 lowmask = (1ULL << lane) - 1ULL;
  const int base = blockIdx.x * 16384;
  for (int r = 0; r < 16; ++r) {
    int rbase = base + r * 1024;
    if (rbase >= M) break;                 // uniform across block
    u64 v[4]; u32 d4[4]; u32 lr4[4]; bool act[4];
    #pragma unroll
    for (int j = 0; j < 4; ++j) {
      int ib = rbase + (wid * 4 + j) * 64 + lane;
      act[j] = ib < M;
      v[j] = act[j] ? src[ib] : 0ULL;
      d4[j] = (u32)(v[j] >> shift) & (u32)(NB - 1);
    }
    // Phase A
    #pragma unroll
    for (int j = 0; j < 4; ++j) {
      u32 d = d4[j];
      u64 mask = __ballot(act[j]);
      for (int b = 0; b < NBITS; ++b) {
        u64 bal = __ballot(act[j] && ((d >> b) & 1u));
        mask &= ((d >> b) & 1u) ? bal : ~bal;
      }
      lr4[j] = (u32)__popcll(mask & lowmask);
      if (act[j] && lr4[j] == 0)
        s_wh[(wid * 4 + j) * NB + d] = (u16)__popcll(mask);
    }
    __syncthreads();
    // Phase B: per-digit exclusive prefix over 16 slots (thread-exclusive)
    u32 mytot = 0;
    if (tid < NB) {
      u32 run = 0;
      #pragma unroll
      for (int s = 0; s < 16; ++s) {
        u32 c = (u32)s_wh[s * NB + tid];
        s_wh[s * NB + tid] = (u16)run;
        run += c;
      }
      mytot = run;
    }
    __syncthreads();
    // Phase C: scatter (read-only on s_gbase / s_wh)
    #pragma unroll
    for (int j = 0; j < 4; ++j) {
      if (!act[j]) continue;
      u32 d = d4[j];
      dst[s_gbase[d] + (u32)s_wh[(wid * 4 + j) * NB + d] + lr4[j]] = v[j];
    }
    __syncthreads();
    // Phase D: advance bases + re-zero (thread-exclusive per digit)
    if (tid < NB) {
      s_gbase[tid] += mytot;
      #pragma unroll
      for (int s = 0; s < 16; ++s) s_wh[s * NB + tid] = 0;
    }
    __syncthreads();
  }
}

__global__ void __launch_bounds__(256) k_scatter8(
    const u64* __restrict__ src, u64* __restrict__ dst,
    const u32* __restrict__ ctr, int shift,
    const u32* __restrict__ hist, int NBR)
{
  __shared__ u32 s_gbase[256];
  __shared__ u16 s_wh[16 * 256];
  scatter_body(src, dst, ctr, shift, 8, hist, NBR, s_gbase, s_wh);
}

__global__ void __launch_bounds__(256) k_scatter6(
    const u64* __restrict__ src, u64* __restrict__ dst,
    const u32* __restrict__ ctr, int shift,
    const u32* __restrict__ hist, int NBR)
{
  __shared__ u32 s_gbase[64];
  __shared__ u16 s_wh[16 * 64];
  scatter_body(src, dst, ctr, shift, 6, hist, NBR, s_gbase, s_wh);
}

// ---------------- unique-run head counts per block (1024 items/block) ----------------
__global__ void __launch_bounds__(256) k_headcount(
    const u64* __restrict__ S, const u32* __restrict__ ctr, u32* __restrict__ bsE)
{
  const int tid = threadIdx.x;
  const int lane = tid & 63;
  const int wid = tid >> 6;
  const int M = (int)ctr[CTR_M];
  if (blockIdx.x * 1024 >= M) {
    if (tid == 0) bsE[blockIdx.x] = 0;
    return;
  }
  const int base = blockIdx.x * 1024 + tid * 4;
  u32 c = 0;
  u64 prev = (base > 0 && base < M) ? (S[base - 1] >> 24) : 0ULL;
  #pragma unroll
  for (int j = 0; j < 4; ++j) {
    int i = base + j;
    if (i < M) {
      u64 k = S[i] >> 24;
      c += ((i == 0) || (k != prev)) ? 1u : 0u;
      prev = k;
    }
  }
  #pragma unroll
  for (int d = 32; d > 0; d >>= 1) c += __shfl_xor(c, d);
  __shared__ u32 s4[4];
  if (lane == 0) s4[wid] = c;
  __syncthreads();
  if (tid == 0) bsE[blockIdx.x] = s4[0] + s4[1] + s4[2] + s4[3];
}

// ---- assign ids (4 items/thread): unique keys + coalesced pairs + fused hist ----
__global__ void __launch_bounds__(256) k_assign(
    const u64* __restrict__ S, const u32* __restrict__ ctr,
    const u32* __restrict__ bsE, u64* __restrict__ stage,
    u32* __restrict__ hist, int NBR, u64* __restrict__ edgekeys)
{
  const int tid = threadIdx.x;
  const int M = (int)ctr[CTR_M];
  if (blockIdx.x * 1024 >= M) return;      // no items, no hist contributions
  const int base = blockIdx.x * 1024 + tid * 4;
  __shared__ u32 s_h[256];
  __shared__ u32 s4[4];
  s_h[tid] = 0;
  u64 v[4]; bool hd[4];
  u32 c = 0;
  u64 prev = (base > 0 && base < M) ? (S[base - 1] >> 24) : 0ULL;
  #pragma unroll
  for (int j = 0; j < 4; ++j) {
    int i = base + j;
    v[j] = (i < M) ? S[i] : 0ULL;
    u64 k = v[j] >> 24;
    hd[j] = (i < M) && ((i == 0) || (k != prev));
    if (i < M) prev = k;
    c += hd[j] ? 1u : 0u;
  }
  u32 total;
  u32 incl = bscan256(c, s4, total);       // also syncs s_h init
  u32 run = bsE[blockIdx.x] + incl - c;
  #pragma unroll
  for (int j = 0; j < 4; ++j) {
    int i = base + j;
    if (i < M) {
      run += hd[j] ? 1u : 0u;
      u32 id = run - 1u;
      if (hd[j]) edgekeys[id] = v[j] >> 24;
      u32 pay = (u32)(v[j] & 0xFFFFFFULL);
      stage[i] = ((u64)pay << 24) | (u64)id;
      atomicAdd(&s_h[(pay >> 16) & 255u], 1u);
    }
  }
  __syncthreads();
  if (s_h[tid]) atomicAdd(&hist[tid * NBR + (blockIdx.x >> 4)], s_h[tid]);
}

// ---- deliver: edge_ids[payload] = id (payload-bucketed for L2 locality) ----
__global__ void __launch_bounds__(256) k_deliver(
    const u64* __restrict__ D, const u32* __restrict__ ctr,
    int* __restrict__ edge_ids)
{
  int i = blockIdx.x * 256 + threadIdx.x;
  if (i >= (int)ctr[CTR_M]) return;
  u64 c = D[i];
  edge_ids[(u32)(c >> 24)] = (int)(c & 0xFFFFFFULL);
}

// ---- rank scan over flag bytes -> bwr (low32 = bits, high32 = wordrank) ----
__global__ void __launch_bounds__(1024) k_scanbits(
    const u32* __restrict__ flag32, u64* __restrict__ bwr,
    int W, u32* __restrict__ ctr)
{
  __shared__ u32 shtmp[16];
  const int tid = threadIdx.x;
  u32 carry = 0;
  for (int start = 0; start < W; start += 1024) {
    int w = start + tid;
    u32 bits = 0;
    if (w < W) {
      #pragma unroll
      for (int k = 0; k < 8; ++k) {
        u32 fo = flag32[w * 8 + k];
        u32 nib = (fo & 1u) | ((fo >> 7) & 2u) | ((fo >> 14) & 4u) | ((fo >> 21) & 8u);
        bits |= nib << (4 * k);
      }
    }
    u32 c = (u32)__popc(bits);
    u32 total;
    u32 incl = block_scan_incl_1024(c, shtmp, total);
    if (w < W) bwr[w] = (u64)bits | ((u64)(carry + incl - c) << 32);
    carry += total;
    __syncthreads();
  }
  if (tid == 0) {
    ctr[CTR_U] = carry;
    ctr[CTR_OUT1] = 3u * (carry + ctr[CTR_E]);
  }
}

// ---------------- output 0a: original vertices ----------------
__global__ void __launch_bounds__(256) k_out0_orig(
    const u64* __restrict__ bwr, const float* __restrict__ pos,
    int N, float* __restrict__ out)
{
  int id = blockIdx.x * 256 + threadIdx.x;
  if (id >= N) return;
  u64 bw = bwr[(u32)id >> 5];
  u32 bits = (u32)bw;
  if (!((bits >> (id & 31)) & 1u)) return;
  u32 j = (u32)(bw >> 32) + (u32)__popc(bits & ((1u << (id & 31)) - 1u));
  size_t o = (size_t)3 * j;
  out[o] = pos[3 * id]; out[o + 1] = pos[3 * id + 1]; out[o + 2] = pos[3 * id + 2];
}

// ---------------- output 0b: interpolated edge vertices ----------------
__global__ void __launch_bounds__(256) k_out0_edge(
    const u64* __restrict__ edgekeys, const float* __restrict__ pos,
    const float* __restrict__ sdf, const u32* __restrict__ ctr,
    float* __restrict__ out)
{
  int e = blockIdx.x * 256 + threadIdx.x;
  if (e >= (int)ctr[CTR_E]) return;
  u64 k = edgekeys[e];
  int a = (int)(k >> 19);
  int b = (int)(k & 0x7FFFFULL);
  float sa = sdf[a], sb = sdf[b];
  float inv = 1.0f / (sa - sb);
  float wa = -sb * inv, wb = sa * inv;
  u32 j = ctr[CTR_U] + (u32)e;
  size_t o = (size_t)3 * j;
  out[o]     = pos[3 * a] * wa + pos[3 * b] * wb;
  out[o + 1] = pos[3 * a + 1] * wa + pos[3 * b + 1] * wb;
  out[o + 2] = pos[3 * a + 2] * wa + pos[3 * b + 2] * wb;
}

// ---------------- output 1: tets = rank(ids), one 16B store per row ----------------
__global__ void __launch_bounds__(256) k_out1(
    const int* __restrict__ idx, const u8* __restrict__ tetidx,
    const int* __restrict__ edge_ids, const int* __restrict__ rowbase,
    const u64* __restrict__ bwr, const u32* __restrict__ ctr,
    int F, int N, float* __restrict__ out)
{
  int f = blockIdx.x * 256 + threadIdx.x;
  if (f >= F) return;
  u32 ti = tetidx[f];
  if (ti == 0) return;
  int4 v = reinterpret_cast<const int4*>(idx)[f];
  int pc = __popc(ti);
  int nt = (pc == 1 || pc == 4) ? 1 : 3;
  u64 row = TETPACK[ti];
  u32 obase = ctr[CTR_OUT1];
  u32 U0 = ctr[CTR_U];
  int rb = rowbase[f];
  float cr[4] = {0.f, 0.f, 0.f, 0.f};
  const int ids[4] = {v.x, v.y, v.z, v.w};
  #pragma unroll
  for (int c = 0; c < 4; ++c) {
    if ((ti >> c) & 1u) {
      int id = ids[c];
      u64 bw = bwr[(u32)id >> 5];
      cr[c] = (float)((u32)(bw >> 32) + (u32)__popc((u32)bw & ((1u << (id & 31)) - 1u)));
    }
  }
  const bool al16 = (obase & 3u) == 0u;
  float* outp = out + (size_t)obase + (size_t)rb * 4;
  for (int t = 0; t < nt; ++t) {
    u32 quad = (u32)(row >> (16 * t)) & 0xFFFFu;
    float o[4];
    #pragma unroll
    for (int k = 0; k < 4; ++k) {
      u32 e = (quad >> (4 * k)) & 15u;
      o[k] = (e < 4u) ? cr[e] : (float)(U0 + (u32)edge_ids[f * 6 + (int)(e - 4u)]);
    }
    if (al16) {
      *reinterpret_cast<float4*>(outp + (size_t)t * 4) =
          make_float4(o[0], o[1], o[2], o[3]);
    } else {
      __builtin_memcpy(outp + (size_t)t * 4, o, 16);
    }
  }
}

extern "C" void kernel_launch(void* const* d_in, const int* in_sizes, int n_in,
                              void* d_out, int out_size, void* d_ws, size_t ws_size,
                              hipStream_t stream)
{
  const float* verts  = (const float*)d_in[0];
  const float* deform = (const float*)d_in[1];
  const float* sdf    = (const float*)d_in[2];
  const int* indices  = (const int*)d_in[3];
  const int* grptr    = (const int*)d_in[4];
  const int N = in_sizes[2];
  const int F = in_sizes[3] / 4;
  const int MMAX = 4 * F;                      // <=4 crossing edges per tet
  const int NBF = (F + 1023) / 1024;
  const int NBR = (MMAX + 16383) / 16384;      // radix blocks (16K items each)
  const int NBA = (MMAX + 1023) / 1024;        // headcount/assign blocks
  const int W = (N + 31) / 32;                 // flag bitmap words

  char* p = (char*)d_ws;
  auto take = [&](size_t bytes) {
    char* r = p;
    p += (bytes + 255) & ~(size_t)255;
    return r;
  };
  u32* ctr       = (u32*)take(256);
  u32* gh        = (u32*)take(1344 * 4);
  u64* A         = (u64*)take((size_t)MMAX * 8);
  u64* B         = (u64*)take((size_t)MMAX * 8);
  u64* EK        = (u64*)take((size_t)MMAX * 8);
  int* edge_ids  = (int*)take((size_t)F * 6 * 4);
  float* pos     = (float*)take((size_t)N * 3 * 4);
  int* rowbase   = (int*)take((size_t)F * 4);
  u8* tetidx     = (u8*)take((size_t)F);
  u32* hist      = (u32*)take((size_t)NBR * 256 * 4);
  u32* bsE       = (u32*)take((size_t)NBA * 4);
  u64* bsF       = (u64*)take((size_t)NBF * 8);
  u8* flag       = (u8*)take((size_t)W * 32);
  u32* occw      = (u32*)take((size_t)W * 4);
  u64* bwr       = (u64*)take((size_t)W * 8);
  if ((size_t)(p - (char*)d_ws) > ws_size) return;  // insufficient scratch

  hipMemsetAsync(ctr, 0, 256, stream);
  hipMemsetAsync(gh, 0, 1344 * 4, stream);
  hipMemsetAsync(flag, 0, (size_t)W * 32, stream);

  float* out = (float*)d_out;

  k_pos<<<(N * 3 + 255) / 256, 256, 0, stream>>>(verts, deform, sdf, grptr,
                                                 pos, occw, N, N * 3);
  k_classify<<<NBF, 256, 0, stream>>>(indices, occw, F, A, ctr, bsF, tetidx, flag);
  k_scanF<<<1, 1024, 0, stream>>>(bsF, NBF, ctr);
  k_rowbase<<<NBF, 256, 0, stream>>>(tetidx, bsF, ctr, F, rowbase);

  // one read of A -> all 6 digit-total segments, then scan each
  k_hist4<<<2048, 256, 0, stream>>>(A, ctr, gh);
  k_scan4<<<1, 256, 0, stream>>>(gh);

  // 5-pass LSD radix over key bits 24..61: digits {8,8,8,8,6}
  const int shifts[5] = {24, 32, 40, 48, 56};
  const int nbitsv[5] = {8, 8, 8, 8, 6};
  const int ghoff[5]  = {0, 256, 512, 768, 1024};
  u64* src = A; u64* dst = B;
  for (int pass = 0; pass < 5; ++pass) {
    k_hist<<<NBR, 256, 0, stream>>>(src, ctr, shifts[pass], nbitsv[pass], hist, NBR);
    k_rowscan<<<(1 << nbitsv[pass]), 256, 0, stream>>>(hist, NBR, gh + ghoff[pass]);
    if (nbitsv[pass] == 8)
      k_scatter8<<<NBR, 256, 0, stream>>>(src, dst, ctr, shifts[pass], hist, NBR);
    else
      k_scatter6<<<NBR, 256, 0, stream>>>(src, dst, ctr, shifts[pass], hist, NBR);
    u64* t = src; src = dst; dst = t;
  }
  // sorted result in src (==B after 5 passes); dst (==A) free -> pair staging
  const u64* S = src;
  u64* stage = dst;

  k_headcount<<<NBA, 256, 0, stream>>>(S, ctr, bsE);
  k_scan_u32<<<1, 1024, 0, stream>>>(bsE, NBA, ctr, CTR_E);
  hipMemsetAsync(hist, 0, (size_t)NBR * 256 * 4, stream);
  k_assign<<<NBA, 256, 0, stream>>>(S, ctr, bsE, stage, hist, NBR, EK);
  // partition pairs by payload>>16 (256KB edge_ids windows) then deliver
  k_rowscan<<<256, 256, 0, stream>>>(hist, NBR, gh + 1088);
  k_scatter8<<<NBR, 256, 0, stream>>>(stage, (u64*)S, ctr, 40, hist, NBR);
  k_deliver<<<(MMAX + 255) / 256, 256, 0, stream>>>(S, ctr, edge_ids);

  k_scanbits<<<1, 1024, 0, stream>>>((const u32*)flag, bwr, W, ctr);
  k_out0_orig<<<(N + 255) / 256, 256, 0, stream>>>(bwr, pos, N, out);
  k_out0_edge<<<(MMAX + 255) / 256, 256, 0, stream>>>(EK, pos, sdf, ctr, out);
  k_out1<<<(F + 255) / 256, 256, 0, stream>>>(indices, tetidx, edge_ids, rowbase,
                                              bwr, ctr, F, N, out);
}

// Round 12
// 609.144 us; speedup vs baseline: 2.1302x; 1.2224x over previous
//
#include <hip/hip_runtime.h>
#include <stdint.h>

typedef unsigned int u32;
typedef unsigned long long u64;
typedef unsigned short u16;
typedef unsigned char u8;

#define CTR_M 0
#define CTR_E 1
#define CTR_C1 2
#define CTR_C3 3
#define CTR_CI 4
#define CTR_T 5
#define CTR_U 6
#define CTR_OUT1 7

// radix window size (items per hist/scatter block): 4096 -> ~1100 blocks,
// ~17 waves/CU (53% occ) instead of 367 blocks @ 18% occ.
#define RWIN 4096
#define RROUNDS (RWIN / 1024)

// TET_TABLE rows packed 4 bits/entry (LSB-first), -1 -> 0xF (never read: row
// count limited by num_tets). Row 15 == [0,1,2,3] doubles as the inner-tet row.
__device__ const u64 TETPACK[16] = {
  0xFFFFFFFFFFFFULL,
  0xFFFFFFFF6540ULL,
  0xFFFFFFFF7841ULL,
  0x610567156817ULL,
  0xFFFFFFFF9752ULL,
  0x290767097604ULL,
  0x921549158914ULL,
  0x286921682106ULL,
  0xFFFFFFFF8963ULL,
  0x398538058405ULL,
  0x376936743741ULL,
  0x971539153510ULL,
  0x875385637325ULL,
  0x273078308740ULL,
  0x653452343214ULL,
  0xFFFFFFFF3210ULL
};

// ---- 2-barrier block-scan primitives (wave shuffle + 4-entry exchange) ----
__device__ __forceinline__ u32 bscan256(u32 x, u32* s4, u32& total)
{
  const int lane = threadIdx.x & 63;
  const int wid = threadIdx.x >> 6;
  u32 incl = x;
  #pragma unroll
  for (int d = 1; d < 64; d <<= 1) {
    u32 t = __shfl_up(incl, d);
    if (lane >= d) incl += t;
  }
  if (lane == 63) s4[wid] = incl;
  __syncthreads();
  u32 w0 = s4[0], w1 = s4[1], w2 = s4[2], w3 = s4[3];
  total = w0 + w1 + w2 + w3;
  u32 off = (wid > 0 ? w0 : 0u) + (wid > 1 ? w1 : 0u) + (wid > 2 ? w2 : 0u);
  return off + incl;
}

__device__ __forceinline__ u64 bscan256_64(u64 x, u64* s4, u64& total)
{
  const int lane = threadIdx.x & 63;
  const int wid = threadIdx.x >> 6;
  u64 incl = x;
  #pragma unroll
  for (int d = 1; d < 64; d <<= 1) {
    u64 t = __shfl_up(incl, d);
    if (lane >= d) incl += t;
  }
  if (lane == 63) s4[wid] = incl;
  __syncthreads();
  u64 w0 = s4[0], w1 = s4[1], w2 = s4[2], w3 = s4[3];
  total = w0 + w1 + w2 + w3;
  u64 off = (wid > 0 ? w0 : 0ull) + (wid > 1 ? w1 : 0ull) + (wid > 2 ? w2 : 0ull);
  return off + incl;
}

// ---- pos = verts + tanh(deform)/grid_res ; also occ bitmap (sdf>0) ----
__global__ void __launch_bounds__(256) k_pos(
    const float* __restrict__ verts, const float* __restrict__ deform,
    const float* __restrict__ sdf, const int* __restrict__ grptr,
    float* __restrict__ pos, u32* __restrict__ occw, int N, int n3)
{
  int i = blockIdx.x * 256 + threadIdx.x;
  if (i < n3) {
    float inv = 1.0f / (float)grptr[0];
    pos[i] = verts[i] + tanhf(deform[i]) * inv;
  }
  const int NOCC = (N + 1023) / 1024;
  if (blockIdx.x < NOCC) {
    __shared__ u32 s_nib[256];
    const int tid = threadIdx.x;
    int base = blockIdx.x * 1024 + tid * 4;
    u32 nib = 0;
    if (base + 3 < N) {
      float4 s = *reinterpret_cast<const float4*>(sdf + base);
      nib = (s.x > 0.0f ? 1u : 0u) | (s.y > 0.0f ? 2u : 0u) |
            (s.z > 0.0f ? 4u : 0u) | (s.w > 0.0f ? 8u : 0u);
    } else {
      for (int k = 0; k < 4; ++k)
        if (base + k < N) nib |= (sdf[base + k] > 0.0f ? 1u : 0u) << k;
    }
    s_nib[tid] = nib;
    __syncthreads();
    if (tid < 32) {
      u32 w = 0;
      #pragma unroll
      for (int j = 0; j < 8; ++j) w |= s_nib[tid * 8 + j] << (4 * j);
      int wi = blockIdx.x * 32 + tid;
      if (wi < (N + 31) / 32) occw[wi] = w;
    }
  }
}

// ---- classify tets, emit crossing-edge records, flag inside verts ----
__global__ void __launch_bounds__(256) k_classify(
    const int* __restrict__ idx, const u32* __restrict__ occw, int F,
    u64* __restrict__ A, u32* __restrict__ ctr,
    u64* __restrict__ bsF, u8* __restrict__ tetidx, u8* __restrict__ flag)
{
  const int tid = threadIdx.x;
  const int lane = tid & 63;
  const int wid = tid >> 6;
  const int base = blockIdx.x * 1024 + tid * 4;
  u32 tis4 = 0;
  u32 cms[4];
  int4 vs[4];
  u64 cnt = 0;
  u32 ec = 0;
  #pragma unroll
  for (int it = 0; it < 4; ++it) {
    const int f = base + it;
    u32 ti = 0, cm = 0;
    int4 v = make_int4(0, 0, 0, 0);
    if (f < F) {
      v = reinterpret_cast<const int4*>(idx)[f];
      u32 b0 = (occw[(u32)v.x >> 5] >> (v.x & 31)) & 1u;
      u32 b1 = (occw[(u32)v.y >> 5] >> (v.y & 31)) & 1u;
      u32 b2 = (occw[(u32)v.z >> 5] >> (v.z & 31)) & 1u;
      u32 b3 = (occw[(u32)v.w >> 5] >> (v.w & 31)) & 1u;
      if (b0) flag[v.x] = 1;
      if (b1) flag[v.y] = 1;
      if (b2) flag[v.z] = 1;
      if (b3) flag[v.w] = 1;
      ti = b0 | (b1 << 1) | (b2 << 2) | (b3 << 3);
      cm  = (b0 ^ b1);
      cm |= (b0 ^ b2) << 1;
      cm |= (b0 ^ b3) << 2;
      cm |= (b1 ^ b2) << 3;
      cm |= (b1 ^ b3) << 4;
      cm |= (b2 ^ b3) << 5;
      int pc = __popc(ti);
      if (pc == 1) cnt += 1ULL;
      else if (pc == 2 || pc == 3) cnt += (1ULL << 21);
      else if (pc == 4) cnt += (1ULL << 42);
    }
    vs[it] = v;
    cms[it] = cm;
    tis4 |= ti << (8 * it);
    ec += __popc(cm);
  }
  u32 incl = ec;
  #pragma unroll
  for (int d = 1; d < 64; d <<= 1) {
    u32 t = __shfl_up(incl, d);
    if (lane >= d) incl += t;
  }
  u32 excl = incl - ec;
  __shared__ u32 s_wtot[4];
  __shared__ u32 s_base;
  if (lane == 63) s_wtot[wid] = incl;
  __syncthreads();
  if (tid == 0) {
    u32 t0 = s_wtot[0], t1 = s_wtot[1], t2 = s_wtot[2], t3 = s_wtot[3];
    u32 tot = t0 + t1 + t2 + t3;
    s_base = tot ? atomicAdd(&ctr[CTR_M], tot) : 0u;
    s_wtot[0] = 0; s_wtot[1] = t0; s_wtot[2] = t0 + t1; s_wtot[3] = t0 + t1 + t2;
  }
  __syncthreads();
  u32 w = s_base + s_wtot[wid] + excl;
  #pragma unroll
  for (int it = 0; it < 4; ++it) {
    u32 cm = cms[it];
    if (!cm) continue;
    const int f = base + it;
    const int va[6] = {vs[it].x, vs[it].x, vs[it].x, vs[it].y, vs[it].y, vs[it].z};
    const int vb[6] = {vs[it].y, vs[it].z, vs[it].w, vs[it].z, vs[it].w, vs[it].w};
    #pragma unroll
    for (int s = 0; s < 6; ++s) {
      if ((cm >> s) & 1u) {
        int a = va[s], b = vb[s];
        int mn = min(a, b), mx = max(a, b);
        u64 key = ((u64)(u32)mn << 19) | (u64)(u32)mx;
        A[w++] = (key << 24) | (u64)(u32)(f * 6 + s);
      }
    }
  }
  if (base < F) {
    if (base + 3 < F) {
      *reinterpret_cast<u32*>(tetidx + base) = tis4;
    } else {
      for (int it = 0; it < 4; ++it)
        if (base + it < F) tetidx[base + it] = (u8)((tis4 >> (8 * it)) & 255u);
    }
  }
  // block reduce of packed category counts: wave shfl_xor + 1 barrier
  u64 r = cnt;
  #pragma unroll
  for (int d = 32; d > 0; d >>= 1) r += __shfl_xor(r, d);
  __shared__ u64 s_w64[4];
  if (lane == 0) s_w64[wid] = r;
  __syncthreads();
  if (tid == 0) bsF[blockIdx.x] = s_w64[0] + s_w64[1] + s_w64[2] + s_w64[3];
}

// ---- all-pass digit histograms in ONE read of A (order-invariant) ----
// segments: 0:[256] s24 | 256:[256] s32 | 512:[256] s40 | 768:[256] s48 |
//           1024:[64] s56 | 1088:[256] partition ((v>>16)&255)
__global__ void __launch_bounds__(256) k_hist4(
    const u64* __restrict__ A, const u32* __restrict__ ctr, u32* __restrict__ gh)
{
  __shared__ u32 sh[1344];
  const int tid = threadIdx.x;
  for (int b = tid; b < 1344; b += 256) sh[b] = 0;
  __syncthreads();
  const int M = (int)ctr[CTR_M];
  for (int i = blockIdx.x * 256 + tid; i < M; i += gridDim.x * 256) {
    u64 v = A[i];
    atomicAdd(&sh[        (u32)(v >> 24) & 255u], 1u);
    atomicAdd(&sh[ 256 + ((u32)(v >> 32) & 255u)], 1u);
    atomicAdd(&sh[ 512 + ((u32)(v >> 40) & 255u)], 1u);
    atomicAdd(&sh[ 768 + ((u32)(v >> 48) & 255u)], 1u);
    atomicAdd(&sh[1024 + ((u32)(v >> 56) &  63u)], 1u);
    atomicAdd(&sh[1088 + ((u32)(v >> 16) & 255u)], 1u);
  }
  __syncthreads();
  for (int b = tid; b < 1344; b += 256) if (sh[b]) atomicAdd(&gh[b], sh[b]);
}

// ---- exclusive scan of each segment of gh (single launch, 2 barriers/seg) ----
__global__ void __launch_bounds__(256) k_scan4(u32* __restrict__ gh)
{
  __shared__ u32 s4[4];
  const int tid = threadIdx.x;
  const int off[6] = {0, 256, 512, 768, 1024, 1088};
  const int len[6] = {256, 256, 256, 256, 64, 256};
  for (int s = 0; s < 6; ++s) {
    u32 v = (tid < len[s]) ? gh[off[s] + tid] : 0u;
    u32 total;
    u32 incl = bscan256(v, s4, total);
    if (tid < len[s]) gh[off[s] + tid] = incl - v;
    __syncthreads();
  }
}

// ---- per-digit row scan: hist[d][0..NBR) -> global exclusive bases ----
__global__ void __launch_bounds__(256) k_rowscan(
    u32* __restrict__ hist, int NBR, const u32* __restrict__ gh)
{
  const int d = blockIdx.x;
  u32* row = hist + (size_t)d * NBR;
  const int tid = threadIdx.x;
  __shared__ u32 s4[4];
  u32 carry = gh[d];
  for (int start = 0; start < NBR; start += 256) {
    int i = start + tid;
    u32 v = (i < NBR) ? row[i] : 0u;
    u32 total;
    u32 incl = bscan256(v, s4, total);
    if (i < NBR) row[i] = carry + incl - v;
    carry += total;
    __syncthreads();
  }
}

// ---- exclusive scan of packed per-block category counts (single block) ----
__global__ void __launch_bounds__(1024) k_scanF(
    u64* __restrict__ bsF, int nb, u32* __restrict__ ctr)
{
  __shared__ u64 sh16[16];
  const int tid = threadIdx.x;
  const int lane = tid & 63;
  const int wid = tid >> 6;
  u64 carry = 0;
  for (int start = 0; start < nb; start += 1024) {
    int i = start + tid;
    u64 v = (i < nb) ? bsF[i] : 0ULL;
    u64 incl = v;
    #pragma unroll
    for (int d = 1; d < 64; d <<= 1) {
      u64 t = __shfl_up(incl, d);
      if (lane >= d) incl += t;
    }
    if (lane == 63) sh16[wid] = incl;
    __syncthreads();
    if (wid == 0) {
      u64 w = (lane < 16) ? sh16[lane] : 0ull;
      #pragma unroll
      for (int d = 1; d < 16; d <<= 1) {
        u64 t = __shfl_up(w, d);
        if (lane >= d) w += t;
      }
      if (lane < 16) sh16[lane] = w;
    }
    __syncthreads();
    u64 waveoff = (wid > 0) ? sh16[wid - 1] : 0ull;
    u64 total = sh16[15];
    if (i < nb) bsF[i] = carry + waveoff + incl - v;
    carry += total;
    __syncthreads();
  }
  if (tid == 0) {
    u32 c1 = (u32)(carry & 0x1FFFFFULL);
    u32 c3 = (u32)((carry >> 21) & 0x1FFFFFULL);
    u32 ci = (u32)((carry >> 42) & 0x1FFFFFULL);
    ctr[CTR_C1] = c1; ctr[CTR_C3] = c3; ctr[CTR_CI] = ci;
    ctr[CTR_T] = c1 + 3u * c3 + ci;
  }
}

// ---- per-tet output row base (mt1 region | mt3 region | inner region) ----
__global__ void __launch_bounds__(256) k_rowbase(
    const u8* __restrict__ tetidx, const u64* __restrict__ bsF,
    const u32* __restrict__ ctr, int F, int* __restrict__ rowbase)
{
  const int tid = threadIdx.x;
  const int base = blockIdx.x * 1024 + tid * 4;
  u32 tis[4];
  u64 cnt = 0;
  #pragma unroll
  for (int it = 0; it < 4; ++it) {
    int f = base + it;
    u32 ti = (f < F) ? (u32)tetidx[f] : 0u;
    tis[it] = ti;
    int pc = __popc(ti);
    if (ti) {
      if (pc == 1) cnt += 1ULL;
      else if (pc <= 3) cnt += (1ULL << 21);
      else cnt += (1ULL << 42);
    }
  }
  __shared__ u64 s4[4];
  u64 total;
  u64 incl = bscan256_64(cnt, s4, total);
  u64 off = bsF[blockIdx.x] + (incl - cnt);
  u32 o1 = (u32)(off & 0x1FFFFFULL);
  u32 o3 = (u32)((off >> 21) & 0x1FFFFFULL);
  u32 oi = (u32)((off >> 42) & 0x1FFFFFULL);
  const u32 C1 = ctr[CTR_C1], C3 = ctr[CTR_C3];
  int rb[4];
  #pragma unroll
  for (int it = 0; it < 4; ++it) {
    u32 ti = tis[it];
    int pc = __popc(ti);
    int r = -1;
    if (ti == 15u) { r = (int)(C1 + 3u * C3 + oi); ++oi; }
    else if (ti) {
      if (pc == 1) { r = (int)o1; ++o1; }
      else { r = (int)(C1 + 3u * o3); ++o3; }
    }
    rb[it] = r;
  }
  if (base + 3 < F) {
    reinterpret_cast<int4*>(rowbase)[base >> 2] = make_int4(rb[0], rb[1], rb[2], rb[3]);
  } else {
    for (int it = 0; it < 4; ++it)
      if (base + it < F) rowbase[base + it] = rb[it];
  }
}

// ---------------- radix sort: per-block histogram (RWIN items/block) ----------------
__global__ void __launch_bounds__(256) k_hist(
    const u64* __restrict__ src, const u32* __restrict__ ctr,
    int shift, int nbits, u32* __restrict__ hist, int NBR)
{
  const int NB = 1 << nbits;
  __shared__ u32 sh[256];
  const int tid = threadIdx.x;
  if (tid < NB) sh[tid] = 0;
  __syncthreads();
  const int M = (int)ctr[CTR_M];
  const int base = blockIdx.x * RWIN;
  for (int r = 0; r < RROUNDS; ++r) {
    int rbase = base + r * 1024;
    if (rbase >= M) break;
    int ib = rbase + tid * 4;
    #pragma unroll
    for (int j = 0; j < 4; ++j) {
      if (ib + j < M) {
        u32 d = (u32)(src[ib + j] >> shift) & (u32)(NB - 1);
        atomicAdd(&sh[d], 1u);
      }
    }
  }
  __syncthreads();
  if (tid < NB) hist[tid * NBR + blockIdx.x] = sh[tid];
}

// ---- single-block scan (kept for small arrays: bsE) ----
__device__ __forceinline__ u32 block_scan_incl_1024(u32 x, u32* shtmp, u32& total)
{
  const int lane = threadIdx.x & 63;
  const int wid = threadIdx.x >> 6;
  u32 incl = x;
  #pragma unroll
  for (int d = 1; d < 64; d <<= 1) {
    u32 t = __shfl_up(incl, d);
    if (lane >= d) incl += t;
  }
  if (lane == 63) shtmp[wid] = incl;
  __syncthreads();
  if (wid == 0) {
    u32 w = (lane < 16) ? shtmp[lane] : 0u;
    #pragma unroll
    for (int d = 1; d < 16; d <<= 1) {
      u32 t = __shfl_up(w, d);
      if (lane >= d) w += t;
    }
    if (lane < 16) shtmp[lane] = w;
  }
  __syncthreads();
  u32 waveoff = (wid > 0) ? shtmp[wid - 1] : 0u;
  total = shtmp[15];
  return waveoff + incl;
}

__global__ void __launch_bounds__(1024) k_scan_u32(
    u32* __restrict__ data, int L, u32* __restrict__ ctr, int slot)
{
  __shared__ u32 shtmp[16];
  const int tid = threadIdx.x;
  u32 carry = 0;
  for (int start = 0; start < L; start += 4096) {
    u32 v[4]; u32 s = 0;
    #pragma unroll
    for (int j = 0; j < 4; ++j) {
      int i = start + tid * 4 + j;
      v[j] = (i < L) ? data[i] : 0u;
      s += v[j];
    }
    u32 total;
    u32 incl = block_scan_incl_1024(s, shtmp, total);
    u32 run = carry + incl - s;
    #pragma unroll
    for (int j = 0; j < 4; ++j) {
      int i = start + tid * 4 + j;
      if (i < L) data[i] = run;
      run += v[j];
    }
    carry += total;
    __syncthreads();
  }
  if (slot >= 0 && tid == 0) ctr[slot] = carry;
}

// ------- radix scatter: stable, race-free, [slot][digit] + per-digit prefix -------
__device__ __forceinline__ void scatter_body(
    const u64* __restrict__ src, u64* __restrict__ dst,
    const u32* __restrict__ ctr, int shift, int NBITS,
    const u32* __restrict__ hist, int NBR,
    u32* s_gbase, u16* s_wh)
{
  const int NB = 1 << NBITS;
  const int tid = threadIdx.x;
  const int lane = tid & 63;
  const int wid = tid >> 6;
  if (tid < NB) s_gbase[tid] = hist[tid * NBR + blockIdx.x];
  for (int b = tid; b < NB * 8; b += 256) reinterpret_cast<u32*>(s_wh)[b] = 0;
  __syncthreads();
  const int M = (int)ctr[CTR_M];
  const u64 lowmask = (1ULL << lane) - 1ULL;
  const int base = blockIdx.x * RWIN;
  for (int r = 0; r < RROUNDS; ++r) {
    int rbase = base + r * 1024;
    if (rbase >= M) break;                 // uniform across block
    u64 v[4]; u32 d4[4]; u32 lr4[4]; bool act[4];
    #pragma unroll
    for (int j = 0; j < 4; ++j) {
      int ib = rbase + (wid * 4 + j) * 64 + lane;
      act[j] = ib < M;
      v[j] = act[j] ? src[ib] : 0ULL;
      d4[j] = (u32)(v[j] >> shift) & (u32)(NB - 1);
    }
    // Phase A
    #pragma unroll
    for (int j = 0; j < 4; ++j) {
      u32 d = d4[j];
      u64 mask = __ballot(act[j]);
      for (int b = 0; b < NBITS; ++b) {
        u64 bal = __ballot(act[j] && ((d >> b) & 1u));
        mask &= ((d >> b) & 1u) ? bal : ~bal;
      }
      lr4[j] = (u32)__popcll(mask & lowmask);
      if (act[j] && lr4[j] == 0)
        s_wh[(wid * 4 + j) * NB + d] = (u16)__popcll(mask);
    }
    __syncthreads();
    // Phase B: per-digit exclusive prefix over 16 slots (thread-exclusive)
    u32 mytot = 0;
    if (tid < NB) {
      u32 run = 0;
      #pragma unroll
      for (int s = 0; s < 16; ++s) {
        u32 c = (u32)s_wh[s * NB + tid];
        s_wh[s * NB + tid] = (u16)run;
        run += c;
      }
      mytot = run;
    }
    __syncthreads();
    // Phase C: scatter (read-only on s_gbase / s_wh)
    #pragma unroll
    for (int j = 0; j < 4; ++j) {
      if (!act[j]) continue;
      u32 d = d4[j];
      dst[s_gbase[d] + (u32)s_wh[(wid * 4 + j) * NB + d] + lr4[j]] = v[j];
    }
    __syncthreads();
    // Phase D: advance bases + re-zero (thread-exclusive per digit)
    if (tid < NB) {
      s_gbase[tid] += mytot;
      #pragma unroll
      for (int s = 0; s < 16; ++s) s_wh[s * NB + tid] = 0;
    }
    __syncthreads();
  }
}

__global__ void __launch_bounds__(256) k_scatter8(
    const u64* __restrict__ src, u64* __restrict__ dst,
    const u32* __restrict__ ctr, int shift,
    const u32* __restrict__ hist, int NBR)
{
  __shared__ u32 s_gbase[256];
  __shared__ u16 s_wh[16 * 256];
  scatter_body(src, dst, ctr, shift, 8, hist, NBR, s_gbase, s_wh);
}

__global__ void __launch_bounds__(256) k_scatter6(
    const u64* __restrict__ src, u64* __restrict__ dst,
    const u32* __restrict__ ctr, int shift,
    const u32* __restrict__ hist, int NBR)
{
  __shared__ u32 s_gbase[64];
  __shared__ u16 s_wh[16 * 64];
  scatter_body(src, dst, ctr, shift, 6, hist, NBR, s_gbase, s_wh);
}

// ---------------- unique-run head counts per block (1024 items/block) ----------------
__global__ void __launch_bounds__(256) k_headcount(
    const u64* __restrict__ S, const u32* __restrict__ ctr, u32* __restrict__ bsE)
{
  const int tid = threadIdx.x;
  const int lane = tid & 63;
  const int wid = tid >> 6;
  const int M = (int)ctr[CTR_M];
  if (blockIdx.x * 1024 >= M) {
    if (tid == 0) bsE[blockIdx.x] = 0;
    return;
  }
  const int base = blockIdx.x * 1024 + tid * 4;
  u32 c = 0;
  u64 prev = (base > 0 && base < M) ? (S[base - 1] >> 24) : 0ULL;
  #pragma unroll
  for (int j = 0; j < 4; ++j) {
    int i = base + j;
    if (i < M) {
      u64 k = S[i] >> 24;
      c += ((i == 0) || (k != prev)) ? 1u : 0u;
      prev = k;
    }
  }
  #pragma unroll
  for (int d = 32; d > 0; d >>= 1) c += __shfl_xor(c, d);
  __shared__ u32 s4[4];
  if (lane == 0) s4[wid] = c;
  __syncthreads();
  if (tid == 0) bsE[blockIdx.x] = s4[0] + s4[1] + s4[2] + s4[3];
}

// ---- assign ids (4 items/thread): unique keys + coalesced pairs + fused hist ----
__global__ void __launch_bounds__(256) k_assign(
    const u64* __restrict__ S, const u32* __restrict__ ctr,
    const u32* __restrict__ bsE, u64* __restrict__ stage,
    u32* __restrict__ hist, int NBR, u64* __restrict__ edgekeys)
{
  const int tid = threadIdx.x;
  const int M = (int)ctr[CTR_M];
  if (blockIdx.x * 1024 >= M) return;      // no items, no hist contributions
  const int base = blockIdx.x * 1024 + tid * 4;
  __shared__ u32 s_h[256];
  __shared__ u32 s4[4];
  s_h[tid] = 0;
  u64 v[4]; bool hd[4];
  u32 c = 0;
  u64 prev = (base > 0 && base < M) ? (S[base - 1] >> 24) : 0ULL;
  #pragma unroll
  for (int j = 0; j < 4; ++j) {
    int i = base + j;
    v[j] = (i < M) ? S[i] : 0ULL;
    u64 k = v[j] >> 24;
    hd[j] = (i < M) && ((i == 0) || (k != prev));
    if (i < M) prev = k;
    c += hd[j] ? 1u : 0u;
  }
  u32 total;
  u32 incl = bscan256(c, s4, total);       // also syncs s_h init
  u32 run = bsE[blockIdx.x] + incl - c;
  #pragma unroll
  for (int j = 0; j < 4; ++j) {
    int i = base + j;
    if (i < M) {
      run += hd[j] ? 1u : 0u;
      u32 id = run - 1u;
      if (hd[j]) edgekeys[id] = v[j] >> 24;
      u32 pay = (u32)(v[j] & 0xFFFFFFULL);
      stage[i] = ((u64)pay << 24) | (u64)id;
      atomicAdd(&s_h[(pay >> 16) & 255u], 1u);
    }
  }
  __syncthreads();
  if (s_h[tid]) atomicAdd(&hist[tid * NBR + (blockIdx.x >> 2)], s_h[tid]);
}

// ---- deliver: edge_ids[payload] = id (payload-bucketed for L2 locality) ----
__global__ void __launch_bounds__(256) k_deliver(
    const u64* __restrict__ D, const u32* __restrict__ ctr,
    int* __restrict__ edge_ids)
{
  int i = blockIdx.x * 256 + threadIdx.x;
  if (i >= (int)ctr[CTR_M]) return;
  u64 c = D[i];
  edge_ids[(u32)(c >> 24)] = (int)(c & 0xFFFFFFULL);
}

// ---- rank scan over flag bytes -> bwr (low32 = bits, high32 = wordrank) ----
__global__ void __launch_bounds__(1024) k_scanbits(
    const u32* __restrict__ flag32, u64* __restrict__ bwr,
    int W, u32* __restrict__ ctr)
{
  __shared__ u32 shtmp[16];
  const int tid = threadIdx.x;
  u32 carry = 0;
  for (int start = 0; start < W; start += 1024) {
    int w = start + tid;
    u32 bits = 0;
    if (w < W) {
      #pragma unroll
      for (int k = 0; k < 8; ++k) {
        u32 fo = flag32[w * 8 + k];
        u32 nib = (fo & 1u) | ((fo >> 7) & 2u) | ((fo >> 14) & 4u) | ((fo >> 21) & 8u);
        bits |= nib << (4 * k);
      }
    }
    u32 c = (u32)__popc(bits);
    u32 total;
    u32 incl = block_scan_incl_1024(c, shtmp, total);
    if (w < W) bwr[w] = (u64)bits | ((u64)(carry + incl - c) << 32);
    carry += total;
    __syncthreads();
  }
  if (tid == 0) {
    ctr[CTR_U] = carry;
    ctr[CTR_OUT1] = 3u * (carry + ctr[CTR_E]);
  }
}

// ---------------- output 0a: original vertices ----------------
__global__ void __launch_bounds__(256) k_out0_orig(
    const u64* __restrict__ bwr, const float* __restrict__ pos,
    int N, float* __restrict__ out)
{
  int id = blockIdx.x * 256 + threadIdx.x;
  if (id >= N) return;
  u64 bw = bwr[(u32)id >> 5];
  u32 bits = (u32)bw;
  if (!((bits >> (id & 31)) & 1u)) return;
  u32 j = (u32)(bw >> 32) + (u32)__popc(bits & ((1u << (id & 31)) - 1u));
  size_t o = (size_t)3 * j;
  out[o] = pos[3 * id]; out[o + 1] = pos[3 * id + 1]; out[o + 2] = pos[3 * id + 2];
}

// ---------------- output 0b: interpolated edge vertices ----------------
__global__ void __launch_bounds__(256) k_out0_edge(
    const u64* __restrict__ edgekeys, const float* __restrict__ pos,
    const float* __restrict__ sdf, const u32* __restrict__ ctr,
    float* __restrict__ out)
{
  int e = blockIdx.x * 256 + threadIdx.x;
  if (e >= (int)ctr[CTR_E]) return;
  u64 k = edgekeys[e];
  int a = (int)(k >> 19);
  int b = (int)(k & 0x7FFFFULL);
  float sa = sdf[a], sb = sdf[b];
  float inv = 1.0f / (sa - sb);
  float wa = -sb * inv, wb = sa * inv;
  u32 j = ctr[CTR_U] + (u32)e;
  size_t o = (size_t)3 * j;
  out[o]     = pos[3 * a] * wa + pos[3 * b] * wb;
  out[o + 1] = pos[3 * a + 1] * wa + pos[3 * b + 1] * wb;
  out[o + 2] = pos[3 * a + 2] * wa + pos[3 * b + 2] * wb;
}

// ---------------- output 1: tets = rank(ids), one 16B store per row ----------------
__global__ void __launch_bounds__(256) k_out1(
    const int* __restrict__ idx, const u8* __restrict__ tetidx,
    const int* __restrict__ edge_ids, const int* __restrict__ rowbase,
    const u64* __restrict__ bwr, const u32* __restrict__ ctr,
    int F, int N, float* __restrict__ out)
{
  int f = blockIdx.x * 256 + threadIdx.x;
  if (f >= F) return;
  u32 ti = tetidx[f];
  if (ti == 0) return;
  int4 v = reinterpret_cast<const int4*>(idx)[f];
  int pc = __popc(ti);
  int nt = (pc == 1 || pc == 4) ? 1 : 3;
  u64 row = TETPACK[ti];
  u32 obase = ctr[CTR_OUT1];
  u32 U0 = ctr[CTR_U];
  int rb = rowbase[f];
  float cr[4] = {0.f, 0.f, 0.f, 0.f};
  const int ids[4] = {v.x, v.y, v.z, v.w};
  #pragma unroll
  for (int c = 0; c < 4; ++c) {
    if ((ti >> c) & 1u) {
      int id = ids[c];
      u64 bw = bwr[(u32)id >> 5];
      cr[c] = (float)((u32)(bw >> 32) + (u32)__popc((u32)bw & ((1u << (id & 31)) - 1u)));
    }
  }
  const bool al16 = (obase & 3u) == 0u;
  float* outp = out + (size_t)obase + (size_t)rb * 4;
  for (int t = 0; t < nt; ++t) {
    u32 quad = (u32)(row >> (16 * t)) & 0xFFFFu;
    float o[4];
    #pragma unroll
    for (int k = 0; k < 4; ++k) {
      u32 e = (quad >> (4 * k)) & 15u;
      o[k] = (e < 4u) ? cr[e] : (float)(U0 + (u32)edge_ids[f * 6 + (int)(e - 4u)]);
    }
    if (al16) {
      *reinterpret_cast<float4*>(outp + (size_t)t * 4) =
          make_float4(o[0], o[1], o[2], o[3]);
    } else {
      __builtin_memcpy(outp + (size_t)t * 4, o, 16);
    }
  }
}

extern "C" void kernel_launch(void* const* d_in, const int* in_sizes, int n_in,
                              void* d_out, int out_size, void* d_ws, size_t ws_size,
                              hipStream_t stream)
{
  const float* verts  = (const float*)d_in[0];
  const float* deform = (const float*)d_in[1];
  const float* sdf    = (const float*)d_in[2];
  const int* indices  = (const int*)d_in[3];
  const int* grptr    = (const int*)d_in[4];
  const int N = in_sizes[2];
  const int F = in_sizes[3] / 4;
  const int MMAX = 4 * F;                      // <=4 crossing edges per tet
  const int NBF = (F + 1023) / 1024;
  const int NBR = (MMAX + RWIN - 1) / RWIN;    // radix blocks (RWIN items each)
  const int NBA = (MMAX + 1023) / 1024;        // headcount/assign blocks
  const int W = (N + 31) / 32;                 // flag bitmap words

  char* p = (char*)d_ws;
  auto take = [&](size_t bytes) {
    char* r = p;
    p += (bytes + 255) & ~(size_t)255;
    return r;
  };
  u32* ctr       = (u32*)take(256);
  u32* gh        = (u32*)take(1344 * 4);
  u64* A         = (u64*)take((size_t)MMAX * 8);
  u64* B         = (u64*)take((size_t)MMAX * 8);
  u64* EK        = (u64*)take((size_t)MMAX * 8);
  int* edge_ids  = (int*)take((size_t)F * 6 * 4);
  float* pos     = (float*)take((size_t)N * 3 * 4);
  int* rowbase   = (int*)take((size_t)F * 4);
  u8* tetidx     = (u8*)take((size_t)F);
  u32* hist      = (u32*)take((size_t)NBR * 256 * 4);
  u32* bsE       = (u32*)take((size_t)NBA * 4);
  u64* bsF       = (u64*)take((size_t)NBF * 8);
  u8* flag       = (u8*)take((size_t)W * 32);
  u32* occw      = (u32*)take((size_t)W * 4);
  u64* bwr       = (u64*)take((size_t)W * 8);
  if ((size_t)(p - (char*)d_ws) > ws_size) return;  // insufficient scratch

  hipMemsetAsync(ctr, 0, 256, stream);
  hipMemsetAsync(gh, 0, 1344 * 4, stream);
  hipMemsetAsync(flag, 0, (size_t)W * 32, stream);

  float* out = (float*)d_out;

  k_pos<<<(N * 3 + 255) / 256, 256, 0, stream>>>(verts, deform, sdf, grptr,
                                                 pos, occw, N, N * 3);
  k_classify<<<NBF, 256, 0, stream>>>(indices, occw, F, A, ctr, bsF, tetidx, flag);
  k_scanF<<<1, 1024, 0, stream>>>(bsF, NBF, ctr);
  k_rowbase<<<NBF, 256, 0, stream>>>(tetidx, bsF, ctr, F, rowbase);

  // one read of A -> all 6 digit-total segments, then scan each
  k_hist4<<<2048, 256, 0, stream>>>(A, ctr, gh);
  k_scan4<<<1, 256, 0, stream>>>(gh);

  // 5-pass LSD radix over key bits 24..61: digits {8,8,8,8,6}
  const int shifts[5] = {24, 32, 40, 48, 56};
  const int nbitsv[5] = {8, 8, 8, 8, 6};
  const int ghoff[5]  = {0, 256, 512, 768, 1024};
  u64* src = A; u64* dst = B;
  for (int pass = 0; pass < 5; ++pass) {
    k_hist<<<NBR, 256, 0, stream>>>(src, ctr, shifts[pass], nbitsv[pass], hist, NBR);
    k_rowscan<<<(1 << nbitsv[pass]), 256, 0, stream>>>(hist, NBR, gh + ghoff[pass]);
    if (nbitsv[pass] == 8)
      k_scatter8<<<NBR, 256, 0, stream>>>(src, dst, ctr, shifts[pass], hist, NBR);
    else
      k_scatter6<<<NBR, 256, 0, stream>>>(src, dst, ctr, shifts[pass], hist, NBR);
    u64* t = src; src = dst; dst = t;
  }
  // sorted result in src (==B after 5 passes); dst (==A) free -> pair staging
  const u64* S = src;
  u64* stage = dst;

  k_headcount<<<NBA, 256, 0, stream>>>(S, ctr, bsE);
  k_scan_u32<<<1, 1024, 0, stream>>>(bsE, NBA, ctr, CTR_E);
  hipMemsetAsync(hist, 0, (size_t)NBR * 256 * 4, stream);
  k_assign<<<NBA, 256, 0, stream>>>(S, ctr, bsE, stage, hist, NBR, EK);
  // partition pairs by payload>>16 (256KB edge_ids windows) then deliver
  k_rowscan<<<256, 256, 0, stream>>>(hist, NBR, gh + 1088);
  k_scatter8<<<NBR, 256, 0, stream>>>(stage, (u64*)S, ctr, 40, hist, NBR);
  k_deliver<<<(MMAX + 255) / 256, 256, 0, stream>>>(S, ctr, edge_ids);

  k_scanbits<<<1, 1024, 0, stream>>>((const u32*)flag, bwr, W, ctr);
  k_out0_orig<<<(N + 255) / 256, 256, 0, stream>>>(bwr, pos, N, out);
  k_out0_edge<<<(MMAX + 255) / 256, 256, 0, stream>>>(EK, pos, sdf, ctr, out);
  k_out1<<<(F + 255) / 256, 256, 0, stream>>>(indices, tetidx, edge_ids, rowbase,
                                              bwr, ctr, F, N, out);
}

// Round 13
// 594.903 us; speedup vs baseline: 2.1812x; 1.0239x over previous
//
#include <hip/hip_runtime.h>
#include <stdint.h>

typedef unsigned int u32;
typedef unsigned long long u64;
typedef unsigned short u16;
typedef unsigned char u8;

#define CTR_M 0
#define CTR_E 1
#define CTR_C1 2
#define CTR_C3 3
#define CTR_CI 4
#define CTR_T 5
#define CTR_U 6
#define CTR_OUT1 7

#define RWIN 4096
#define RROUNDS (RWIN / 1024)

// TET_TABLE rows packed 4 bits/entry (LSB-first), -1 -> 0xF (never read: row
// count limited by num_tets). Row 15 == [0,1,2,3] doubles as the inner-tet row.
__device__ const u64 TETPACK[16] = {
  0xFFFFFFFFFFFFULL,
  0xFFFFFFFF6540ULL,
  0xFFFFFFFF7841ULL,
  0x610567156817ULL,
  0xFFFFFFFF9752ULL,
  0x290767097604ULL,
  0x921549158914ULL,
  0x286921682106ULL,
  0xFFFFFFFF8963ULL,
  0x398538058405ULL,
  0x376936743741ULL,
  0x971539153510ULL,
  0x875385637325ULL,
  0x273078308740ULL,
  0x653452343214ULL,
  0xFFFFFFFF3210ULL
};

// ---- 2-barrier block-scan primitive (wave shuffle + 4-entry exchange) ----
__device__ __forceinline__ u32 bscan256(u32 x, u32* s4, u32& total)
{
  const int lane = threadIdx.x & 63;
  const int wid = threadIdx.x >> 6;
  u32 incl = x;
  #pragma unroll
  for (int d = 1; d < 64; d <<= 1) {
    u32 t = __shfl_up(incl, d);
    if (lane >= d) incl += t;
  }
  if (lane == 63) s4[wid] = incl;
  __syncthreads();
  u32 w0 = s4[0], w1 = s4[1], w2 = s4[2], w3 = s4[3];
  total = w0 + w1 + w2 + w3;
  u32 off = (wid > 0 ? w0 : 0u) + (wid > 1 ? w1 : 0u) + (wid > 2 ? w2 : 0u);
  return off + incl;
}

__device__ __forceinline__ u64 bscan256_64(u64 x, u64* s4, u64& total)
{
  const int lane = threadIdx.x & 63;
  const int wid = threadIdx.x >> 6;
  u64 incl = x;
  #pragma unroll
  for (int d = 1; d < 64; d <<= 1) {
    u64 t = __shfl_up(incl, d);
    if (lane >= d) incl += t;
  }
  if (lane == 63) s4[wid] = incl;
  __syncthreads();
  u64 w0 = s4[0], w1 = s4[1], w2 = s4[2], w3 = s4[3];
  total = w0 + w1 + w2 + w3;
  u64 off = (wid > 0 ? w0 : 0ull) + (wid > 1 ? w1 : 0ull) + (wid > 2 ? w2 : 0ull);
  return off + incl;
}

// ---- pos = verts + tanh(deform)/grid_res ; also occ bitmap (sdf>0) ----
__global__ void __launch_bounds__(256) k_pos(
    const float* __restrict__ verts, const float* __restrict__ deform,
    const float* __restrict__ sdf, const int* __restrict__ grptr,
    float* __restrict__ pos, u32* __restrict__ occw, int N, int n3)
{
  int i = blockIdx.x * 256 + threadIdx.x;
  if (i < n3) {
    float inv = 1.0f / (float)grptr[0];
    pos[i] = verts[i] + tanhf(deform[i]) * inv;
  }
  const int NOCC = (N + 1023) / 1024;
  if (blockIdx.x < NOCC) {
    __shared__ u32 s_nib[256];
    const int tid = threadIdx.x;
    int base = blockIdx.x * 1024 + tid * 4;
    u32 nib = 0;
    if (base + 3 < N) {
      float4 s = *reinterpret_cast<const float4*>(sdf + base);
      nib = (s.x > 0.0f ? 1u : 0u) | (s.y > 0.0f ? 2u : 0u) |
            (s.z > 0.0f ? 4u : 0u) | (s.w > 0.0f ? 8u : 0u);
    } else {
      for (int k = 0; k < 4; ++k)
        if (base + k < N) nib |= (sdf[base + k] > 0.0f ? 1u : 0u) << k;
    }
    s_nib[tid] = nib;
    __syncthreads();
    if (tid < 32) {
      u32 w = 0;
      #pragma unroll
      for (int j = 0; j < 8; ++j) w |= s_nib[tid * 8 + j] << (4 * j);
      int wi = blockIdx.x * 32 + tid;
      if (wi < (N + 31) / 32) occw[wi] = w;
    }
  }
}

// ---- classify tets, emit crossing-edge records, flag inside verts ----
__global__ void __launch_bounds__(256) k_classify(
    const int* __restrict__ idx, const u32* __restrict__ occw, int F,
    u64* __restrict__ A, u32* __restrict__ ctr,
    u64* __restrict__ bsF, u8* __restrict__ tetidx, u8* __restrict__ flag)
{
  const int tid = threadIdx.x;
  const int lane = tid & 63;
  const int wid = tid >> 6;
  const int base = blockIdx.x * 1024 + tid * 4;
  u32 tis4 = 0;
  u32 cms[4];
  int4 vs[4];
  u64 cnt = 0;
  u32 ec = 0;
  #pragma unroll
  for (int it = 0; it < 4; ++it) {
    const int f = base + it;
    u32 ti = 0, cm = 0;
    int4 v = make_int4(0, 0, 0, 0);
    if (f < F) {
      v = reinterpret_cast<const int4*>(idx)[f];
      u32 b0 = (occw[(u32)v.x >> 5] >> (v.x & 31)) & 1u;
      u32 b1 = (occw[(u32)v.y >> 5] >> (v.y & 31)) & 1u;
      u32 b2 = (occw[(u32)v.z >> 5] >> (v.z & 31)) & 1u;
      u32 b3 = (occw[(u32)v.w >> 5] >> (v.w & 31)) & 1u;
      if (b0) flag[v.x] = 1;
      if (b1) flag[v.y] = 1;
      if (b2) flag[v.z] = 1;
      if (b3) flag[v.w] = 1;
      ti = b0 | (b1 << 1) | (b2 << 2) | (b3 << 3);
      cm  = (b0 ^ b1);
      cm |= (b0 ^ b2) << 1;
      cm |= (b0 ^ b3) << 2;
      cm |= (b1 ^ b2) << 3;
      cm |= (b1 ^ b3) << 4;
      cm |= (b2 ^ b3) << 5;
      int pc = __popc(ti);
      if (pc == 1) cnt += 1ULL;
      else if (pc == 2 || pc == 3) cnt += (1ULL << 21);
      else if (pc == 4) cnt += (1ULL << 42);
    }
    vs[it] = v;
    cms[it] = cm;
    tis4 |= ti << (8 * it);
    ec += __popc(cm);
  }
  u32 incl = ec;
  #pragma unroll
  for (int d = 1; d < 64; d <<= 1) {
    u32 t = __shfl_up(incl, d);
    if (lane >= d) incl += t;
  }
  u32 excl = incl - ec;
  __shared__ u32 s_wtot[4];
  __shared__ u32 s_base;
  if (lane == 63) s_wtot[wid] = incl;
  __syncthreads();
  if (tid == 0) {
    u32 t0 = s_wtot[0], t1 = s_wtot[1], t2 = s_wtot[2], t3 = s_wtot[3];
    u32 tot = t0 + t1 + t2 + t3;
    s_base = tot ? atomicAdd(&ctr[CTR_M], tot) : 0u;
    s_wtot[0] = 0; s_wtot[1] = t0; s_wtot[2] = t0 + t1; s_wtot[3] = t0 + t1 + t2;
  }
  __syncthreads();
  u32 w = s_base + s_wtot[wid] + excl;
  #pragma unroll
  for (int it = 0; it < 4; ++it) {
    u32 cm = cms[it];
    if (!cm) continue;
    const int f = base + it;
    const int va[6] = {vs[it].x, vs[it].x, vs[it].x, vs[it].y, vs[it].y, vs[it].z};
    const int vb[6] = {vs[it].y, vs[it].z, vs[it].w, vs[it].z, vs[it].w, vs[it].w};
    #pragma unroll
    for (int s = 0; s < 6; ++s) {
      if ((cm >> s) & 1u) {
        int a = va[s], b = vb[s];
        int mn = min(a, b), mx = max(a, b);
        u64 key = ((u64)(u32)mn << 19) | (u64)(u32)mx;
        A[w++] = (key << 24) | (u64)(u32)(f * 6 + s);
      }
    }
  }
  if (base < F) {
    if (base + 3 < F) {
      *reinterpret_cast<u32*>(tetidx + base) = tis4;
    } else {
      for (int it = 0; it < 4; ++it)
        if (base + it < F) tetidx[base + it] = (u8)((tis4 >> (8 * it)) & 255u);
    }
  }
  u64 r = cnt;
  #pragma unroll
  for (int d = 32; d > 0; d >>= 1) r += __shfl_xor(r, d);
  __shared__ u64 s_w64[4];
  if (lane == 0) s_w64[wid] = r;
  __syncthreads();
  if (tid == 0) bsF[blockIdx.x] = s_w64[0] + s_w64[1] + s_w64[2] + s_w64[3];
}

// ---- pad A[M .. roundup(M,RWIN)) with max-key sentinels ----
__global__ void __launch_bounds__(256) k_pad(
    u64* __restrict__ A, const u32* __restrict__ ctr)
{
  const u32 M = ctr[CTR_M];
  const u32 Mp = (M + RWIN - 1) & ~(u32)(RWIN - 1);
  u32 i = M + blockIdx.x * 256 + threadIdx.x;
  if (i < Mp) A[i] = ~0ULL;
}

// ---- all-pass digit histograms in ONE read of A (order-invariant) ----
// segments: 0:[256] s24 | 256:[256] s32 | 512:[256] s40 | 768:[256] s48 |
//           1024:[64] s56 | 1088:[256] partition ((v>>16)&255)
__global__ void __launch_bounds__(256) k_hist4(
    const u64* __restrict__ A, const u32* __restrict__ ctr, u32* __restrict__ gh)
{
  __shared__ u32 sh[1344];
  const int tid = threadIdx.x;
  for (int b = tid; b < 1344; b += 256) sh[b] = 0;
  __syncthreads();
  const int M = (int)ctr[CTR_M];
  for (int i = blockIdx.x * 256 + tid; i < M; i += gridDim.x * 256) {
    u64 v = A[i];
    atomicAdd(&sh[        (u32)(v >> 24) & 255u], 1u);
    atomicAdd(&sh[ 256 + ((u32)(v >> 32) & 255u)], 1u);
    atomicAdd(&sh[ 512 + ((u32)(v >> 40) & 255u)], 1u);
    atomicAdd(&sh[ 768 + ((u32)(v >> 48) & 255u)], 1u);
    atomicAdd(&sh[1024 + ((u32)(v >> 56) &  63u)], 1u);
    atomicAdd(&sh[1088 + ((u32)(v >> 16) & 255u)], 1u);
  }
  __syncthreads();
  for (int b = tid; b < 1344; b += 256) if (sh[b]) atomicAdd(&gh[b], sh[b]);
}

// ---- exclusive scan of each segment of gh ----
__global__ void __launch_bounds__(256) k_scan4(u32* __restrict__ gh)
{
  __shared__ u32 s4[4];
  const int tid = threadIdx.x;
  const int off[6] = {0, 256, 512, 768, 1024, 1088};
  const int len[6] = {256, 256, 256, 256, 64, 256};
  for (int s = 0; s < 6; ++s) {
    u32 v = (tid < len[s]) ? gh[off[s] + tid] : 0u;
    u32 total;
    u32 incl = bscan256(v, s4, total);
    if (tid < len[s]) gh[off[s] + tid] = incl - v;
    __syncthreads();
  }
}

// ---- per-digit row scan: hist[d][0..NBR) -> global exclusive bases ----
__global__ void __launch_bounds__(256) k_rowscan(
    u32* __restrict__ hist, int NBR, const u32* __restrict__ gh)
{
  const int d = blockIdx.x;
  u32* row = hist + (size_t)d * NBR;
  const int tid = threadIdx.x;
  __shared__ u32 s4[4];
  u32 carry = gh[d];
  for (int start = 0; start < NBR; start += 256) {
    int i = start + tid;
    u32 v = (i < NBR) ? row[i] : 0u;
    u32 total;
    u32 incl = bscan256(v, s4, total);
    if (i < NBR) row[i] = carry + incl - v;
    carry += total;
    __syncthreads();
  }
}

// ---- exclusive scan of packed per-block category counts (single block) ----
__global__ void __launch_bounds__(1024) k_scanF(
    u64* __restrict__ bsF, int nb, u32* __restrict__ ctr)
{
  __shared__ u64 sh16[16];
  const int tid = threadIdx.x;
  const int lane = tid & 63;
  const int wid = tid >> 6;
  u64 carry = 0;
  for (int start = 0; start < nb; start += 1024) {
    int i = start + tid;
    u64 v = (i < nb) ? bsF[i] : 0ULL;
    u64 incl = v;
    #pragma unroll
    for (int d = 1; d < 64; d <<= 1) {
      u64 t = __shfl_up(incl, d);
      if (lane >= d) incl += t;
    }
    if (lane == 63) sh16[wid] = incl;
    __syncthreads();
    if (wid == 0) {
      u64 w = (lane < 16) ? sh16[lane] : 0ull;
      #pragma unroll
      for (int d = 1; d < 16; d <<= 1) {
        u64 t = __shfl_up(w, d);
        if (lane >= d) w += t;
      }
      if (lane < 16) sh16[lane] = w;
    }
    __syncthreads();
    u64 waveoff = (wid > 0) ? sh16[wid - 1] : 0ull;
    u64 total = sh16[15];
    if (i < nb) bsF[i] = carry + waveoff + incl - v;
    carry += total;
    __syncthreads();
  }
  if (tid == 0) {
    u32 c1 = (u32)(carry & 0x1FFFFFULL);
    u32 c3 = (u32)((carry >> 21) & 0x1FFFFFULL);
    u32 ci = (u32)((carry >> 42) & 0x1FFFFFULL);
    ctr[CTR_C1] = c1; ctr[CTR_C3] = c3; ctr[CTR_CI] = ci;
    ctr[CTR_T] = c1 + 3u * c3 + ci;
  }
}

// ---- per-tet output row base (mt1 region | mt3 region | inner region) ----
__global__ void __launch_bounds__(256) k_rowbase(
    const u8* __restrict__ tetidx, const u64* __restrict__ bsF,
    const u32* __restrict__ ctr, int F, int* __restrict__ rowbase)
{
  const int tid = threadIdx.x;
  const int base = blockIdx.x * 1024 + tid * 4;
  u32 tis[4];
  u64 cnt = 0;
  #pragma unroll
  for (int it = 0; it < 4; ++it) {
    int f = base + it;
    u32 ti = (f < F) ? (u32)tetidx[f] : 0u;
    tis[it] = ti;
    int pc = __popc(ti);
    if (ti) {
      if (pc == 1) cnt += 1ULL;
      else if (pc <= 3) cnt += (1ULL << 21);
      else cnt += (1ULL << 42);
    }
  }
  __shared__ u64 s4[4];
  u64 total;
  u64 incl = bscan256_64(cnt, s4, total);
  u64 off = bsF[blockIdx.x] + (incl - cnt);
  u32 o1 = (u32)(off & 0x1FFFFFULL);
  u32 o3 = (u32)((off >> 21) & 0x1FFFFFULL);
  u32 oi = (u32)((off >> 42) & 0x1FFFFFULL);
  const u32 C1 = ctr[CTR_C1], C3 = ctr[CTR_C3];
  int rb[4];
  #pragma unroll
  for (int it = 0; it < 4; ++it) {
    u32 ti = tis[it];
    int pc = __popc(ti);
    int r = -1;
    if (ti == 15u) { r = (int)(C1 + 3u * C3 + oi); ++oi; }
    else if (ti) {
      if (pc == 1) { r = (int)o1; ++o1; }
      else { r = (int)(C1 + 3u * o3); ++o3; }
    }
    rb[it] = r;
  }
  if (base + 3 < F) {
    reinterpret_cast<int4*>(rowbase)[base >> 2] = make_int4(rb[0], rb[1], rb[2], rb[3]);
  } else {
    for (int it = 0; it < 4; ++it)
      if (base + it < F) rowbase[base + it] = rb[it];
  }
}

// ---- radix per-block histogram (RWIN items/block, sentinel-padded input) ----
__global__ void __launch_bounds__(256) k_hist(
    const u64* __restrict__ src, const u32* __restrict__ ctr,
    int shift, int nbits, u32* __restrict__ hist, int NBR)
{
  const int NB = 1 << nbits;
  const u32 M = ctr[CTR_M];
  const u32 Mp = (M + RWIN - 1) & ~(u32)(RWIN - 1);
  const u32 base = blockIdx.x * RWIN;
  if (base >= Mp) return;
  __shared__ u32 sh[256];
  const int tid = threadIdx.x;
  if (tid < NB) sh[tid] = 0;
  __syncthreads();
  #pragma unroll
  for (int r = 0; r < RROUNDS; ++r) {
    u32 ib = base + r * 1024 + tid * 4;
    #pragma unroll
    for (int j = 0; j < 4; ++j) {
      u32 d = (u32)(src[ib + j] >> shift) & (u32)(NB - 1);
      atomicAdd(&sh[d], 1u);
    }
  }
  __syncthreads();
  if (tid < NB) hist[tid * NBR + blockIdx.x] = sh[tid];
}

// ---- single-block scan (kept for small arrays: bsE) ----
__device__ __forceinline__ u32 block_scan_incl_1024(u32 x, u32* shtmp, u32& total)
{
  const int lane = threadIdx.x & 63;
  const int wid = threadIdx.x >> 6;
  u32 incl = x;
  #pragma unroll
  for (int d = 1; d < 64; d <<= 1) {
    u32 t = __shfl_up(incl, d);
    if (lane >= d) incl += t;
  }
  if (lane == 63) shtmp[wid] = incl;
  __syncthreads();
  if (wid == 0) {
    u32 w = (lane < 16) ? shtmp[lane] : 0u;
    #pragma unroll
    for (int d = 1; d < 16; d <<= 1) {
      u32 t = __shfl_up(w, d);
      if (lane >= d) w += t;
    }
    if (lane < 16) shtmp[lane] = w;
  }
  __syncthreads();
  u32 waveoff = (wid > 0) ? shtmp[wid - 1] : 0u;
  total = shtmp[15];
  return waveoff + incl;
}

__global__ void __launch_bounds__(1024) k_scan_u32(
    u32* __restrict__ data, int L, u32* __restrict__ ctr, int slot)
{
  __shared__ u32 shtmp[16];
  const int tid = threadIdx.x;
  u32 carry = 0;
  for (int start = 0; start < L; start += 4096) {
    u32 v[4]; u32 s = 0;
    #pragma unroll
    for (int j = 0; j < 4; ++j) {
      int i = start + tid * 4 + j;
      v[j] = (i < L) ? data[i] : 0u;
      s += v[j];
    }
    u32 total;
    u32 incl = block_scan_incl_1024(s, shtmp, total);
    u32 run = carry + incl - s;
    #pragma unroll
    for (int j = 0; j < 4; ++j) {
      int i = start + tid * 4 + j;
      if (i < L) data[i] = run;
      run += v[j];
    }
    carry += total;
    __syncthreads();
  }
  if (slot >= 0 && tid == 0) ctr[slot] = carry;
}

// ------- radix scatter: stable, LDS-staged for coalesced global writes -------
// Per 1024-item round:
//  A: ballot-rank per (slot,digit); writer lane stores count
//  B: thread d: slot-prefix per digit; bscan over digit totals -> s_drs
//  C: stage items into LDS at lpos = drs[d] + slotpref + lanerank (digit order)
//  copy: thread-linear read of stage -> dst[gbase[d] + (lpos - drs[d])]
//  D: gbase[d] += round total; re-zero s_wh
template<int NBITS, bool PADDED>
__device__ __forceinline__ void scatter_body(
    const u64* __restrict__ src, u64* __restrict__ dst,
    const u32* __restrict__ ctr, int shift,
    const u32* __restrict__ hist, int NBR,
    u32* s_gbase, u16* s_wh, u64* s_stage, u32* s_drs, u32* s4)
{
  const int NB = 1 << NBITS;
  const int tid = threadIdx.x;
  const int lane = tid & 63;
  const int wid = tid >> 6;
  const u32 M = ctr[CTR_M];
  const u32 Mp = PADDED ? ((M + RWIN - 1) & ~(u32)(RWIN - 1)) : M;
  const u32 base = blockIdx.x * RWIN;
  if (base >= Mp) return;
  if (tid < NB) s_gbase[tid] = hist[tid * NBR + blockIdx.x];
  for (int b = tid; b < NB * 8; b += 256) reinterpret_cast<u32*>(s_wh)[b] = 0;
  __syncthreads();
  const u64 lowmask = (1ULL << lane) - 1ULL;
  for (int r = 0; r < RROUNDS; ++r) {
    u32 rbase = base + r * 1024;
    if (rbase >= Mp) break;                 // uniform across block
    u64 v[4]; u32 d4[4]; u32 lr4[4]; bool act[4];
    #pragma unroll
    for (int j = 0; j < 4; ++j) {
      u32 ib = rbase + (wid * 4 + j) * 64 + lane;
      act[j] = PADDED ? true : (ib < M);
      v[j] = act[j] ? src[ib] : ~0ULL;
      d4[j] = (u32)(v[j] >> shift) & (u32)(NB - 1);
    }
    // Phase A
    #pragma unroll
    for (int j = 0; j < 4; ++j) {
      u32 d = d4[j];
      u64 mask = PADDED ? ~0ULL : __ballot(act[j]);
      for (int b = 0; b < NBITS; ++b) {
        u64 bal = __ballot(((d >> b) & 1u) != 0u);
        mask &= ((d >> b) & 1u) ? bal : ~bal;
      }
      lr4[j] = (u32)__popcll(mask & lowmask);
      if (act[j] && lr4[j] == 0)
        s_wh[(wid * 4 + j) * NB + d] = (u16)__popcll(mask);
    }
    __syncthreads();
    // Phase B: per-digit slot prefix + digit-start scan
    u32 mytot = 0;
    if (tid < NB) {
      u32 run = 0;
      #pragma unroll
      for (int s = 0; s < 16; ++s) {
        u32 c = (u32)s_wh[s * NB + tid];
        s_wh[s * NB + tid] = (u16)run;
        run += c;
      }
      mytot = run;
    }
    u32 dtot;
    u32 dincl = bscan256(mytot, s4, dtot);
    if (tid < NB) s_drs[tid] = dincl - mytot;
    __syncthreads();
    // Phase C: stage into LDS in digit order
    #pragma unroll
    for (int j = 0; j < 4; ++j) {
      if (!act[j]) continue;
      u32 d = d4[j];
      u32 lpos = s_drs[d] + (u32)s_wh[(wid * 4 + j) * NB + d] + lr4[j];
      s_stage[lpos] = v[j];
    }
    __syncthreads();
    // copy out (coalesced within digit runs)
    #pragma unroll
    for (int k = 0; k < 4; ++k) {
      u32 i = k * 256u + (u32)tid;
      if (i < dtot) {
        u64 vv = s_stage[i];
        u32 d = (u32)(vv >> shift) & (u32)(NB - 1);
        dst[s_gbase[d] + (i - s_drs[d])] = vv;
      }
    }
    __syncthreads();
    // Phase D: advance bases + re-zero
    if (tid < NB) {
      s_gbase[tid] += mytot;
      #pragma unroll
      for (int s = 0; s < 16; ++s) s_wh[s * NB + tid] = 0;
    }
    __syncthreads();
  }
}

__global__ void __launch_bounds__(256) k_scatter8p(
    const u64* __restrict__ src, u64* __restrict__ dst,
    const u32* __restrict__ ctr, int shift,
    const u32* __restrict__ hist, int NBR)
{
  __shared__ u32 s_gbase[256];
  __shared__ u16 s_wh[16 * 256];
  __shared__ u64 s_stage[1024];
  __shared__ u32 s_drs[256];
  __shared__ u32 s4[4];
  scatter_body<8, true>(src, dst, ctr, shift, hist, NBR,
                        s_gbase, s_wh, s_stage, s_drs, s4);
}

__global__ void __launch_bounds__(256) k_scatter8m(
    const u64* __restrict__ src, u64* __restrict__ dst,
    const u32* __restrict__ ctr, int shift,
    const u32* __restrict__ hist, int NBR)
{
  __shared__ u32 s_gbase[256];
  __shared__ u16 s_wh[16 * 256];
  __shared__ u64 s_stage[1024];
  __shared__ u32 s_drs[256];
  __shared__ u32 s4[4];
  scatter_body<8, false>(src, dst, ctr, shift, hist, NBR,
                         s_gbase, s_wh, s_stage, s_drs, s4);
}

__global__ void __launch_bounds__(256) k_scatter6p(
    const u64* __restrict__ src, u64* __restrict__ dst,
    const u32* __restrict__ ctr, int shift,
    const u32* __restrict__ hist, int NBR)
{
  __shared__ u32 s_gbase[64];
  __shared__ u16 s_wh[16 * 64];
  __shared__ u64 s_stage[1024];
  __shared__ u32 s_drs[64];
  __shared__ u32 s4[4];
  scatter_body<6, true>(src, dst, ctr, shift, hist, NBR,
                        s_gbase, s_wh, s_stage, s_drs, s4);
}

// ---------------- unique-run head counts per block (1024 items/block) ----------------
__global__ void __launch_bounds__(256) k_headcount(
    const u64* __restrict__ S, const u32* __restrict__ ctr, u32* __restrict__ bsE)
{
  const int tid = threadIdx.x;
  const int lane = tid & 63;
  const int wid = tid >> 6;
  const int M = (int)ctr[CTR_M];
  if (blockIdx.x * 1024 >= M) {
    if (tid == 0) bsE[blockIdx.x] = 0;
    return;
  }
  const int base = blockIdx.x * 1024 + tid * 4;
  u32 c = 0;
  u64 prev = (base > 0 && base < M) ? (S[base - 1] >> 24) : 0ULL;
  #pragma unroll
  for (int j = 0; j < 4; ++j) {
    int i = base + j;
    if (i < M) {
      u64 k = S[i] >> 24;
      c += ((i == 0) || (k != prev)) ? 1u : 0u;
      prev = k;
    }
  }
  #pragma unroll
  for (int d = 32; d > 0; d >>= 1) c += __shfl_xor(c, d);
  __shared__ u32 s4[4];
  if (lane == 0) s4[wid] = c;
  __syncthreads();
  if (tid == 0) bsE[blockIdx.x] = s4[0] + s4[1] + s4[2] + s4[3];
}

// ---- assign ids (4 items/thread): unique keys + coalesced pairs + fused hist ----
__global__ void __launch_bounds__(256) k_assign(
    const u64* __restrict__ S, const u32* __restrict__ ctr,
    const u32* __restrict__ bsE, u64* __restrict__ stage,
    u32* __restrict__ hist, int NBR, u64* __restrict__ edgekeys)
{
  const int tid = threadIdx.x;
  const int M = (int)ctr[CTR_M];
  if (blockIdx.x * 1024 >= M) return;      // no items, no hist contributions
  const int base = blockIdx.x * 1024 + tid * 4;
  __shared__ u32 s_h[256];
  __shared__ u32 s4[4];
  s_h[tid] = 0;
  u64 v[4]; bool hd[4];
  u32 c = 0;
  u64 prev = (base > 0 && base < M) ? (S[base - 1] >> 24) : 0ULL;
  #pragma unroll
  for (int j = 0; j < 4; ++j) {
    int i = base + j;
    v[j] = (i < M) ? S[i] : 0ULL;
    u64 k = v[j] >> 24;
    hd[j] = (i < M) && ((i == 0) || (k != prev));
    if (i < M) prev = k;
    c += hd[j] ? 1u : 0u;
  }
  u32 total;
  u32 incl = bscan256(c, s4, total);       // also syncs s_h init
  u32 run = bsE[blockIdx.x] + incl - c;
  #pragma unroll
  for (int j = 0; j < 4; ++j) {
    int i = base + j;
    if (i < M) {
      run += hd[j] ? 1u : 0u;
      u32 id = run - 1u;
      if (hd[j]) edgekeys[id] = v[j] >> 24;
      u32 pay = (u32)(v[j] & 0xFFFFFFULL);
      stage[i] = ((u64)pay << 24) | (u64)id;
      atomicAdd(&s_h[(pay >> 16) & 255u], 1u);
    }
  }
  __syncthreads();
  if (s_h[tid]) atomicAdd(&hist[tid * NBR + (blockIdx.x >> 2)], s_h[tid]);
}

// ---- deliver: edge_ids[payload] = id (payload-bucketed for L2 locality) ----
__global__ void __launch_bounds__(256) k_deliver(
    const u64* __restrict__ D, const u32* __restrict__ ctr,
    int* __restrict__ edge_ids)
{
  int i = blockIdx.x * 256 + threadIdx.x;
  if (i >= (int)ctr[CTR_M]) return;
  u64 c = D[i];
  edge_ids[(u32)(c >> 24)] = (int)(c & 0xFFFFFFULL);
}

// ---- rank scan over flag bytes -> bwr (low32 = bits, high32 = wordrank) ----
__global__ void __launch_bounds__(1024) k_scanbits(
    const u32* __restrict__ flag32, u64* __restrict__ bwr,
    int W, u32* __restrict__ ctr)
{
  __shared__ u32 shtmp[16];
  const int tid = threadIdx.x;
  u32 carry = 0;
  for (int start = 0; start < W; start += 1024) {
    int w = start + tid;
    u32 bits = 0;
    if (w < W) {
      #pragma unroll
      for (int k = 0; k < 8; ++k) {
        u32 fo = flag32[w * 8 + k];
        u32 nib = (fo & 1u) | ((fo >> 7) & 2u) | ((fo >> 14) & 4u) | ((fo >> 21) & 8u);
        bits |= nib << (4 * k);
      }
    }
    u32 c = (u32)__popc(bits);
    u32 total;
    u32 incl = block_scan_incl_1024(c, shtmp, total);
    if (w < W) bwr[w] = (u64)bits | ((u64)(carry + incl - c) << 32);
    carry += total;
    __syncthreads();
  }
  if (tid == 0) {
    ctr[CTR_U] = carry;
    ctr[CTR_OUT1] = 3u * (carry + ctr[CTR_E]);
  }
}

// ---------------- output 0a: original vertices ----------------
__global__ void __launch_bounds__(256) k_out0_orig(
    const u64* __restrict__ bwr, const float* __restrict__ pos,
    int N, float* __restrict__ out)
{
  int id = blockIdx.x * 256 + threadIdx.x;
  if (id >= N) return;
  u64 bw = bwr[(u32)id >> 5];
  u32 bits = (u32)bw;
  if (!((bits >> (id & 31)) & 1u)) return;
  u32 j = (u32)(bw >> 32) + (u32)__popc(bits & ((1u << (id & 31)) - 1u));
  size_t o = (size_t)3 * j;
  out[o] = pos[3 * id]; out[o + 1] = pos[3 * id + 1]; out[o + 2] = pos[3 * id + 2];
}

// ---------------- output 0b: interpolated edge vertices ----------------
__global__ void __launch_bounds__(256) k_out0_edge(
    const u64* __restrict__ edgekeys, const float* __restrict__ pos,
    const float* __restrict__ sdf, const u32* __restrict__ ctr,
    float* __restrict__ out)
{
  int e = blockIdx.x * 256 + threadIdx.x;
  if (e >= (int)ctr[CTR_E]) return;
  u64 k = edgekeys[e];
  int a = (int)(k >> 19);
  int b = (int)(k & 0x7FFFFULL);
  float sa = sdf[a], sb = sdf[b];
  float inv = 1.0f / (sa - sb);
  float wa = -sb * inv, wb = sa * inv;
  u32 j = ctr[CTR_U] + (u32)e;
  size_t o = (size_t)3 * j;
  out[o]     = pos[3 * a] * wa + pos[3 * b] * wb;
  out[o + 1] = pos[3 * a + 1] * wa + pos[3 * b + 1] * wb;
  out[o + 2] = pos[3 * a + 2] * wa + pos[3 * b + 2] * wb;
}

// ---------------- output 1: tets = rank(ids), one 16B store per row ----------------
__global__ void __launch_bounds__(256) k_out1(
    const int* __restrict__ idx, const u8* __restrict__ tetidx,
    const int* __restrict__ edge_ids, const int* __restrict__ rowbase,
    const u64* __restrict__ bwr, const u32* __restrict__ ctr,
    int F, int N, float* __restrict__ out)
{
  int f = blockIdx.x * 256 + threadIdx.x;
  if (f >= F) return;
  u32 ti = tetidx[f];
  if (ti == 0) return;
  int4 v = reinterpret_cast<const int4*>(idx)[f];
  int pc = __popc(ti);
  int nt = (pc == 1 || pc == 4) ? 1 : 3;
  u64 row = TETPACK[ti];
  u32 obase = ctr[CTR_OUT1];
  u32 U0 = ctr[CTR_U];
  int rb = rowbase[f];
  float cr[4] = {0.f, 0.f, 0.f, 0.f};
  const int ids[4] = {v.x, v.y, v.z, v.w};
  #pragma unroll
  for (int c = 0; c < 4; ++c) {
    if ((ti >> c) & 1u) {
      int id = ids[c];
      u64 bw = bwr[(u32)id >> 5];
      cr[c] = (float)((u32)(bw >> 32) + (u32)__popc((u32)bw & ((1u << (id & 31)) - 1u)));
    }
  }
  const bool al16 = (obase & 3u) == 0u;
  float* outp = out + (size_t)obase + (size_t)rb * 4;
  for (int t = 0; t < nt; ++t) {
    u32 quad = (u32)(row >> (16 * t)) & 0xFFFFu;
    float o[4];
    #pragma unroll
    for (int k = 0; k < 4; ++k) {
      u32 e = (quad >> (4 * k)) & 15u;
      o[k] = (e < 4u) ? cr[e] : (float)(U0 + (u32)edge_ids[f * 6 + (int)(e - 4u)]);
    }
    if (al16) {
      *reinterpret_cast<float4*>(outp + (size_t)t * 4) =
          make_float4(o[0], o[1], o[2], o[3]);
    } else {
      __builtin_memcpy(outp + (size_t)t * 4, o, 16);
    }
  }
}

extern "C" void kernel_launch(void* const* d_in, const int* in_sizes, int n_in,
                              void* d_out, int out_size, void* d_ws, size_t ws_size,
                              hipStream_t stream)
{
  const float* verts  = (const float*)d_in[0];
  const float* deform = (const float*)d_in[1];
  const float* sdf    = (const float*)d_in[2];
  const int* indices  = (const int*)d_in[3];
  const int* grptr    = (const int*)d_in[4];
  const int N = in_sizes[2];
  const int F = in_sizes[3] / 4;
  const int MMAX = 4 * F;                      // <=4 crossing edges per tet
  const int NBF = (F + 1023) / 1024;
  const int NBR = (MMAX + RWIN - 1) / RWIN;    // radix blocks (RWIN items each)
  const int NBA = (MMAX + 1023) / 1024;        // headcount/assign blocks
  const int W = (N + 31) / 32;                 // flag bitmap words

  char* p = (char*)d_ws;
  auto take = [&](size_t bytes) {
    char* r = p;
    p += (bytes + 255) & ~(size_t)255;
    return r;
  };
  u32* ctr       = (u32*)take(256);
  u32* gh        = (u32*)take(1344 * 4);
  u64* A         = (u64*)take((size_t)NBR * RWIN * 8);
  u64* B         = (u64*)take((size_t)NBR * RWIN * 8);
  u64* EK        = (u64*)take((size_t)MMAX * 8);
  int* edge_ids  = (int*)take((size_t)F * 6 * 4);
  float* pos     = (float*)take((size_t)N * 3 * 4);
  int* rowbase   = (int*)take((size_t)F * 4);
  u8* tetidx     = (u8*)take((size_t)F);
  u32* hist      = (u32*)take((size_t)NBR * 256 * 4);
  u32* bsE       = (u32*)take((size_t)NBA * 4);
  u64* bsF       = (u64*)take((size_t)NBF * 8);
  u8* flag       = (u8*)take((size_t)W * 32);
  u32* occw      = (u32*)take((size_t)W * 4);
  u64* bwr       = (u64*)take((size_t)W * 8);
  if ((size_t)(p - (char*)d_ws) > ws_size) return;  // insufficient scratch

  hipMemsetAsync(ctr, 0, 256, stream);
  hipMemsetAsync(gh, 0, 1344 * 4, stream);
  hipMemsetAsync(flag, 0, (size_t)W * 32, stream);

  float* out = (float*)d_out;

  k_pos<<<(N * 3 + 255) / 256, 256, 0, stream>>>(verts, deform, sdf, grptr,
                                                 pos, occw, N, N * 3);
  k_classify<<<NBF, 256, 0, stream>>>(indices, occw, F, A, ctr, bsF, tetidx, flag);
  k_pad<<<RWIN / 256, 256, 0, stream>>>(A, ctr);
  k_scanF<<<1, 1024, 0, stream>>>(bsF, NBF, ctr);
  k_rowbase<<<NBF, 256, 0, stream>>>(tetidx, bsF, ctr, F, rowbase);

  // one read of A -> all 6 digit-total segments, then scan each
  k_hist4<<<2048, 256, 0, stream>>>(A, ctr, gh);
  k_scan4<<<1, 256, 0, stream>>>(gh);

  // 5-pass LSD radix over key bits 24..61: digits {8,8,8,8,6}
  const int shifts[5] = {24, 32, 40, 48, 56};
  const int nbitsv[5] = {8, 8, 8, 8, 6};
  const int ghoff[5]  = {0, 256, 512, 768, 1024};
  u64* src = A; u64* dst = B;
  for (int pass = 0; pass < 5; ++pass) {
    k_hist<<<NBR, 256, 0, stream>>>(src, ctr, shifts[pass], nbitsv[pass], hist, NBR);
    k_rowscan<<<(1 << nbitsv[pass]), 256, 0, stream>>>(hist, NBR, gh + ghoff[pass]);
    if (nbitsv[pass] == 8)
      k_scatter8p<<<NBR, 256, 0, stream>>>(src, dst, ctr, shifts[pass], hist, NBR);
    else
      k_scatter6p<<<NBR, 256, 0, stream>>>(src, dst, ctr, shifts[pass], hist, NBR);
    u64* t = src; src = dst; dst = t;
  }
  // sorted result in src (==B after 5 passes); dst (==A) free -> pair staging
  const u64* S = src;
  u64* stage = dst;

  k_headcount<<<NBA, 256, 0, stream>>>(S, ctr, bsE);
  k_scan_u32<<<1, 1024, 0, stream>>>(bsE, NBA, ctr, CTR_E);
  hipMemsetAsync(hist, 0, (size_t)NBR * 256 * 4, stream);
  k_assign<<<NBA, 256, 0, stream>>>(S, ctr, bsE, stage, hist, NBR, EK);
  // partition pairs by payload>>16 (256KB edge_ids windows) then deliver
  k_rowscan<<<256, 256, 0, stream>>>(hist, NBR, gh + 1088);
  k_scatter8m<<<NBR, 256, 0, stream>>>(stage, (u64*)S, ctr, 40, hist, NBR);
  k_deliver<<<(MMAX + 255) / 256, 256, 0, stream>>>(S, ctr, edge_ids);

  k_scanbits<<<1, 1024, 0, stream>>>((const u32*)flag, bwr, W, ctr);
  k_out0_orig<<<(N + 255) / 256, 256, 0, stream>>>(bwr, pos, N, out);
  k_out0_edge<<<(MMAX + 255) / 256, 256, 0, stream>>>(EK, pos, sdf, ctr, out);
  k_out1<<<(F + 255) / 256, 256, 0, stream>>>(indices, tetidx, edge_ids, rowbase,
                                              bwr, ctr, F, N, out);
}